// Round 2
// baseline (10518.728 us; speedup 1.0000x reference)
//
#include <hip/hip_runtime.h>

// ---------------------------------------------------------------------------
// SparseEncoderResUNet on MI355X — round 2: fp32, compacted stage-1,
// total workspace footprint 127.08 MB (round-1 crash attributed to ws overflow
// at ~283 MB). Guard: if ws_size < NEED, write zeros (clean fail, no fault).
//
// Layout (floats from ws base):
//   A = 0          (8,388,608)  xin2 -> xin3 -> x4
//   B = 8,388,608  (8,388,608)  x1c (head) -> t2 -> t3
//   C = 16,777,216 (8,388,608)  t1c/idx/list (head) -> x2 -> x3
//   W = 25,165,824 (6,530,304)  transposed weights
//   m2/m3/cnt tail -> total 31,769,872 floats = 127,079,488 bytes
// ---------------------------------------------------------------------------

enum { EPI_MASK = 1, EPI_LEAKY = 2, EPI_RESID = 4 };
#define ROWCAP 32768

__device__ __forceinline__ float leaky(float v) { return v >= 0.f ? v : 0.2f * v; }

// ---------------- weight transpose: w[co][cik] -> wT[cik][co] ----------------
__global__ __launch_bounds__(256) void transpose_w_kernel(
    const float* __restrict__ w, float* __restrict__ wT, int CO, int CIK)
{
    int i = blockIdx.x * 256 + threadIdx.x;
    if (i >= CO * CIK) return;
    int co = i / CIK, r = i - co * CIK;
    wT[(size_t)r * CO + co] = w[i];
}

// interleaved-by-4 layout for stage1b: w4[(r>>2)*CO*4 + co*4 + (r&3)]
__global__ __launch_bounds__(256) void transpose_w4_kernel(
    const float* __restrict__ w, float* __restrict__ w4, int CO, int CIK)
{
    int i = blockIdx.x * 256 + threadIdx.x;
    if (i >= CO * CIK) return;
    int co = i / CIK, r = i - co * CIK;
    w4[(((size_t)(r >> 2) * CO) + co) * 4 + (r & 3)] = w[i];
}

// ---------------- maxpool k3 s2 p1 (down_mask) ----------------
template<int DIN, int DOUT>
__global__ __launch_bounds__(256) void maxpool_kernel(
    const float* __restrict__ in, float* __restrict__ out)
{
    int i = blockIdx.x * 256 + threadIdx.x;
    constexpr int D3O = DOUT * DOUT * DOUT;
    if (i >= 2 * D3O) return;
    int b = i / D3O;
    int v = i - b * D3O;
    int z = v / (DOUT * DOUT), y = (v / DOUT) % DOUT, x = v % DOUT;
    float mx = 0.f;
    #pragma unroll
    for (int dz = 0; dz < 3; ++dz)
        #pragma unroll
        for (int dy = 0; dy < 3; ++dy)
            #pragma unroll
            for (int dx = 0; dx < 3; ++dx) {
                int zi = 2 * z - 1 + dz, yi = 2 * y - 1 + dy, xi = 2 * x - 1 + dx;
                if ((unsigned)zi < (unsigned)DIN && (unsigned)yi < (unsigned)DIN &&
                    (unsigned)xi < (unsigned)DIN)
                    mx = fmaxf(mx, in[(size_t)b * DIN * DIN * DIN + (zi * DIN + yi) * DIN + xi]);
            }
    out[i] = mx;
}

// ---------------- active-voxel list + dense index map ----------------
__global__ __launch_bounds__(256) void build_list_kernel(
    const float* __restrict__ m, int* __restrict__ list, int* __restrict__ idxmap,
    int* __restrict__ count)
{
    int i = blockIdx.x * 256 + threadIdx.x;
    if (i >= 2 * 262144) return;
    if (m[i] > 0.5f) {
        int k = atomicAdd(count, 1);
        if (k < ROWCAP) {           // ~26k expected at 5%; cap guards OOB
            list[k] = i;
            idxmap[i] = k;
        }
    }
}

// ---------------- stage1 conv-a (3->64, gathered) -> t1c[row][64] ----------------
__global__ __launch_bounds__(64) void stage1a_kernel(
    const float* __restrict__ x, const float* __restrict__ waT,  // [81][64]
    const int* __restrict__ list, const int* __restrict__ count,
    float* __restrict__ t1c)
{
    __shared__ float smem[81];
    int n = min(*count, ROWCAP);
    for (int i = blockIdx.x; i < n; i += gridDim.x) {
        int lin = list[i];
        int b = lin >> 18;
        int v = lin & 262143;
        int z = v >> 12, y = (v >> 6) & 63, xx = v & 63;
        for (int j = threadIdx.x; j < 81; j += 64) {
            int ci = j / 27, t = j - ci * 27;
            int zz = z + t / 9 - 1, yy = y + (t / 3) % 3 - 1, xc = xx + t % 3 - 1;
            float val = 0.f;
            if ((unsigned)zz < 64u && (unsigned)yy < 64u && (unsigned)xc < 64u)
                val = x[(size_t)(b * 3 + ci) * 262144 + (zz << 12) + (yy << 6) + xc];
            smem[j] = val;
        }
        __syncthreads();
        float acc = 0.f;
        #pragma unroll 9
        for (int j = 0; j < 81; ++j)
            acc = fmaf(smem[j], waT[j * 64 + threadIdx.x], acc);
        t1c[(size_t)i * 64 + threadIdx.x] = leaky(acc);
        __syncthreads();
    }
}

// ---------------- stage1 conv-b (64->64, gathered via idxmap) + 1x1 identity ----------------
__global__ __launch_bounds__(64) void stage1b_kernel(
    const float* __restrict__ t1c, const float* __restrict__ x,
    const float* __restrict__ wb4,  // [(1728/4)][64][4]
    const float* __restrict__ wdT,  // [3][64]
    const int* __restrict__ list, const int* __restrict__ idxmap,
    const int* __restrict__ count,
    float* __restrict__ x1c)
{
    __shared__ float sw[4 * 1728];
    int n = min(*count, ROWCAP);
    int nq = (n + 3) >> 2;
    for (int q = blockIdx.x; q < nq; q += gridDim.x) {
        for (int vv = 0; vv < 4; ++vv) {
            int i = q * 4 + vv;
            int lin = (i < n) ? list[i] : list[0];
            int b = lin >> 18;
            int v = lin & 262143;
            int z = v >> 12, y = (v >> 6) & 63, xx = v & 63;
            const int* im = idxmap + b * 262144;
            #pragma unroll
            for (int t = 0; t < 27; ++t) {
                int zz = z + t / 9 - 1, yy = y + (t / 3) % 3 - 1, xc = xx + t % 3 - 1;
                float val = 0.f;
                if ((unsigned)zz < 64u && (unsigned)yy < 64u && (unsigned)xc < 64u) {
                    int r = im[(zz << 12) + (yy << 6) + xc];
                    if (r >= 0)
                        val = t1c[(size_t)r * 64 + threadIdx.x];
                }
                sw[vv * 1728 + threadIdx.x * 27 + t] = val;
            }
        }
        __syncthreads();
        float acc[4] = {0.f, 0.f, 0.f, 0.f};
        const float* wp = wb4 + threadIdx.x * 4;
        for (int j4 = 0; j4 < 432; ++j4) {
            float4 w = *(const float4*)(wp + (size_t)j4 * 256);
            #pragma unroll
            for (int vv = 0; vv < 4; ++vv) {
                float4 s = *(const float4*)(&sw[vv * 1728 + j4 * 4]);
                acc[vv] = fmaf(s.x, w.x, acc[vv]);
                acc[vv] = fmaf(s.y, w.y, acc[vv]);
                acc[vv] = fmaf(s.z, w.z, acc[vv]);
                acc[vv] = fmaf(s.w, w.w, acc[vv]);
            }
        }
        #pragma unroll
        for (int vv = 0; vv < 4; ++vv) {
            int i = q * 4 + vv;
            if (i < n) {
                int lin = list[i];
                int b = lin >> 18;
                int v = lin & 262143;
                float id = 0.f;
                #pragma unroll
                for (int ci = 0; ci < 3; ++ci)
                    id = fmaf(x[(size_t)(b * 3 + ci) * 262144 + v], wdT[ci * 64 + threadIdx.x], id);
                x1c[(size_t)i * 64 + threadIdx.x] = leaky(acc[vv] + id);
            }
        }
        __syncthreads();
    }
}

// ---------------- wd1: gather-conv 64ch 64^3 -> 128ch 32^3, stride 2, leaky --------
template<int CO_T>
__global__ __launch_bounds__(256) void wd1_kernel(
    const float* __restrict__ x1c, const int* __restrict__ idxmap,
    const float* __restrict__ wT,   // [64*27][128]
    float* __restrict__ out)        // [2][128][32768]
{
    int v = blockIdx.x * 256 + threadIdx.x;   // 0..32767
    int b = blockIdx.z;
    int cog = blockIdx.y * CO_T;
    int zo = v >> 10, yo = (v >> 5) & 31, xo = v & 31;
    float acc[CO_T];
    #pragma unroll
    for (int j = 0; j < CO_T; ++j) acc[j] = 0.f;
    const int* im = idxmap + b * 262144;

    #pragma unroll
    for (int kz = 0; kz < 3; ++kz) {
        int zi = 2 * zo - 1 + kz;
        #pragma unroll
        for (int ky = 0; ky < 3; ++ky) {
            int yi = 2 * yo - 1 + ky;
            #pragma unroll
            for (int kx = 0; kx < 3; ++kx) {
                int xi = 2 * xo - 1 + kx;
                int r = -1;
                if ((unsigned)zi < 64u && (unsigned)yi < 64u && (unsigned)xi < 64u)
                    r = im[(zi << 12) + (yi << 6) + xi];
                if (r >= 0) {
                    const float* xr = x1c + (size_t)r * 64;
                    int tap = kz * 9 + ky * 3 + kx;
                    for (int ci = 0; ci < 64; ci += 4) {
                        float4 xv = *(const float4*)(xr + ci);
                        const float* w0 = wT + (size_t)((ci + 0) * 27 + tap) * 128 + cog;
                        const float* w1 = wT + (size_t)((ci + 1) * 27 + tap) * 128 + cog;
                        const float* w2 = wT + (size_t)((ci + 2) * 27 + tap) * 128 + cog;
                        const float* w3 = wT + (size_t)((ci + 3) * 27 + tap) * 128 + cog;
                        #pragma unroll
                        for (int j = 0; j < CO_T; ++j) {
                            acc[j] = fmaf(xv.x, w0[j], acc[j]);
                            acc[j] = fmaf(xv.y, w1[j], acc[j]);
                            acc[j] = fmaf(xv.z, w2[j], acc[j]);
                            acc[j] = fmaf(xv.w, w3[j], acc[j]);
                        }
                    }
                }
            }
        }
    }
    #pragma unroll
    for (int j = 0; j < CO_T; ++j)
        out[((size_t)(b * 128 + cog + j)) * 32768 + v] = leaky(acc[j]);
}

// ---------------- dense direct conv k3 p1, optional stride 2, fused epilogue ----------------
template<int CI, int CO, int CO_T, int DIN, int DOUT, int STRIDE, int EPI>
__global__ __launch_bounds__(256) void conv3x3_kernel(
    const float* __restrict__ in,   // [B][CI][DIN^3]
    const float* __restrict__ wT,   // [CI*27][CO]
    const float* __restrict__ mask, // [B][DOUT^3]
    const float* __restrict__ resid,// [B][CO][DOUT^3]
    float* __restrict__ out)        // [B][CO][DOUT^3]
{
    constexpr int D3O = DOUT * DOUT * DOUT;
    constexpr int D3I = DIN * DIN * DIN;
    int v = blockIdx.x * 256 + threadIdx.x;
    int b = blockIdx.z;
    int cog = blockIdx.y * CO_T;
    int xo = v % DOUT;
    int yo = (v / DOUT) % DOUT;
    int zo = v / (DOUT * DOUT);
    float acc[CO_T];
    #pragma unroll
    for (int j = 0; j < CO_T; ++j) acc[j] = 0.f;

    const float* inb = in + (size_t)b * CI * D3I;
    int zb = zo * STRIDE - 1, yb = yo * STRIDE - 1, xb = xo * STRIDE - 1;

    for (int ci = 0; ci < CI; ++ci) {
        const float* inc = inb + (size_t)ci * D3I;
        #pragma unroll
        for (int kz = 0; kz < 3; ++kz) {
            int zi = zb + kz;
            #pragma unroll
            for (int ky = 0; ky < 3; ++ky) {
                int yi = yb + ky;
                float iv[3];
                #pragma unroll
                for (int kx = 0; kx < 3; ++kx) {
                    int xi = xb + kx;
                    bool ok = ((unsigned)zi < (unsigned)DIN) & ((unsigned)yi < (unsigned)DIN) &
                              ((unsigned)xi < (unsigned)DIN);
                    iv[kx] = ok ? inc[(zi * DIN + yi) * DIN + xi] : 0.f;
                }
                const float* wp = wT + (size_t)((ci * 9 + kz * 3 + ky) * 3) * CO + cog;
                #pragma unroll
                for (int kx = 0; kx < 3; ++kx)
                    #pragma unroll
                    for (int j = 0; j < CO_T; ++j)
                        acc[j] = fmaf(iv[kx], wp[kx * CO + j], acc[j]);
            }
        }
    }

    float m = 1.f;
    if (EPI & EPI_MASK) m = mask[(size_t)b * D3O + v];
    #pragma unroll
    for (int j = 0; j < CO_T; ++j) {
        float val = acc[j];
        if (EPI & EPI_MASK) val *= m;
        if (EPI & EPI_RESID) val += resid[((size_t)(b * CO + cog + j)) * D3O + v];
        if (EPI & EPI_LEAKY) val = leaky(val);
        out[((size_t)(b * CO + cog + j)) * D3O + v] = val;
    }
}

// ---------------- final mean/max pool over 8^3 ----------------
__global__ __launch_bounds__(64) void reduce_kernel(
    const float* __restrict__ x4, float* __restrict__ out)
{
    int bc = blockIdx.x;
    int b = bc >> 7, c = bc & 127;
    const float* p = x4 + (size_t)(b * 128 + c) * 512;
    float s = 0.f, mx = -3.4e38f;
    for (int i = threadIdx.x; i < 512; i += 64) {
        float v = p[i];
        s += v;
        mx = fmaxf(mx, v);
    }
    #pragma unroll
    for (int o = 32; o > 0; o >>= 1) {
        s += __shfl_down(s, o);
        mx = fmaxf(mx, __shfl_down(mx, o));
    }
    if (threadIdx.x == 0) {
        out[b * 256 + c] = s * (1.f / 512.f);
        out[b * 256 + 128 + c] = mx;
    }
}

// fallback: clean deterministic fail if workspace too small (diagnostic)
__global__ __launch_bounds__(256) void zero_out_kernel(float* __restrict__ out, int n)
{
    int i = blockIdx.x * 256 + threadIdx.x;
    if (i < n) out[i] = 0.f;
}

// ---------------------------------------------------------------------------
extern "C" void kernel_launch(void* const* d_in, const int* in_sizes, int n_in,
                              void* d_out, int out_size, void* d_ws, size_t ws_size,
                              hipStream_t stream)
{
    (void)in_sizes; (void)n_in;
    const float* x    = (const float*)d_in[0];
    const float* mask = (const float*)d_in[1];
    const float* w1a  = (const float*)d_in[2];
    const float* w1b  = (const float*)d_in[3];
    const float* w1d  = (const float*)d_in[4];
    const float* wd1  = (const float*)d_in[5];
    const float* w2a  = (const float*)d_in[6];
    const float* w2b  = (const float*)d_in[7];
    const float* wd2  = (const float*)d_in[8];
    const float* w3a  = (const float*)d_in[9];
    const float* w3b  = (const float*)d_in[10];
    const float* wd3  = (const float*)d_in[11];
    float* out = (float*)d_out;
    float* ws = (float*)d_ws;

    const size_t NEED_BYTES = 31769872ull * 4ull;  // 127,079,488
    if (ws_size < NEED_BYTES) {
        // workspace too small: clean fail (absmax ~= ref magnitude), no fault
        zero_out_kernel<<<dim3((out_size + 255) / 256), 256, 0, stream>>>(out, out_size);
        return;
    }

    // region bases (floats)
    const size_t SZ  = 8388608;           // one stage-2 tensor [2][128][32768]
    float* A    = ws;                      // xin2 -> xin3 -> x4
    float* Bb   = ws + SZ;                 // x1c -> t2 -> t3
    float* C    = ws + 2 * SZ;             // t1c/idx/list -> x2 -> x3
    float* x1c  = Bb;                      // [ROWCAP][64] = 2,097,152
    float* t1c  = C;                       // [ROWCAP][64] = 2,097,152
    int*   idx  = (int*)(C + 2097152);     // [524288]
    int*   list = (int*)(C + 2621440);     // [131072]
    size_t off = 3 * SZ;
    auto alloc = [&](size_t n) { float* p = ws + off; off += (n + 63) & ~63ull; return p; };
    float* waT  = alloc(81 * 64);
    float* wb4  = alloc(1728 * 64);
    float* wdTt = alloc(3 * 64);
    float* wd1T = alloc(1728 * 128);
    float* w2aT = alloc(3456 * 128);
    float* w2bT = alloc(3456 * 128);
    float* wd2T = alloc(3456 * 256);
    float* w3aT = alloc(6912 * 256);
    float* w3bT = alloc(6912 * 256);
    float* wd3T = alloc(6912 * 128);
    float* m2   = alloc(2 * 32768);
    float* m3   = alloc(2 * 4096);
    int*   cnt  = (int*)alloc(16);

    hipMemsetAsync(cnt, 0, 4, stream);
    hipMemsetAsync(idx, 0xFF, 524288 * 4, stream);   // idxmap = -1

    auto tg = [](int n) { return dim3((n + 255) / 256); };
    transpose_w_kernel <<<tg(64 * 81),    256, 0, stream>>>(w1a, waT,  64, 81);
    transpose_w4_kernel<<<tg(64 * 1728),  256, 0, stream>>>(w1b, wb4,  64, 1728);
    transpose_w_kernel <<<tg(64 * 3),     256, 0, stream>>>(w1d, wdTt, 64, 3);
    transpose_w_kernel <<<tg(128 * 1728), 256, 0, stream>>>(wd1, wd1T, 128, 1728);
    transpose_w_kernel <<<tg(128 * 3456), 256, 0, stream>>>(w2a, w2aT, 128, 3456);
    transpose_w_kernel <<<tg(128 * 3456), 256, 0, stream>>>(w2b, w2bT, 128, 3456);
    transpose_w_kernel <<<tg(256 * 3456), 256, 0, stream>>>(wd2, wd2T, 256, 3456);
    transpose_w_kernel <<<tg(256 * 6912), 256, 0, stream>>>(w3a, w3aT, 256, 6912);
    transpose_w_kernel <<<tg(256 * 6912), 256, 0, stream>>>(w3b, w3bT, 256, 6912);
    transpose_w_kernel <<<tg(128 * 6912), 256, 0, stream>>>(wd3, wd3T, 128, 6912);

    maxpool_kernel<64, 32><<<dim3(2 * 32768 / 256), 256, 0, stream>>>(mask, m2);
    maxpool_kernel<32, 16><<<dim3(2 * 4096 / 256),  256, 0, stream>>>(m2, m3);
    build_list_kernel<<<dim3(2 * 262144 / 256), 256, 0, stream>>>(mask, list, idx, cnt);

    stage1a_kernel<<<dim3(2048), 64, 0, stream>>>(x, waT, list, cnt, t1c);
    stage1b_kernel<<<dim3(2048), 64, 0, stream>>>(t1c, x, wb4, wdTt, list, idx, cnt, x1c);

    // wd1: gather from compacted x1 -> dense [2][128][32^3], leaky
    wd1_kernel<16><<<dim3(128, 8, 2), 256, 0, stream>>>(x1c, idx, wd1T, A);
    // stage2 res block (xin2=A, t2=B, x2=C)
    conv3x3_kernel<128, 128, 16, 32, 32, 1, EPI_MASK | EPI_LEAKY>
        <<<dim3(128, 8, 2), 256, 0, stream>>>(A, w2aT, m2, nullptr, Bb);
    conv3x3_kernel<128, 128, 16, 32, 32, 1, EPI_MASK | EPI_RESID | EPI_LEAKY>
        <<<dim3(128, 8, 2), 256, 0, stream>>>(Bb, w2bT, m2, A, C);
    // wd2: 128ch 32^3 -> 256ch 16^3, stride 2, leaky   (xin3 = A)
    conv3x3_kernel<128, 256, 16, 32, 16, 2, EPI_LEAKY>
        <<<dim3(16, 16, 2), 256, 0, stream>>>(C, wd2T, nullptr, nullptr, A);
    // stage3 res block (t3 = B, x3 = C)
    conv3x3_kernel<256, 256, 8, 16, 16, 1, EPI_MASK | EPI_LEAKY>
        <<<dim3(16, 32, 2), 256, 0, stream>>>(A, w3aT, m3, nullptr, Bb);
    conv3x3_kernel<256, 256, 8, 16, 16, 1, EPI_MASK | EPI_RESID | EPI_LEAKY>
        <<<dim3(16, 32, 2), 256, 0, stream>>>(Bb, w3bT, m3, A, C);
    // wd3: 256ch 16^3 -> 128ch 8^3, stride 2, leaky   (x4 = A; xin3 dead)
    conv3x3_kernel<256, 128, 8, 16, 8, 2, EPI_LEAKY>
        <<<dim3(2, 16, 2), 256, 0, stream>>>(C, wd3T, nullptr, nullptr, A);

    reduce_kernel<<<dim3(256), 64, 0, stream>>>(A, out);
}

// Round 3
// 7181.371 us; speedup vs baseline: 1.4647x; 1.4647x over previous
//
#include <hip/hip_runtime.h>

// ---------------------------------------------------------------------------
// SparseEncoderResUNet on MI355X — round 3: register-tiled fp32 direct conv.
// Round-2 diagnosis: dense convs at 23.6 TF, VALU-issue-bound on unvectorized
// per-lane weight loads (~23% FMA density). Fix: VX voxels x 8 co per thread,
// explicit float4 weight/input loads (alignment by construction), split-K wd3.
// Workspace footprint unchanged: 127.08 MB.
// ---------------------------------------------------------------------------

enum { EPI_MASK = 1, EPI_LEAKY = 2, EPI_RESID = 4 };
#define ROWCAP 32768

__device__ __forceinline__ float leaky(float v) { return v >= 0.f ? v : 0.2f * v; }

// ---------------- weight transpose: w[co][cik] -> wT[cik][co] ----------------
__global__ __launch_bounds__(256) void transpose_w_kernel(
    const float* __restrict__ w, float* __restrict__ wT, int CO, int CIK)
{
    int i = blockIdx.x * 256 + threadIdx.x;
    if (i >= CO * CIK) return;
    int co = i / CIK, r = i - co * CIK;
    wT[(size_t)r * CO + co] = w[i];
}

// interleaved-by-4 layout for stage1b: w4[(r>>2)*CO*4 + co*4 + (r&3)]
__global__ __launch_bounds__(256) void transpose_w4_kernel(
    const float* __restrict__ w, float* __restrict__ w4, int CO, int CIK)
{
    int i = blockIdx.x * 256 + threadIdx.x;
    if (i >= CO * CIK) return;
    int co = i / CIK, r = i - co * CIK;
    w4[(((size_t)(r >> 2) * CO) + co) * 4 + (r & 3)] = w[i];
}

// ---------------- maxpool k3 s2 p1 (down_mask) ----------------
template<int DIN, int DOUT>
__global__ __launch_bounds__(256) void maxpool_kernel(
    const float* __restrict__ in, float* __restrict__ out)
{
    int i = blockIdx.x * 256 + threadIdx.x;
    constexpr int D3O = DOUT * DOUT * DOUT;
    if (i >= 2 * D3O) return;
    int b = i / D3O;
    int v = i - b * D3O;
    int z = v / (DOUT * DOUT), y = (v / DOUT) % DOUT, x = v % DOUT;
    float mx = 0.f;
    #pragma unroll
    for (int dz = 0; dz < 3; ++dz)
        #pragma unroll
        for (int dy = 0; dy < 3; ++dy)
            #pragma unroll
            for (int dx = 0; dx < 3; ++dx) {
                int zi = 2 * z - 1 + dz, yi = 2 * y - 1 + dy, xi = 2 * x - 1 + dx;
                if ((unsigned)zi < (unsigned)DIN && (unsigned)yi < (unsigned)DIN &&
                    (unsigned)xi < (unsigned)DIN)
                    mx = fmaxf(mx, in[(size_t)b * DIN * DIN * DIN + (zi * DIN + yi) * DIN + xi]);
            }
    out[i] = mx;
}

// ---------------- active-voxel list + dense index map ----------------
__global__ __launch_bounds__(256) void build_list_kernel(
    const float* __restrict__ m, int* __restrict__ list, int* __restrict__ idxmap,
    int* __restrict__ count)
{
    int i = blockIdx.x * 256 + threadIdx.x;
    if (i >= 2 * 262144) return;
    if (m[i] > 0.5f) {
        int k = atomicAdd(count, 1);
        if (k < ROWCAP) {
            list[k] = i;
            idxmap[i] = k;
        }
    }
}

// ---------------- stage1 conv-a (3->64, gathered) -> t1c[row][64] ----------------
__global__ __launch_bounds__(64) void stage1a_kernel(
    const float* __restrict__ x, const float* __restrict__ waT,  // [81][64]
    const int* __restrict__ list, const int* __restrict__ count,
    float* __restrict__ t1c)
{
    __shared__ float smem[81];
    int n = min(*count, ROWCAP);
    for (int i = blockIdx.x; i < n; i += gridDim.x) {
        int lin = list[i];
        int b = lin >> 18;
        int v = lin & 262143;
        int z = v >> 12, y = (v >> 6) & 63, xx = v & 63;
        for (int j = threadIdx.x; j < 81; j += 64) {
            int ci = j / 27, t = j - ci * 27;
            int zz = z + t / 9 - 1, yy = y + (t / 3) % 3 - 1, xc = xx + t % 3 - 1;
            float val = 0.f;
            if ((unsigned)zz < 64u && (unsigned)yy < 64u && (unsigned)xc < 64u)
                val = x[(size_t)(b * 3 + ci) * 262144 + (zz << 12) + (yy << 6) + xc];
            smem[j] = val;
        }
        __syncthreads();
        float acc = 0.f;
        #pragma unroll 9
        for (int j = 0; j < 81; ++j)
            acc = fmaf(smem[j], waT[j * 64 + threadIdx.x], acc);
        t1c[(size_t)i * 64 + threadIdx.x] = leaky(acc);
        __syncthreads();
    }
}

// ---------------- stage1 conv-b (64->64, gathered via idxmap) + 1x1 identity ----------------
__global__ __launch_bounds__(64) void stage1b_kernel(
    const float* __restrict__ t1c, const float* __restrict__ x,
    const float* __restrict__ wb4,  // [(1728/4)][64][4]
    const float* __restrict__ wdT,  // [3][64]
    const int* __restrict__ list, const int* __restrict__ idxmap,
    const int* __restrict__ count,
    float* __restrict__ x1c)
{
    __shared__ float sw[4 * 1728];
    int n = min(*count, ROWCAP);
    int nq = (n + 3) >> 2;
    for (int q = blockIdx.x; q < nq; q += gridDim.x) {
        for (int vv = 0; vv < 4; ++vv) {
            int i = q * 4 + vv;
            int lin = (i < n) ? list[i] : list[0];
            int b = lin >> 18;
            int v = lin & 262143;
            int z = v >> 12, y = (v >> 6) & 63, xx = v & 63;
            const int* im = idxmap + b * 262144;
            #pragma unroll
            for (int t = 0; t < 27; ++t) {
                int zz = z + t / 9 - 1, yy = y + (t / 3) % 3 - 1, xc = xx + t % 3 - 1;
                float val = 0.f;
                if ((unsigned)zz < 64u && (unsigned)yy < 64u && (unsigned)xc < 64u) {
                    int r = im[(zz << 12) + (yy << 6) + xc];
                    if (r >= 0)
                        val = t1c[(size_t)r * 64 + threadIdx.x];
                }
                sw[vv * 1728 + threadIdx.x * 27 + t] = val;
            }
        }
        __syncthreads();
        float acc[4] = {0.f, 0.f, 0.f, 0.f};
        const float* wp = wb4 + threadIdx.x * 4;
        for (int j4 = 0; j4 < 432; ++j4) {
            float4 w = *(const float4*)(wp + (size_t)j4 * 256);
            #pragma unroll
            for (int vv = 0; vv < 4; ++vv) {
                float4 s = *(const float4*)(&sw[vv * 1728 + j4 * 4]);
                acc[vv] = fmaf(s.x, w.x, acc[vv]);
                acc[vv] = fmaf(s.y, w.y, acc[vv]);
                acc[vv] = fmaf(s.z, w.z, acc[vv]);
                acc[vv] = fmaf(s.w, w.w, acc[vv]);
            }
        }
        #pragma unroll
        for (int vv = 0; vv < 4; ++vv) {
            int i = q * 4 + vv;
            if (i < n) {
                int lin = list[i];
                int b = lin >> 18;
                int v = lin & 262143;
                float id = 0.f;
                #pragma unroll
                for (int ci = 0; ci < 3; ++ci)
                    id = fmaf(x[(size_t)(b * 3 + ci) * 262144 + v], wdT[ci * 64 + threadIdx.x], id);
                x1c[(size_t)i * 64 + threadIdx.x] = leaky(acc[vv] + id);
            }
        }
        __syncthreads();
    }
}

// ---------------- wd1: gather-conv 64ch 64^3 -> 128ch 32^3, stride 2, leaky --------
template<int CO_T>
__global__ __launch_bounds__(256) void wd1_kernel(
    const float* __restrict__ x1c, const int* __restrict__ idxmap,
    const float* __restrict__ wT,   // [64*27][128]
    float* __restrict__ out)        // [2][128][32768]
{
    int v = blockIdx.x * 256 + threadIdx.x;
    int b = blockIdx.z;
    int cog = blockIdx.y * CO_T;
    int zo = v >> 10, yo = (v >> 5) & 31, xo = v & 31;
    float acc[CO_T];
    #pragma unroll
    for (int j = 0; j < CO_T; ++j) acc[j] = 0.f;
    const int* im = idxmap + b * 262144;

    #pragma unroll
    for (int kz = 0; kz < 3; ++kz) {
        int zi = 2 * zo - 1 + kz;
        #pragma unroll
        for (int ky = 0; ky < 3; ++ky) {
            int yi = 2 * yo - 1 + ky;
            #pragma unroll
            for (int kx = 0; kx < 3; ++kx) {
                int xi = 2 * xo - 1 + kx;
                int r = -1;
                if ((unsigned)zi < 64u && (unsigned)yi < 64u && (unsigned)xi < 64u)
                    r = im[(zi << 12) + (yi << 6) + xi];
                if (r >= 0) {
                    const float* xr = x1c + (size_t)r * 64;
                    int tap = kz * 9 + ky * 3 + kx;
                    for (int ci = 0; ci < 64; ci += 4) {
                        float4 xv = *(const float4*)(xr + ci);
                        const float4* w0 = (const float4*)(wT + (size_t)((ci + 0) * 27 + tap) * 128 + cog);
                        const float4* w1 = (const float4*)(wT + (size_t)((ci + 1) * 27 + tap) * 128 + cog);
                        const float4* w2 = (const float4*)(wT + (size_t)((ci + 2) * 27 + tap) * 128 + cog);
                        const float4* w3 = (const float4*)(wT + (size_t)((ci + 3) * 27 + tap) * 128 + cog);
                        #pragma unroll
                        for (int j4 = 0; j4 < CO_T / 4; ++j4) {
                            float4 a0 = w0[j4], a1 = w1[j4], a2 = w2[j4], a3 = w3[j4];
                            float* ac = &acc[j4 * 4];
                            ac[0] = fmaf(xv.x, a0.x, ac[0]); ac[1] = fmaf(xv.x, a0.y, ac[1]);
                            ac[2] = fmaf(xv.x, a0.z, ac[2]); ac[3] = fmaf(xv.x, a0.w, ac[3]);
                            ac[0] = fmaf(xv.y, a1.x, ac[0]); ac[1] = fmaf(xv.y, a1.y, ac[1]);
                            ac[2] = fmaf(xv.y, a1.z, ac[2]); ac[3] = fmaf(xv.y, a1.w, ac[3]);
                            ac[0] = fmaf(xv.z, a2.x, ac[0]); ac[1] = fmaf(xv.z, a2.y, ac[1]);
                            ac[2] = fmaf(xv.z, a2.z, ac[2]); ac[3] = fmaf(xv.z, a2.w, ac[3]);
                            ac[0] = fmaf(xv.w, a3.x, ac[0]); ac[1] = fmaf(xv.w, a3.y, ac[1]);
                            ac[2] = fmaf(xv.w, a3.z, ac[2]); ac[3] = fmaf(xv.w, a3.w, ac[3]);
                        }
                    }
                }
            }
        }
    }
    #pragma unroll
    for (int j = 0; j < CO_T; ++j)
        out[((size_t)(b * 128 + cog + j)) * 32768 + v] = leaky(acc[j]);
}

// ---------------- register-tiled dense conv k3 p1 (VX voxels x CO_T ch / thread) ---
// KS>1: split-K over ci chunks, raw partials to out[kc][B][CO][D3O], no epilogue.
template<int CI, int CO, int CO_T, int VX, int DIN, int DOUT, int STRIDE, int EPI, int KS>
__global__ __launch_bounds__(256) void conv_v2_kernel(
    const float* __restrict__ in,   // [B][CI][DIN^3]
    const float* __restrict__ wT,   // [CI*27][CO]
    const float* __restrict__ mask, // [B][DOUT^3]
    const float* __restrict__ resid,// [B][CO][DOUT^3]
    float* __restrict__ out)
{
    constexpr int D3O = DOUT * DOUT * DOUT;
    constexpr int D3I = DIN * DIN * DIN;
    constexpr int NIV = (STRIDE == 1) ? VX + 2 : 2 * VX + 1;  // input taps along x
    constexpr int NCOG = CO / CO_T;
    constexpr int CICH = CI / KS;

    int g = blockIdx.x * 256 + threadIdx.x;
    if (g * VX >= D3O) return;
    int b = blockIdx.z;
    int cog = (blockIdx.y % NCOG) * CO_T;
    int kc = blockIdx.y / NCOG;

    int v0 = g * VX;
    int x0 = v0 % DOUT;                  // multiple of VX
    int yo = (v0 / DOUT) % DOUT;
    int zo = v0 / (DOUT * DOUT);
    int zb = zo * STRIDE - 1, yb = yo * STRIDE - 1;
    int xb = x0 * STRIDE;                // iv[j] = input x = xb - 1 + j

    float acc[VX][CO_T] = {};

    const float* inb = in + ((size_t)b * CI + kc * CICH) * D3I
                          + ((size_t)(zb + 0) * DIN + yb) * DIN + xb;  // tap(0,0) base
    const float* wci = wT + (size_t)(kc * CICH) * 27 * CO + cog;

    for (int ci = 0; ci < CICH; ++ci) {
        #pragma unroll
        for (int kz = 0; kz < 3; ++kz) {
            int zi = zb + kz;
            bool zok = (unsigned)zi < (unsigned)DIN;
            #pragma unroll
            for (int ky = 0; ky < 3; ++ky) {
                int yi = yb + ky;
                bool ok = zok & ((unsigned)yi < (unsigned)DIN);
                float iv[NIV];
                #pragma unroll
                for (int j = 0; j < NIV; ++j) iv[j] = 0.f;
                const float* rp = inb + (kz * DIN + ky) * DIN;  // input x = xb
                if (ok) {
                    if (STRIDE == 1) {
                        if (VX == 4) {
                            float4 t = *(const float4*)rp;
                            iv[1] = t.x; iv[2] = t.y; iv[3] = t.z; iv[4] = t.w;
                        } else {
                            float2 t = *(const float2*)rp;
                            iv[1] = t.x; iv[2] = t.y;
                        }
                        if (x0 > 0) iv[0] = rp[-1];
                        if (x0 + VX < DIN) iv[NIV - 1] = rp[VX];
                    } else {
                        #pragma unroll
                        for (int j = 0; j < 2 * VX; j += 4) {
                            float4 t = *(const float4*)(rp + j);
                            iv[1 + j] = t.x; iv[2 + j] = t.y; iv[3 + j] = t.z; iv[4 + j] = t.w;
                        }
                        if (x0 > 0) iv[0] = rp[-1];
                    }
                }
                #pragma unroll
                for (int kx = 0; kx < 3; ++kx) {
                    float w[CO_T];
                    const float4* wp = (const float4*)(wci + (size_t)((kz * 3 + ky) * 3 + kx) * CO);
                    #pragma unroll
                    for (int j4 = 0; j4 < CO_T / 4; ++j4)
                        *(float4*)&w[j4 * 4] = wp[j4];
                    #pragma unroll
                    for (int vx = 0; vx < VX; ++vx) {
                        float xv = iv[vx * STRIDE + kx];
                        #pragma unroll
                        for (int j = 0; j < CO_T; ++j)
                            acc[vx][j] = fmaf(xv, w[j], acc[vx][j]);
                    }
                }
            }
        }
        inb += D3I;
        wci += 27 * CO;
    }

    if (KS > 1) out += (size_t)kc * 2 * CO * D3O;   // raw partial
    float m[VX];
    if (EPI & EPI_MASK) {
        #pragma unroll
        for (int vx = 0; vx < VX; ++vx) m[vx] = mask[(size_t)b * D3O + v0 + vx];
    }
    #pragma unroll
    for (int j = 0; j < CO_T; ++j) {
        float o[VX];
        const size_t obase = ((size_t)(b * CO + cog + j)) * D3O + v0;
        #pragma unroll
        for (int vx = 0; vx < VX; ++vx) {
            float val = acc[vx][j];
            if (EPI & EPI_MASK) val *= m[vx];
            if (EPI & EPI_RESID) val += resid[obase + vx];
            if (EPI & EPI_LEAKY) val = leaky(val);
            o[vx] = val;
        }
        if (VX == 4)
            *(float4*)(out + obase) = make_float4(o[0], o[1], o[2], o[3]);
        else if (VX == 2)
            *(float2*)(out + obase) = make_float2(o[0], o[1]);
        else
            out[obase] = o[0];
    }
}

// ---------------- final: sum 8 wd3 partials + leaky + mean/max pool over 8^3 -------
__global__ __launch_bounds__(64) void reduce_kernel(
    const float* __restrict__ part,   // [8][2][128][512]
    float* __restrict__ out)
{
    int bc = blockIdx.x;
    int b = bc >> 7, c = bc & 127;
    const float* p = part + (size_t)(b * 128 + c) * 512;
    float s = 0.f, mx = -3.4e38f;
    for (int i = threadIdx.x; i < 512; i += 64) {
        float v = 0.f;
        #pragma unroll
        for (int k = 0; k < 8; ++k) v += p[(size_t)k * 131072 + i];
        v = leaky(v);
        s += v;
        mx = fmaxf(mx, v);
    }
    #pragma unroll
    for (int o = 32; o > 0; o >>= 1) {
        s += __shfl_down(s, o);
        mx = fmaxf(mx, __shfl_down(mx, o));
    }
    if (threadIdx.x == 0) {
        out[b * 256 + c] = s * (1.f / 512.f);
        out[b * 256 + 128 + c] = mx;
    }
}

// fallback: clean deterministic fail if workspace too small (diagnostic)
__global__ __launch_bounds__(256) void zero_out_kernel(float* __restrict__ out, int n)
{
    int i = blockIdx.x * 256 + threadIdx.x;
    if (i < n) out[i] = 0.f;
}

// ---------------------------------------------------------------------------
extern "C" void kernel_launch(void* const* d_in, const int* in_sizes, int n_in,
                              void* d_out, int out_size, void* d_ws, size_t ws_size,
                              hipStream_t stream)
{
    (void)in_sizes; (void)n_in;
    const float* x    = (const float*)d_in[0];
    const float* mask = (const float*)d_in[1];
    const float* w1a  = (const float*)d_in[2];
    const float* w1b  = (const float*)d_in[3];
    const float* w1d  = (const float*)d_in[4];
    const float* wd1  = (const float*)d_in[5];
    const float* w2a  = (const float*)d_in[6];
    const float* w2b  = (const float*)d_in[7];
    const float* wd2  = (const float*)d_in[8];
    const float* w3a  = (const float*)d_in[9];
    const float* w3b  = (const float*)d_in[10];
    const float* wd3  = (const float*)d_in[11];
    float* out = (float*)d_out;
    float* ws = (float*)d_ws;

    const size_t NEED_BYTES = 31769872ull * 4ull;  // 127,079,488
    if (ws_size < NEED_BYTES) {
        zero_out_kernel<<<dim3((out_size + 255) / 256), 256, 0, stream>>>(out, out_size);
        return;
    }

    // region bases (floats)
    const size_t SZ  = 8388608;           // one stage-2 tensor [2][128][32768]
    float* A    = ws;                      // xin2 -> xin3 -> wd3-partials
    float* Bb   = ws + SZ;                 // x1c -> t2 -> t3
    float* C    = ws + 2 * SZ;             // t1c/idx/list -> x2 -> x3
    float* x1c  = Bb;
    float* t1c  = C;
    int*   idx  = (int*)(C + 2097152);
    int*   list = (int*)(C + 2621440);
    size_t off = 3 * SZ;
    auto alloc = [&](size_t n) { float* p = ws + off; off += (n + 63) & ~63ull; return p; };
    float* waT  = alloc(81 * 64);
    float* wb4  = alloc(1728 * 64);
    float* wdTt = alloc(3 * 64);
    float* wd1T = alloc(1728 * 128);
    float* w2aT = alloc(3456 * 128);
    float* w2bT = alloc(3456 * 128);
    float* wd2T = alloc(3456 * 256);
    float* w3aT = alloc(6912 * 256);
    float* w3bT = alloc(6912 * 256);
    float* wd3T = alloc(6912 * 128);
    float* m2   = alloc(2 * 32768);
    float* m3   = alloc(2 * 4096);
    int*   cnt  = (int*)alloc(16);

    hipMemsetAsync(cnt, 0, 4, stream);
    hipMemsetAsync(idx, 0xFF, 524288 * 4, stream);   // idxmap = -1

    auto tg = [](int n) { return dim3((n + 255) / 256); };
    transpose_w_kernel <<<tg(64 * 81),    256, 0, stream>>>(w1a, waT,  64, 81);
    transpose_w4_kernel<<<tg(64 * 1728),  256, 0, stream>>>(w1b, wb4,  64, 1728);
    transpose_w_kernel <<<tg(64 * 3),     256, 0, stream>>>(w1d, wdTt, 64, 3);
    transpose_w_kernel <<<tg(128 * 1728), 256, 0, stream>>>(wd1, wd1T, 128, 1728);
    transpose_w_kernel <<<tg(128 * 3456), 256, 0, stream>>>(w2a, w2aT, 128, 3456);
    transpose_w_kernel <<<tg(128 * 3456), 256, 0, stream>>>(w2b, w2bT, 128, 3456);
    transpose_w_kernel <<<tg(256 * 3456), 256, 0, stream>>>(wd2, wd2T, 256, 3456);
    transpose_w_kernel <<<tg(256 * 6912), 256, 0, stream>>>(w3a, w3aT, 256, 6912);
    transpose_w_kernel <<<tg(256 * 6912), 256, 0, stream>>>(w3b, w3bT, 256, 6912);
    transpose_w_kernel <<<tg(128 * 6912), 256, 0, stream>>>(wd3, wd3T, 128, 6912);

    maxpool_kernel<64, 32><<<dim3(2 * 32768 / 256), 256, 0, stream>>>(mask, m2);
    maxpool_kernel<32, 16><<<dim3(2 * 4096 / 256),  256, 0, stream>>>(m2, m3);
    build_list_kernel<<<dim3(2 * 262144 / 256), 256, 0, stream>>>(mask, list, idx, cnt);

    stage1a_kernel<<<dim3(2048), 64, 0, stream>>>(x, waT, list, cnt, t1c);
    stage1b_kernel<<<dim3(2048), 64, 0, stream>>>(t1c, x, wb4, wdTt, list, idx, cnt, x1c);

    // wd1: gather from compacted x1 -> dense [2][128][32^3], leaky (xin2 = A)
    wd1_kernel<16><<<dim3(128, 8, 2), 256, 0, stream>>>(x1c, idx, wd1T, A);

    // stage2 res block: t2 = B, x2 = C
    conv_v2_kernel<128, 128, 8, 4, 32, 32, 1, EPI_MASK | EPI_LEAKY, 1>
        <<<dim3(32, 16, 2), 256, 0, stream>>>(A, w2aT, m2, nullptr, Bb);
    conv_v2_kernel<128, 128, 8, 4, 32, 32, 1, EPI_MASK | EPI_RESID | EPI_LEAKY, 1>
        <<<dim3(32, 16, 2), 256, 0, stream>>>(Bb, w2bT, m2, A, C);
    // wd2: 128ch 32^3 -> 256ch 16^3, stride 2, leaky (xin3 = A)
    conv_v2_kernel<128, 256, 8, 2, 32, 16, 2, EPI_LEAKY, 1>
        <<<dim3(8, 32, 2), 256, 0, stream>>>(C, wd2T, nullptr, nullptr, A);
    // stage3 res block: t3 = B, x3 = C
    conv_v2_kernel<256, 256, 8, 2, 16, 16, 1, EPI_MASK | EPI_LEAKY, 1>
        <<<dim3(8, 32, 2), 256, 0, stream>>>(A, w3aT, m3, nullptr, Bb);
    conv_v2_kernel<256, 256, 8, 2, 16, 16, 1, EPI_MASK | EPI_RESID | EPI_LEAKY, 1>
        <<<dim3(8, 32, 2), 256, 0, stream>>>(Bb, w3bT, m3, A, C);
    // wd3: split-K=8 over ci, partials -> A[8][2][128][512]
    conv_v2_kernel<256, 128, 8, 4, 16, 8, 2, 0, 8>
        <<<dim3(1, 128, 2), 256, 0, stream>>>(C, wd3T, nullptr, nullptr, A);

    // fused: sum partials + leaky + mean/max pool
    reduce_kernel<<<dim3(256), 64, 0, stream>>>(A, out);
}

// Round 4
// 5806.693 us; speedup vs baseline: 1.8115x; 1.2367x over previous
//
#include <hip/hip_runtime.h>

// ---------------------------------------------------------------------------
// SparseEncoderResUNet on MI355X — round 4: occupancy-driven retile.
// Round-3 diagnosis: convs latency-bound (VALUBusy 35%, Occupancy 23%,
// grids 2-4 blocks/CU). Fix: CO_T=4 + split-K so every dense conv launches
// ~2048 blocks (8 blocks/CU = 32 waves). Split-K partials go to dead buffer
// regions; tiny combine kernels fuse mask/resid/leaky. Footprint 127.08 MB.
// ---------------------------------------------------------------------------

enum { EPI_MASK = 1, EPI_LEAKY = 2, EPI_RESID = 4 };
#define ROWCAP 32768

__device__ __forceinline__ float leaky(float v) { return v >= 0.f ? v : 0.2f * v; }

// ---------------- weight transpose: w[co][cik] -> wT[cik][co] ----------------
__global__ __launch_bounds__(256) void transpose_w_kernel(
    const float* __restrict__ w, float* __restrict__ wT, int CO, int CIK)
{
    int i = blockIdx.x * 256 + threadIdx.x;
    if (i >= CO * CIK) return;
    int co = i / CIK, r = i - co * CIK;
    wT[(size_t)r * CO + co] = w[i];
}

// interleaved-by-4 layout for stage1b: w4[(r>>2)*CO*4 + co*4 + (r&3)]
__global__ __launch_bounds__(256) void transpose_w4_kernel(
    const float* __restrict__ w, float* __restrict__ w4, int CO, int CIK)
{
    int i = blockIdx.x * 256 + threadIdx.x;
    if (i >= CO * CIK) return;
    int co = i / CIK, r = i - co * CIK;
    w4[(((size_t)(r >> 2) * CO) + co) * 4 + (r & 3)] = w[i];
}

// ---------------- maxpool k3 s2 p1 (down_mask) ----------------
template<int DIN, int DOUT>
__global__ __launch_bounds__(256) void maxpool_kernel(
    const float* __restrict__ in, float* __restrict__ out)
{
    int i = blockIdx.x * 256 + threadIdx.x;
    constexpr int D3O = DOUT * DOUT * DOUT;
    if (i >= 2 * D3O) return;
    int b = i / D3O;
    int v = i - b * D3O;
    int z = v / (DOUT * DOUT), y = (v / DOUT) % DOUT, x = v % DOUT;
    float mx = 0.f;
    #pragma unroll
    for (int dz = 0; dz < 3; ++dz)
        #pragma unroll
        for (int dy = 0; dy < 3; ++dy)
            #pragma unroll
            for (int dx = 0; dx < 3; ++dx) {
                int zi = 2 * z - 1 + dz, yi = 2 * y - 1 + dy, xi = 2 * x - 1 + dx;
                if ((unsigned)zi < (unsigned)DIN && (unsigned)yi < (unsigned)DIN &&
                    (unsigned)xi < (unsigned)DIN)
                    mx = fmaxf(mx, in[(size_t)b * DIN * DIN * DIN + (zi * DIN + yi) * DIN + xi]);
            }
    out[i] = mx;
}

// ---------------- active-voxel list + dense index map ----------------
__global__ __launch_bounds__(256) void build_list_kernel(
    const float* __restrict__ m, int* __restrict__ list, int* __restrict__ idxmap,
    int* __restrict__ count)
{
    int i = blockIdx.x * 256 + threadIdx.x;
    if (i >= 2 * 262144) return;
    if (m[i] > 0.5f) {
        int k = atomicAdd(count, 1);
        if (k < ROWCAP) {
            list[k] = i;
            idxmap[i] = k;
        }
    }
}

// ---------------- stage1 conv-a (3->64, gathered) -> t1c[row][64] ----------------
__global__ __launch_bounds__(64) void stage1a_kernel(
    const float* __restrict__ x, const float* __restrict__ waT,  // [81][64]
    const int* __restrict__ list, const int* __restrict__ count,
    float* __restrict__ t1c)
{
    __shared__ float smem[81];
    int n = min(*count, ROWCAP);
    for (int i = blockIdx.x; i < n; i += gridDim.x) {
        int lin = list[i];
        int b = lin >> 18;
        int v = lin & 262143;
        int z = v >> 12, y = (v >> 6) & 63, xx = v & 63;
        for (int j = threadIdx.x; j < 81; j += 64) {
            int ci = j / 27, t = j - ci * 27;
            int zz = z + t / 9 - 1, yy = y + (t / 3) % 3 - 1, xc = xx + t % 3 - 1;
            float val = 0.f;
            if ((unsigned)zz < 64u && (unsigned)yy < 64u && (unsigned)xc < 64u)
                val = x[(size_t)(b * 3 + ci) * 262144 + (zz << 12) + (yy << 6) + xc];
            smem[j] = val;
        }
        __syncthreads();
        float acc = 0.f;
        #pragma unroll 9
        for (int j = 0; j < 81; ++j)
            acc = fmaf(smem[j], waT[j * 64 + threadIdx.x], acc);
        t1c[(size_t)i * 64 + threadIdx.x] = leaky(acc);
        __syncthreads();
    }
}

// ---------------- stage1 conv-b (64->64, gathered via idxmap) + 1x1 identity ----------------
__global__ __launch_bounds__(64) void stage1b_kernel(
    const float* __restrict__ t1c, const float* __restrict__ x,
    const float* __restrict__ wb4,  // [(1728/4)][64][4]
    const float* __restrict__ wdT,  // [3][64]
    const int* __restrict__ list, const int* __restrict__ idxmap,
    const int* __restrict__ count,
    float* __restrict__ x1c)
{
    __shared__ float sw[4 * 1728];
    int n = min(*count, ROWCAP);
    int nq = (n + 3) >> 2;
    for (int q = blockIdx.x; q < nq; q += gridDim.x) {
        for (int vv = 0; vv < 4; ++vv) {
            int i = q * 4 + vv;
            int lin = (i < n) ? list[i] : list[0];
            int b = lin >> 18;
            int v = lin & 262143;
            int z = v >> 12, y = (v >> 6) & 63, xx = v & 63;
            const int* im = idxmap + b * 262144;
            #pragma unroll
            for (int t = 0; t < 27; ++t) {
                int zz = z + t / 9 - 1, yy = y + (t / 3) % 3 - 1, xc = xx + t % 3 - 1;
                float val = 0.f;
                if ((unsigned)zz < 64u && (unsigned)yy < 64u && (unsigned)xc < 64u) {
                    int r = im[(zz << 12) + (yy << 6) + xc];
                    if (r >= 0)
                        val = t1c[(size_t)r * 64 + threadIdx.x];
                }
                sw[vv * 1728 + threadIdx.x * 27 + t] = val;
            }
        }
        __syncthreads();
        float acc[4] = {0.f, 0.f, 0.f, 0.f};
        const float* wp = wb4 + threadIdx.x * 4;
        for (int j4 = 0; j4 < 432; ++j4) {
            float4 w = *(const float4*)(wp + (size_t)j4 * 256);
            #pragma unroll
            for (int vv = 0; vv < 4; ++vv) {
                float4 s = *(const float4*)(&sw[vv * 1728 + j4 * 4]);
                acc[vv] = fmaf(s.x, w.x, acc[vv]);
                acc[vv] = fmaf(s.y, w.y, acc[vv]);
                acc[vv] = fmaf(s.z, w.z, acc[vv]);
                acc[vv] = fmaf(s.w, w.w, acc[vv]);
            }
        }
        #pragma unroll
        for (int vv = 0; vv < 4; ++vv) {
            int i = q * 4 + vv;
            if (i < n) {
                int lin = list[i];
                int b = lin >> 18;
                int v = lin & 262143;
                float id = 0.f;
                #pragma unroll
                for (int ci = 0; ci < 3; ++ci)
                    id = fmaf(x[(size_t)(b * 3 + ci) * 262144 + v], wdT[ci * 64 + threadIdx.x], id);
                x1c[(size_t)i * 64 + threadIdx.x] = leaky(acc[vv] + id);
            }
        }
        __syncthreads();
    }
}

// ---------------- wd1: gather-conv 64ch 64^3 -> 128ch 32^3, stride 2, leaky --------
template<int CO_T>
__global__ __launch_bounds__(256) void wd1_kernel(
    const float* __restrict__ x1c, const int* __restrict__ idxmap,
    const float* __restrict__ wT,   // [64*27][128]
    float* __restrict__ out)        // [2][128][32768]
{
    int v = blockIdx.x * 256 + threadIdx.x;
    int b = blockIdx.z;
    int cog = blockIdx.y * CO_T;
    int zo = v >> 10, yo = (v >> 5) & 31, xo = v & 31;
    float acc[CO_T];
    #pragma unroll
    for (int j = 0; j < CO_T; ++j) acc[j] = 0.f;
    const int* im = idxmap + b * 262144;

    #pragma unroll
    for (int kz = 0; kz < 3; ++kz) {
        int zi = 2 * zo - 1 + kz;
        #pragma unroll
        for (int ky = 0; ky < 3; ++ky) {
            int yi = 2 * yo - 1 + ky;
            #pragma unroll
            for (int kx = 0; kx < 3; ++kx) {
                int xi = 2 * xo - 1 + kx;
                int r = -1;
                if ((unsigned)zi < 64u && (unsigned)yi < 64u && (unsigned)xi < 64u)
                    r = im[(zi << 12) + (yi << 6) + xi];
                if (r >= 0) {
                    const float* xr = x1c + (size_t)r * 64;
                    int tap = kz * 9 + ky * 3 + kx;
                    for (int ci = 0; ci < 64; ci += 4) {
                        float4 xv = *(const float4*)(xr + ci);
                        const float4* w0 = (const float4*)(wT + (size_t)((ci + 0) * 27 + tap) * 128 + cog);
                        const float4* w1 = (const float4*)(wT + (size_t)((ci + 1) * 27 + tap) * 128 + cog);
                        const float4* w2 = (const float4*)(wT + (size_t)((ci + 2) * 27 + tap) * 128 + cog);
                        const float4* w3 = (const float4*)(wT + (size_t)((ci + 3) * 27 + tap) * 128 + cog);
                        #pragma unroll
                        for (int j4 = 0; j4 < CO_T / 4; ++j4) {
                            float4 a0 = w0[j4], a1 = w1[j4], a2 = w2[j4], a3 = w3[j4];
                            float* ac = &acc[j4 * 4];
                            ac[0] = fmaf(xv.x, a0.x, ac[0]); ac[1] = fmaf(xv.x, a0.y, ac[1]);
                            ac[2] = fmaf(xv.x, a0.z, ac[2]); ac[3] = fmaf(xv.x, a0.w, ac[3]);
                            ac[0] = fmaf(xv.y, a1.x, ac[0]); ac[1] = fmaf(xv.y, a1.y, ac[1]);
                            ac[2] = fmaf(xv.y, a1.z, ac[2]); ac[3] = fmaf(xv.y, a1.w, ac[3]);
                            ac[0] = fmaf(xv.z, a2.x, ac[0]); ac[1] = fmaf(xv.z, a2.y, ac[1]);
                            ac[2] = fmaf(xv.z, a2.z, ac[2]); ac[3] = fmaf(xv.z, a2.w, ac[3]);
                            ac[0] = fmaf(xv.w, a3.x, ac[0]); ac[1] = fmaf(xv.w, a3.y, ac[1]);
                            ac[2] = fmaf(xv.w, a3.z, ac[2]); ac[3] = fmaf(xv.w, a3.w, ac[3]);
                        }
                    }
                }
            }
        }
    }
    #pragma unroll
    for (int j = 0; j < CO_T; ++j)
        out[((size_t)(b * 128 + cog + j)) * 32768 + v] = leaky(acc[j]);
}

// ---------------- register-tiled dense conv k3 p1 (VX voxels x CO_T ch / thread) ---
// KS>1: split-K over ci chunks, raw partials to out[kc][B][CO][D3O], no epilogue.
template<int CI, int CO, int CO_T, int VX, int DIN, int DOUT, int STRIDE, int EPI, int KS>
__global__ __launch_bounds__(256) void conv_v2_kernel(
    const float* __restrict__ in,   // [B][CI][DIN^3]
    const float* __restrict__ wT,   // [CI*27][CO]
    const float* __restrict__ mask, // [B][DOUT^3]
    const float* __restrict__ resid,// [B][CO][DOUT^3]
    float* __restrict__ out)
{
    constexpr int D3O = DOUT * DOUT * DOUT;
    constexpr int D3I = DIN * DIN * DIN;
    constexpr int NIV = (STRIDE == 1) ? VX + 2 : 2 * VX + 1;  // input taps along x
    constexpr int NCOG = CO / CO_T;
    constexpr int CICH = CI / KS;

    int g = blockIdx.x * 256 + threadIdx.x;
    if (g * VX >= D3O) return;
    int b = blockIdx.z;
    int cog = (blockIdx.y % NCOG) * CO_T;
    int kc = blockIdx.y / NCOG;

    int v0 = g * VX;
    int x0 = v0 % DOUT;                  // multiple of VX
    int yo = (v0 / DOUT) % DOUT;
    int zo = v0 / (DOUT * DOUT);
    int zb = zo * STRIDE - 1, yb = yo * STRIDE - 1;
    int xb = x0 * STRIDE;                // iv[j] = input x = xb - 1 + j

    float acc[VX][CO_T] = {};

    const float* inb = in + ((size_t)b * CI + kc * CICH) * D3I
                          + ((size_t)(zb + 0) * DIN + yb) * DIN + xb;  // tap(0,0) base
    const float* wci = wT + (size_t)(kc * CICH) * 27 * CO + cog;

    for (int ci = 0; ci < CICH; ++ci) {
        #pragma unroll
        for (int kz = 0; kz < 3; ++kz) {
            int zi = zb + kz;
            bool zok = (unsigned)zi < (unsigned)DIN;
            #pragma unroll
            for (int ky = 0; ky < 3; ++ky) {
                int yi = yb + ky;
                bool ok = zok & ((unsigned)yi < (unsigned)DIN);
                float iv[NIV];
                #pragma unroll
                for (int j = 0; j < NIV; ++j) iv[j] = 0.f;
                const float* rp = inb + (kz * DIN + ky) * DIN;  // input x = xb
                if (ok) {
                    if (STRIDE == 1) {
                        if (VX == 4) {
                            float4 t = *(const float4*)rp;
                            iv[1] = t.x; iv[2] = t.y; iv[3] = t.z; iv[4] = t.w;
                        } else {
                            float2 t = *(const float2*)rp;
                            iv[1] = t.x; iv[2] = t.y;
                        }
                        if (x0 > 0) iv[0] = rp[-1];
                        if (x0 + VX < DIN) iv[NIV - 1] = rp[VX];
                    } else {
                        #pragma unroll
                        for (int j = 0; j < 2 * VX; j += 4) {
                            float4 t = *(const float4*)(rp + j);
                            iv[1 + j] = t.x; iv[2 + j] = t.y; iv[3 + j] = t.z; iv[4 + j] = t.w;
                        }
                        if (x0 > 0) iv[0] = rp[-1];
                    }
                }
                #pragma unroll
                for (int kx = 0; kx < 3; ++kx) {
                    float w[CO_T];
                    const float4* wp = (const float4*)(wci + (size_t)((kz * 3 + ky) * 3 + kx) * CO);
                    #pragma unroll
                    for (int j4 = 0; j4 < CO_T / 4; ++j4)
                        *(float4*)&w[j4 * 4] = wp[j4];
                    #pragma unroll
                    for (int vx = 0; vx < VX; ++vx) {
                        float xv = iv[vx * STRIDE + kx];
                        #pragma unroll
                        for (int j = 0; j < CO_T; ++j)
                            acc[vx][j] = fmaf(xv, w[j], acc[vx][j]);
                    }
                }
            }
        }
        inb += D3I;
        wci += 27 * CO;
    }

    if (KS > 1) out += (size_t)kc * 2 * CO * D3O;   // raw partial
    float m[VX];
    if (EPI & EPI_MASK) {
        #pragma unroll
        for (int vx = 0; vx < VX; ++vx) m[vx] = mask[(size_t)b * D3O + v0 + vx];
    }
    #pragma unroll
    for (int j = 0; j < CO_T; ++j) {
        float o[VX];
        const size_t obase = ((size_t)(b * CO + cog + j)) * D3O + v0;
        #pragma unroll
        for (int vx = 0; vx < VX; ++vx) {
            float val = acc[vx][j];
            if (EPI & EPI_MASK) val *= m[vx];
            if (EPI & EPI_RESID) val += resid[obase + vx];
            if (EPI & EPI_LEAKY) val = leaky(val);
            o[vx] = val;
        }
        if (VX == 4)
            *(float4*)(out + obase) = make_float4(o[0], o[1], o[2], o[3]);
        else if (VX == 2)
            *(float2*)(out + obase) = make_float2(o[0], o[1]);
        else
            out[obase] = o[0];
    }
}

// ---------------- combine split-K partials + fused epilogue ----------------
// part: [KS][2][CO][D3O]; out may alias part's first [2][CO][D3O] (1:1 thread map)
template<int CO, int D3O, int KS, int EPI>
__global__ __launch_bounds__(256) void combine_kernel(
    const float* __restrict__ part, const float* __restrict__ mask,
    const float* __restrict__ resid, float* __restrict__ out)
{
    constexpr int N = 2 * CO * D3O;
    int i = blockIdx.x * 256 + threadIdx.x;
    if (i >= N) return;
    float s = 0.f;
    #pragma unroll
    for (int k = 0; k < KS; ++k) s += part[(size_t)k * N + i];
    if (EPI & EPI_MASK) {
        int b = i / (CO * D3O);
        int v = i % D3O;
        s *= mask[b * D3O + v];
    }
    if (EPI & EPI_RESID) s += resid[i];
    if (EPI & EPI_LEAKY) s = leaky(s);
    out[i] = s;
}

// ---------------- final: sum 16 wd3 partials + leaky + mean/max pool over 8^3 ------
__global__ __launch_bounds__(64) void reduce_kernel(
    const float* __restrict__ part,   // [16][2][128][512]
    float* __restrict__ out)
{
    int bc = blockIdx.x;
    int b = bc >> 7, c = bc & 127;
    const float* p = part + (size_t)(b * 128 + c) * 512;
    float s = 0.f, mx = -3.4e38f;
    for (int i = threadIdx.x; i < 512; i += 64) {
        float v = 0.f;
        #pragma unroll
        for (int k = 0; k < 16; ++k) v += p[(size_t)k * 131072 + i];
        v = leaky(v);
        s += v;
        mx = fmaxf(mx, v);
    }
    #pragma unroll
    for (int o = 32; o > 0; o >>= 1) {
        s += __shfl_down(s, o);
        mx = fmaxf(mx, __shfl_down(mx, o));
    }
    if (threadIdx.x == 0) {
        out[b * 256 + c] = s * (1.f / 512.f);
        out[b * 256 + 128 + c] = mx;
    }
}

// fallback: clean deterministic fail if workspace too small (diagnostic)
__global__ __launch_bounds__(256) void zero_out_kernel(float* __restrict__ out, int n)
{
    int i = blockIdx.x * 256 + threadIdx.x;
    if (i < n) out[i] = 0.f;
}

// ---------------------------------------------------------------------------
extern "C" void kernel_launch(void* const* d_in, const int* in_sizes, int n_in,
                              void* d_out, int out_size, void* d_ws, size_t ws_size,
                              hipStream_t stream)
{
    (void)in_sizes; (void)n_in;
    const float* x    = (const float*)d_in[0];
    const float* mask = (const float*)d_in[1];
    const float* w1a  = (const float*)d_in[2];
    const float* w1b  = (const float*)d_in[3];
    const float* w1d  = (const float*)d_in[4];
    const float* wd1  = (const float*)d_in[5];
    const float* w2a  = (const float*)d_in[6];
    const float* w2b  = (const float*)d_in[7];
    const float* wd2  = (const float*)d_in[8];
    const float* w3a  = (const float*)d_in[9];
    const float* w3b  = (const float*)d_in[10];
    const float* wd3  = (const float*)d_in[11];
    float* out = (float*)d_out;
    float* ws = (float*)d_ws;

    const size_t NEED_BYTES = 31769872ull * 4ull;  // 127,079,488
    if (ws_size < NEED_BYTES) {
        zero_out_kernel<<<dim3((out_size + 255) / 256), 256, 0, stream>>>(out, out_size);
        return;
    }

    // region bases (floats); liveness chain:
    //  A: xin2 -> xin3 -> wd3-partials[16][2][128][512]
    //  B: x1c -> t2 -> wd2-partials[2][2][256][4096] -> t3
    //  C: t1c/idx/list -> x2 -> conv3a-partials -> conv3b-partials -> x3 (in place)
    const size_t SZ  = 8388608;
    float* A    = ws;
    float* Bb   = ws + SZ;
    float* C    = ws + 2 * SZ;
    float* x1c  = Bb;
    float* t1c  = C;
    int*   idx  = (int*)(C + 2097152);
    int*   list = (int*)(C + 2621440);
    size_t off = 3 * SZ;
    auto alloc = [&](size_t n) { float* p = ws + off; off += (n + 63) & ~63ull; return p; };
    float* waT  = alloc(81 * 64);
    float* wb4  = alloc(1728 * 64);
    float* wdTt = alloc(3 * 64);
    float* wd1T = alloc(1728 * 128);
    float* w2aT = alloc(3456 * 128);
    float* w2bT = alloc(3456 * 128);
    float* wd2T = alloc(3456 * 256);
    float* w3aT = alloc(6912 * 256);
    float* w3bT = alloc(6912 * 256);
    float* wd3T = alloc(6912 * 128);
    float* m2   = alloc(2 * 32768);
    float* m3   = alloc(2 * 4096);
    int*   cnt  = (int*)alloc(16);

    hipMemsetAsync(cnt, 0, 4, stream);
    hipMemsetAsync(idx, 0xFF, 524288 * 4, stream);   // idxmap = -1

    auto tg = [](int n) { return dim3((n + 255) / 256); };
    transpose_w_kernel <<<tg(64 * 81),    256, 0, stream>>>(w1a, waT,  64, 81);
    transpose_w4_kernel<<<tg(64 * 1728),  256, 0, stream>>>(w1b, wb4,  64, 1728);
    transpose_w_kernel <<<tg(64 * 3),     256, 0, stream>>>(w1d, wdTt, 64, 3);
    transpose_w_kernel <<<tg(128 * 1728), 256, 0, stream>>>(wd1, wd1T, 128, 1728);
    transpose_w_kernel <<<tg(128 * 3456), 256, 0, stream>>>(w2a, w2aT, 128, 3456);
    transpose_w_kernel <<<tg(128 * 3456), 256, 0, stream>>>(w2b, w2bT, 128, 3456);
    transpose_w_kernel <<<tg(256 * 3456), 256, 0, stream>>>(wd2, wd2T, 256, 3456);
    transpose_w_kernel <<<tg(256 * 6912), 256, 0, stream>>>(w3a, w3aT, 256, 6912);
    transpose_w_kernel <<<tg(256 * 6912), 256, 0, stream>>>(w3b, w3bT, 256, 6912);
    transpose_w_kernel <<<tg(128 * 6912), 256, 0, stream>>>(wd3, wd3T, 128, 6912);

    maxpool_kernel<64, 32><<<dim3(2 * 32768 / 256), 256, 0, stream>>>(mask, m2);
    maxpool_kernel<32, 16><<<dim3(2 * 4096 / 256),  256, 0, stream>>>(m2, m3);
    build_list_kernel<<<dim3(2 * 262144 / 256), 256, 0, stream>>>(mask, list, idx, cnt);

    stage1a_kernel<<<dim3(2048), 64, 0, stream>>>(x, waT, list, cnt, t1c);
    stage1b_kernel<<<dim3(2048), 64, 0, stream>>>(t1c, x, wb4, wdTt, list, idx, cnt, x1c);

    // wd1: gather from compacted x1 -> dense xin2 = A, leaky
    wd1_kernel<16><<<dim3(128, 8, 2), 256, 0, stream>>>(x1c, idx, wd1T, A);

    // stage2 res block: 2048 blocks each (8/CU)
    conv_v2_kernel<128, 128, 4, 4, 32, 32, 1, EPI_MASK | EPI_LEAKY, 1>
        <<<dim3(32, 32, 2), 256, 0, stream>>>(A, w2aT, m2, nullptr, Bb);
    conv_v2_kernel<128, 128, 4, 4, 32, 32, 1, EPI_MASK | EPI_RESID | EPI_LEAKY, 1>
        <<<dim3(32, 32, 2), 256, 0, stream>>>(Bb, w2bT, m2, A, C);

    // wd2 split-K=2: partials -> Bb, combine(leaky) -> A (= xin3)
    conv_v2_kernel<128, 256, 4, 2, 32, 16, 2, 0, 2>
        <<<dim3(8, 128, 2), 256, 0, stream>>>(C, wd2T, nullptr, nullptr, Bb);
    combine_kernel<256, 4096, 2, EPI_LEAKY>
        <<<dim3(8192), 256, 0, stream>>>(Bb, nullptr, nullptr, A);

    // conv3a split-K=2: partials -> C, combine(mask,leaky) -> Bb (= t3)
    conv_v2_kernel<256, 256, 4, 2, 16, 16, 1, 0, 2>
        <<<dim3(8, 128, 2), 256, 0, stream>>>(A, w3aT, nullptr, nullptr, C);
    combine_kernel<256, 4096, 2, EPI_MASK | EPI_LEAKY>
        <<<dim3(8192), 256, 0, stream>>>(C, m3, nullptr, Bb);

    // conv3b split-K=2: partials -> C, combine(mask,resid,leaky) -> C (in place, = x3)
    conv_v2_kernel<256, 256, 4, 2, 16, 16, 1, 0, 2>
        <<<dim3(8, 128, 2), 256, 0, stream>>>(Bb, w3bT, nullptr, nullptr, C);
    combine_kernel<256, 4096, 2, EPI_MASK | EPI_RESID | EPI_LEAKY>
        <<<dim3(8192), 256, 0, stream>>>(C, m3, A, C);

    // wd3 split-K=16: partials -> A[16][2][128][512]
    conv_v2_kernel<256, 128, 4, 4, 16, 8, 2, 0, 16>
        <<<dim3(1, 512, 2), 256, 0, stream>>>(C, wd3T, nullptr, nullptr, A);

    // fused: sum 16 partials + leaky + mean/max pool
    reduce_kernel<<<dim3(256), 64, 0, stream>>>(A, out);
}

// Round 5
// 3301.948 us; speedup vs baseline: 3.1856x; 1.7586x over previous
//
#include <hip/hip_runtime.h>

// ---------------------------------------------------------------------------
// SparseEncoderResUNet on MI355X — round 5: split-bf16 MFMA implicit GEMM.
// Dense convs (conv2a/b, wd2, conv3a/b) run on matrix cores:
//   activations stored channel-last, x-padded (shared halo), as hi/lo bf16;
//   weights pre-packed into mfma_f32_16x16x32_bf16 A-fragment layout;
//   acc += ah*bh + ah*bl + al*bh + al*bl  (4 MFMAs, ~2^-18 rel residual).
// wd1 = sparse fp32 gather -> hi/lo CL; wd3 = fp32 from hi/lo CL; stage1 as-is.
// Workspace: 126,688,256 B (under the proven 127,079,488 budget).
// ---------------------------------------------------------------------------

enum { EPI_MASK = 1, EPI_LEAKY = 2, EPI_RESID = 4 };
#define ROWCAP 32768

typedef short  bf16x8 __attribute__((ext_vector_type(8)));
typedef float  f32x4  __attribute__((ext_vector_type(4)));
typedef ushort us4    __attribute__((ext_vector_type(4)));

__device__ __forceinline__ float leaky(float v) { return v >= 0.f ? v : 0.2f * v; }
__device__ __forceinline__ ushort f2bf(float f) {
    unsigned u = __float_as_uint(f);
    return (ushort)((u + 0x7FFFu + ((u >> 16) & 1u)) >> 16);
}
__device__ __forceinline__ float bf2f(ushort h) {
    return __uint_as_float((unsigned)h << 16);
}

// ---------------- weight transpose: w[co][cik] -> wT[cik][co] ----------------
__global__ __launch_bounds__(256) void transpose_w_kernel(
    const float* __restrict__ w, float* __restrict__ wT, int CO, int CIK)
{
    int i = blockIdx.x * 256 + threadIdx.x;
    if (i >= CO * CIK) return;
    int co = i / CIK, r = i - co * CIK;
    wT[(size_t)r * CO + co] = w[i];
}

// interleaved-by-4 layout for stage1b
__global__ __launch_bounds__(256) void transpose_w4_kernel(
    const float* __restrict__ w, float* __restrict__ w4, int CO, int CIK)
{
    int i = blockIdx.x * 256 + threadIdx.x;
    if (i >= CO * CIK) return;
    int co = i / CIK, r = i - co * CIK;
    w4[(((size_t)(r >> 2) * CO) + co) * 4 + (r & 3)] = w[i];
}

// ---------------- pack weights into MFMA A-frag layout (hi/lo bf16) ----------
// out index i = (((tap*NCI + ct)*NMT + mt)*64 + L)*8 + j
//   co = mt*16 + (L&15),  ci = ct*32 + (L>>4)*8 + j,  w[co][ci][tap]
__global__ __launch_bounds__(256) void pack_w_kernel(
    const float* __restrict__ w, ushort* __restrict__ Ah, ushort* __restrict__ Al,
    int CI, int CO)
{
    int i = blockIdx.x * 256 + threadIdx.x;
    if (i >= 27 * CI * CO) return;
    int j = i & 7, L = (i >> 3) & 63, rest = i >> 9;
    int NMT = CO >> 4, NCI = CI >> 5;
    int mt = rest % NMT; rest /= NMT;
    int ct = rest % NCI;
    int tap = rest / NCI;
    int co = mt * 16 + (L & 15);
    int ci = ct * 32 + (L >> 4) * 8 + j;
    float v = w[((size_t)co * CI + ci) * 27 + tap];
    ushort h = f2bf(v);
    Ah[i] = h;
    Al[i] = f2bf(v - bf2f(h));
}

// ---------------- maxpool k3 s2 p1 (down_mask) ----------------
template<int DIN, int DOUT>
__global__ __launch_bounds__(256) void maxpool_kernel(
    const float* __restrict__ in, float* __restrict__ out)
{
    int i = blockIdx.x * 256 + threadIdx.x;
    constexpr int D3O = DOUT * DOUT * DOUT;
    if (i >= 2 * D3O) return;
    int b = i / D3O;
    int v = i - b * D3O;
    int z = v / (DOUT * DOUT), y = (v / DOUT) % DOUT, x = v % DOUT;
    float mx = 0.f;
    #pragma unroll
    for (int dz = 0; dz < 3; ++dz)
        #pragma unroll
        for (int dy = 0; dy < 3; ++dy)
            #pragma unroll
            for (int dx = 0; dx < 3; ++dx) {
                int zi = 2 * z - 1 + dz, yi = 2 * y - 1 + dy, xi = 2 * x - 1 + dx;
                if ((unsigned)zi < (unsigned)DIN && (unsigned)yi < (unsigned)DIN &&
                    (unsigned)xi < (unsigned)DIN)
                    mx = fmaxf(mx, in[(size_t)b * DIN * DIN * DIN + (zi * DIN + yi) * DIN + xi]);
            }
    out[i] = mx;
}

// ---------------- active-voxel list + dense index map ----------------
__global__ __launch_bounds__(256) void build_list_kernel(
    const float* __restrict__ m, int* __restrict__ list, int* __restrict__ idxmap,
    int* __restrict__ count)
{
    int i = blockIdx.x * 256 + threadIdx.x;
    if (i >= 2 * 262144) return;
    if (m[i] > 0.5f) {
        int k = atomicAdd(count, 1);
        if (k < ROWCAP) {
            list[k] = i;
            idxmap[i] = k;
        }
    }
}

// ---------------- stage1 conv-a (3->64, gathered) -> t1c[row][64] ----------------
__global__ __launch_bounds__(64) void stage1a_kernel(
    const float* __restrict__ x, const float* __restrict__ waT,
    const int* __restrict__ list, const int* __restrict__ count,
    float* __restrict__ t1c)
{
    __shared__ float smem[81];
    int n = min(*count, ROWCAP);
    for (int i = blockIdx.x; i < n; i += gridDim.x) {
        int lin = list[i];
        int b = lin >> 18;
        int v = lin & 262143;
        int z = v >> 12, y = (v >> 6) & 63, xx = v & 63;
        for (int j = threadIdx.x; j < 81; j += 64) {
            int ci = j / 27, t = j - ci * 27;
            int zz = z + t / 9 - 1, yy = y + (t / 3) % 3 - 1, xc = xx + t % 3 - 1;
            float val = 0.f;
            if ((unsigned)zz < 64u && (unsigned)yy < 64u && (unsigned)xc < 64u)
                val = x[(size_t)(b * 3 + ci) * 262144 + (zz << 12) + (yy << 6) + xc];
            smem[j] = val;
        }
        __syncthreads();
        float acc = 0.f;
        #pragma unroll 9
        for (int j = 0; j < 81; ++j)
            acc = fmaf(smem[j], waT[j * 64 + threadIdx.x], acc);
        t1c[(size_t)i * 64 + threadIdx.x] = leaky(acc);
        __syncthreads();
    }
}

// ---------------- stage1 conv-b (64->64, gathered) + 1x1 identity ----------------
__global__ __launch_bounds__(64) void stage1b_kernel(
    const float* __restrict__ t1c, const float* __restrict__ x,
    const float* __restrict__ wb4, const float* __restrict__ wdT,
    const int* __restrict__ list, const int* __restrict__ idxmap,
    const int* __restrict__ count,
    float* __restrict__ x1c)
{
    __shared__ float sw[4 * 1728];
    int n = min(*count, ROWCAP);
    int nq = (n + 3) >> 2;
    for (int q = blockIdx.x; q < nq; q += gridDim.x) {
        for (int vv = 0; vv < 4; ++vv) {
            int i = q * 4 + vv;
            int lin = (i < n) ? list[i] : list[0];
            int b = lin >> 18;
            int v = lin & 262143;
            int z = v >> 12, y = (v >> 6) & 63, xx = v & 63;
            const int* im = idxmap + b * 262144;
            #pragma unroll
            for (int t = 0; t < 27; ++t) {
                int zz = z + t / 9 - 1, yy = y + (t / 3) % 3 - 1, xc = xx + t % 3 - 1;
                float val = 0.f;
                if ((unsigned)zz < 64u && (unsigned)yy < 64u && (unsigned)xc < 64u) {
                    int r = im[(zz << 12) + (yy << 6) + xc];
                    if (r >= 0)
                        val = t1c[(size_t)r * 64 + threadIdx.x];
                }
                sw[vv * 1728 + threadIdx.x * 27 + t] = val;
            }
        }
        __syncthreads();
        float acc[4] = {0.f, 0.f, 0.f, 0.f};
        const float* wp = wb4 + threadIdx.x * 4;
        for (int j4 = 0; j4 < 432; ++j4) {
            float4 w = *(const float4*)(wp + (size_t)j4 * 256);
            #pragma unroll
            for (int vv = 0; vv < 4; ++vv) {
                float4 s = *(const float4*)(&sw[vv * 1728 + j4 * 4]);
                acc[vv] = fmaf(s.x, w.x, acc[vv]);
                acc[vv] = fmaf(s.y, w.y, acc[vv]);
                acc[vv] = fmaf(s.z, w.z, acc[vv]);
                acc[vv] = fmaf(s.w, w.w, acc[vv]);
            }
        }
        #pragma unroll
        for (int vv = 0; vv < 4; ++vv) {
            int i = q * 4 + vv;
            if (i < n) {
                int lin = list[i];
                int b = lin >> 18;
                int v = lin & 262143;
                float id = 0.f;
                #pragma unroll
                for (int ci = 0; ci < 3; ++ci)
                    id = fmaf(x[(size_t)(b * 3 + ci) * 262144 + v], wdT[ci * 64 + threadIdx.x], id);
                x1c[(size_t)i * 64 + threadIdx.x] = leaky(acc[vv] + id);
            }
        }
        __syncthreads();
    }
}

// ---------------- wd1: gather-conv -> channel-last padded hi/lo bf16 ----------
// out layout: [2][32][32][33][128] + 128 lead; writes interior x only.
__global__ __launch_bounds__(256) void wd1_kernel(
    const float* __restrict__ x1c, const int* __restrict__ idxmap,
    const float* __restrict__ wT,   // [64*27][128]
    ushort* __restrict__ out_hi, ushort* __restrict__ out_lo)
{
    constexpr int CO_T = 16;
    int v = blockIdx.x * 256 + threadIdx.x;
    int b = blockIdx.z;
    int cog = blockIdx.y * CO_T;
    int zo = v >> 10, yo = (v >> 5) & 31, xo = v & 31;
    float acc[CO_T];
    #pragma unroll
    for (int j = 0; j < CO_T; ++j) acc[j] = 0.f;
    const int* im = idxmap + b * 262144;

    #pragma unroll
    for (int kz = 0; kz < 3; ++kz) {
        int zi = 2 * zo - 1 + kz;
        #pragma unroll
        for (int ky = 0; ky < 3; ++ky) {
            int yi = 2 * yo - 1 + ky;
            #pragma unroll
            for (int kx = 0; kx < 3; ++kx) {
                int xi = 2 * xo - 1 + kx;
                int r = -1;
                if ((unsigned)zi < 64u && (unsigned)yi < 64u && (unsigned)xi < 64u)
                    r = im[(zi << 12) + (yi << 6) + xi];
                if (r >= 0) {
                    const float* xr = x1c + (size_t)r * 64;
                    int tap = kz * 9 + ky * 3 + kx;
                    for (int ci = 0; ci < 64; ci += 4) {
                        float4 xv = *(const float4*)(xr + ci);
                        const float4* w0 = (const float4*)(wT + (size_t)((ci + 0) * 27 + tap) * 128 + cog);
                        const float4* w1 = (const float4*)(wT + (size_t)((ci + 1) * 27 + tap) * 128 + cog);
                        const float4* w2 = (const float4*)(wT + (size_t)((ci + 2) * 27 + tap) * 128 + cog);
                        const float4* w3 = (const float4*)(wT + (size_t)((ci + 3) * 27 + tap) * 128 + cog);
                        #pragma unroll
                        for (int j4 = 0; j4 < CO_T / 4; ++j4) {
                            float4 a0 = w0[j4], a1 = w1[j4], a2 = w2[j4], a3 = w3[j4];
                            float* ac = &acc[j4 * 4];
                            ac[0] = fmaf(xv.x, a0.x, ac[0]); ac[1] = fmaf(xv.x, a0.y, ac[1]);
                            ac[2] = fmaf(xv.x, a0.z, ac[2]); ac[3] = fmaf(xv.x, a0.w, ac[3]);
                            ac[0] = fmaf(xv.y, a1.x, ac[0]); ac[1] = fmaf(xv.y, a1.y, ac[1]);
                            ac[2] = fmaf(xv.y, a1.z, ac[2]); ac[3] = fmaf(xv.y, a1.w, ac[3]);
                            ac[0] = fmaf(xv.z, a2.x, ac[0]); ac[1] = fmaf(xv.z, a2.y, ac[1]);
                            ac[2] = fmaf(xv.z, a2.z, ac[2]); ac[3] = fmaf(xv.z, a2.w, ac[3]);
                            ac[0] = fmaf(xv.w, a3.x, ac[0]); ac[1] = fmaf(xv.w, a3.y, ac[1]);
                            ac[2] = fmaf(xv.w, a3.z, ac[2]); ac[3] = fmaf(xv.w, a3.w, ac[3]);
                        }
                    }
                }
            }
        }
    }
    size_t oa = ((((size_t)b * 32 + zo) * 32 + yo) * 33 + xo) * 128 + 128 + cog;
    #pragma unroll
    for (int g = 0; g < 4; ++g) {
        us4 h, l;
        #pragma unroll
        for (int r = 0; r < 4; ++r) {
            float val = leaky(acc[g * 4 + r]);
            ushort hb = f2bf(val);
            h[r] = hb;
            l[r] = f2bf(val - bf2f(hb));
        }
        *(us4*)(out_hi + oa + g * 4) = h;
        *(us4*)(out_lo + oa + g * 4) = l;
    }
}

// ---------------- MFMA implicit-GEMM conv (split-bf16, 4 products) -----------
// in : CL padded-x hi/lo [2][DI][DI][DI+1][CI] + CI lead
// out: CL padded-x hi/lo [2][DO][DO][DO+1][CO] + CO lead
// A  : packed frags [27][CI/32][CO/16][64][8] hi/lo
// block = 4 waves; wave covers NCT*16 co x DO vox (one x-row).
template<int CI, int CO, int DI, int DO, int S, int NCT, int EPI>
__global__ __launch_bounds__(256) void mfma_conv_kernel(
    const ushort* __restrict__ in_hi, const ushort* __restrict__ in_lo,
    const ushort* __restrict__ Ah, const ushort* __restrict__ Al,
    const float* __restrict__ mask,
    const ushort* __restrict__ rh_, const ushort* __restrict__ rl_,
    ushort* __restrict__ out_hi, ushort* __restrict__ out_lo)
{
    constexpr int NNF = DO / 16;
    constexpr int NCI = CI / 32;
    constexpr int NMT = CO / 16;
    const int row = blockIdx.x;
    const int y = row % DO;
    const int z = (row / DO) % DO;
    const int b = row / (DO * DO);
    const int wave = threadIdx.x >> 6;
    const int lane = threadIdx.x & 63;
    const int n_l = lane & 15;
    const int q = lane >> 4;
    const int mt0 = (blockIdx.y * 4 + wave) * NCT;

    f32x4 acc[NCT][NNF];
    #pragma unroll
    for (int a = 0; a < NCT; ++a)
        #pragma unroll
        for (int c = 0; c < NNF; ++c)
            acc[a][c] = (f32x4){0.f, 0.f, 0.f, 0.f};

    #pragma unroll
    for (int dz = 0; dz < 3; ++dz) {
        int zp = z * S + dz - 1;
        if ((unsigned)zp >= (unsigned)DI) continue;
        #pragma unroll
        for (int dy = 0; dy < 3; ++dy) {
            int yp = y * S + dy - 1;
            if ((unsigned)yp >= (unsigned)DI) continue;
            const size_t rowb = ((((size_t)b * DI + zp) * DI + yp) * (DI + 1)) * CI + CI;
            #pragma unroll
            for (int dx = 0; dx < 3; ++dx) {
                const int tap = dz * 9 + dy * 3 + dx;
                #pragma unroll
                for (int ct = 0; ct < NCI; ++ct) {
                    bf16x8 bh[NNF], bl[NNF];
                    #pragma unroll
                    for (int nf = 0; nf < NNF; ++nf) {
                        int xp = (nf * 16 + n_l) * S + dx - 1;
                        size_t ba = rowb + (size_t)xp * CI + ct * 32 + q * 8;
                        bh[nf] = *(const bf16x8*)(in_hi + ba);
                        bl[nf] = *(const bf16x8*)(in_lo + ba);
                    }
                    #pragma unroll
                    for (int mt = 0; mt < NCT; ++mt) {
                        size_t aa = ((size_t)(tap * NCI + ct) * NMT + (mt0 + mt)) * 512 + lane * 8;
                        bf16x8 ahf = *(const bf16x8*)(Ah + aa);
                        bf16x8 alf = *(const bf16x8*)(Al + aa);
                        #pragma unroll
                        for (int nf = 0; nf < NNF; ++nf) {
                            acc[mt][nf] = __builtin_amdgcn_mfma_f32_16x16x32_bf16(ahf, bh[nf], acc[mt][nf], 0, 0, 0);
                            acc[mt][nf] = __builtin_amdgcn_mfma_f32_16x16x32_bf16(ahf, bl[nf], acc[mt][nf], 0, 0, 0);
                            acc[mt][nf] = __builtin_amdgcn_mfma_f32_16x16x32_bf16(alf, bh[nf], acc[mt][nf], 0, 0, 0);
                            acc[mt][nf] = __builtin_amdgcn_mfma_f32_16x16x32_bf16(alf, bl[nf], acc[mt][nf], 0, 0, 0);
                        }
                    }
                }
            }
        }
    }

    // epilogue: C/D layout col(n)=lane&15, row(m within 16) = q*4 + reg
    const size_t orowb = ((((size_t)b * DO + z) * DO + y) * (DO + 1)) * CO + CO;
    #pragma unroll
    for (int nf = 0; nf < NNF; ++nf) {
        int xo = nf * 16 + n_l;
        float mval = 1.f;
        if (EPI & EPI_MASK) mval = mask[(((size_t)b * DO + z) * DO + y) * DO + xo];
        #pragma unroll
        for (int mt = 0; mt < NCT; ++mt) {
            size_t oa = orowb + (size_t)xo * CO + (mt0 + mt) * 16 + q * 4;
            float rs[4] = {0.f, 0.f, 0.f, 0.f};
            if (EPI & EPI_RESID) {
                us4 rh4 = *(const us4*)(rh_ + oa);
                us4 rl4 = *(const us4*)(rl_ + oa);
                #pragma unroll
                for (int r = 0; r < 4; ++r) rs[r] = bf2f(rh4[r]) + bf2f(rl4[r]);
            }
            us4 oh, ol;
            #pragma unroll
            for (int r = 0; r < 4; ++r) {
                float v = acc[mt][nf][r];
                if (EPI & EPI_MASK) v *= mval;
                if (EPI & EPI_RESID) v += rs[r];
                if (EPI & EPI_LEAKY) v = leaky(v);
                ushort hb = f2bf(v);
                oh[r] = hb;
                ol[r] = f2bf(v - bf2f(hb));
            }
            *(us4*)(out_hi + oa) = oh;
            *(us4*)(out_lo + oa) = ol;
        }
    }
}

// ---------------- wd3: fp32 split-K conv from hi/lo CL x3 ----------------
// x3: [2][16][16][17][256] + 256 lead.  w: original [128][256][27].
// part: [8][2][128][512]
__global__ __launch_bounds__(256) void wd3_kernel(
    const ushort* __restrict__ xh, const ushort* __restrict__ xl,
    const float* __restrict__ w, float* __restrict__ part)
{
    int gid = blockIdx.x * 256 + threadIdx.x;     // 262144 threads
    int v = gid & 511;
    int c4 = (gid >> 9) & 31;
    int b = (gid >> 14) & 1;
    int kc = gid >> 15;                           // 0..7
    int x = v & 7, y = (v >> 3) & 7, z = v >> 6;
    int cog = c4 * 4;
    float acc[4] = {0.f, 0.f, 0.f, 0.f};
    const float* wb = w + (size_t)cog * 6912 + (size_t)(kc * 32) * 27;

    for (int dz = 0; dz < 3; ++dz) {
        int zp = 2 * z + dz - 1;
        if ((unsigned)zp >= 16u) continue;
        for (int dy = 0; dy < 3; ++dy) {
            int yp = 2 * y + dy - 1;
            if ((unsigned)yp >= 16u) continue;
            const size_t rowb = ((((size_t)b * 16 + zp) * 16 + yp) * 17) * 256 + 256;
            for (int dx = 0; dx < 3; ++dx) {
                int xp = 2 * x + dx - 1;           // padded: always valid
                int tap = dz * 9 + dy * 3 + dx;
                const size_t base = rowb + (size_t)xp * 256 + kc * 32;
                #pragma unroll 4
                for (int ci = 0; ci < 32; ++ci) {
                    float xv = bf2f(xh[base + ci]) + bf2f(xl[base + ci]);
                    #pragma unroll
                    for (int j = 0; j < 4; ++j)
                        acc[j] = fmaf(xv, wb[(size_t)j * 6912 + ci * 27 + tap], acc[j]);
                }
            }
        }
    }
    #pragma unroll
    for (int j = 0; j < 4; ++j)
        part[(((size_t)kc * 2 + b) * 128 + cog + j) * 512 + v] = acc[j];
}

// ---------------- final: sum 8 partials + leaky + mean/max pool over 8^3 ------
__global__ __launch_bounds__(64) void reduce_kernel(
    const float* __restrict__ part, float* __restrict__ out)
{
    int bc = blockIdx.x;
    int b = bc >> 7, c = bc & 127;
    const float* p = part + (size_t)(b * 128 + c) * 512;
    float s = 0.f, mx = -3.4e38f;
    for (int i = threadIdx.x; i < 512; i += 64) {
        float v = 0.f;
        #pragma unroll
        for (int k = 0; k < 8; ++k) v += p[(size_t)k * 131072 + i];
        v = leaky(v);
        s += v;
        mx = fmaxf(mx, v);
    }
    #pragma unroll
    for (int o = 32; o > 0; o >>= 1) {
        s += __shfl_down(s, o);
        mx = fmaxf(mx, __shfl_down(mx, o));
    }
    if (threadIdx.x == 0) {
        out[b * 256 + c] = s * (1.f / 512.f);
        out[b * 256 + 128 + c] = mx;
    }
}

__global__ __launch_bounds__(256) void zero_out_kernel(float* __restrict__ out, int n)
{
    int i = blockIdx.x * 256 + threadIdx.x;
    if (i < n) out[i] = 0.f;
}

// ---------------------------------------------------------------------------
extern "C" void kernel_launch(void* const* d_in, const int* in_sizes, int n_in,
                              void* d_out, int out_size, void* d_ws, size_t ws_size,
                              hipStream_t stream)
{
    (void)in_sizes; (void)n_in;
    const float* x    = (const float*)d_in[0];
    const float* mask = (const float*)d_in[1];
    const float* w1a  = (const float*)d_in[2];
    const float* w1b  = (const float*)d_in[3];
    const float* w1d  = (const float*)d_in[4];
    const float* wd1  = (const float*)d_in[5];
    const float* w2a  = (const float*)d_in[6];
    const float* w2b  = (const float*)d_in[7];
    const float* wd2  = (const float*)d_in[8];
    const float* w3a  = (const float*)d_in[9];
    const float* w3b  = (const float*)d_in[10];
    const float* wd3  = (const float*)d_in[11];
    float* out = (float*)d_out;
    char* ws = (char*)d_ws;

    // ---- byte map (see round-5 notes): total NEED = 126,688,256 ----
    const size_t RSZ   = 34603520;     // one stage-2 region (hi+lo)
    const size_t A2HI  = 17301760;     // hi->lo offset within stage-2 region
    const size_t A3HI  = 4456960;      // hi->lo offset within stage-3 tensor
    char* R1 = ws;
    char* R2 = ws + RSZ;
    char* R3 = ws + 2 * RSZ;
    size_t off = 3 * RSZ;              // 103,810,560
    auto alloc = [&](size_t bytes) { char* p = ws + off; off = (off + bytes + 255) & ~255ull; return p; };
    ushort* pk2a_h = (ushort*)alloc(884736);
    ushort* pk2a_l = (ushort*)alloc(884736);
    ushort* pk2b_h = (ushort*)alloc(884736);
    ushort* pk2b_l = (ushort*)alloc(884736);
    ushort* pkd2_h = (ushort*)alloc(1769472);
    ushort* pkd2_l = (ushort*)alloc(1769472);
    ushort* pk3a_h = (ushort*)alloc(3538944);
    ushort* pk3a_l = (ushort*)alloc(3538944);
    ushort* pk3b_h = (ushort*)alloc(3538944);
    ushort* pk3b_l = (ushort*)alloc(3538944);
    float*  wd1T   = (float*)alloc(884736);
    float*  waT    = (float*)alloc(20736);
    float*  wb4    = (float*)alloc(442368);
    float*  wdTt   = (float*)alloc(768);
    float*  m2     = (float*)alloc(262144);
    float*  m3     = (float*)alloc(32768);
    int*    cnt    = (int*)alloc(256);
    const size_t NEED = off;

    if (ws_size < NEED) {
        zero_out_kernel<<<dim3((out_size + 255) / 256), 256, 0, stream>>>(out, out_size);
        return;
    }

    // stage-1 scratch aliased into R2 (dead before t2 is written)
    float* t1c  = (float*)R2;
    float* x1c  = (float*)(R2 + 8388608);
    int*   idx  = (int*)(R2 + 16777216);
    int*   list = (int*)(R2 + 18874368);
    // wd3 partials aliased into R2 (t3 dead by then)
    float* part = (float*)R2;

    // stage-2/3 tensor views
    ushort* xin2_h = (ushort*)R1;             ushort* xin2_l = (ushort*)(R1 + A2HI);
    ushort* t2_h   = (ushort*)R2;             ushort* t2_l   = (ushort*)(R2 + A2HI);
    ushort* x2_h   = (ushort*)R3;             ushort* x2_l   = (ushort*)(R3 + A2HI);
    ushort* xin3_h = (ushort*)R1;             ushort* xin3_l = (ushort*)(R1 + A3HI);
    ushort* t3_h   = (ushort*)R2;             ushort* t3_l   = (ushort*)(R2 + A3HI);
    ushort* x3_h   = (ushort*)R3;             ushort* x3_l   = (ushort*)(R3 + A3HI);

    hipMemsetAsync(cnt, 0, 4, stream);
    hipMemsetAsync(idx, 0xFF, 2097152, stream);
    hipMemsetAsync(R1, 0, RSZ, stream);           // xin2 pads

    auto tg = [](int n) { return dim3((n + 255) / 256); };
    // weight prep
    pack_w_kernel<<<tg(27 * 128 * 128), 256, 0, stream>>>(w2a, pk2a_h, pk2a_l, 128, 128);
    pack_w_kernel<<<tg(27 * 128 * 128), 256, 0, stream>>>(w2b, pk2b_h, pk2b_l, 128, 128);
    pack_w_kernel<<<tg(27 * 128 * 256), 256, 0, stream>>>(wd2, pkd2_h, pkd2_l, 128, 256);
    pack_w_kernel<<<tg(27 * 256 * 256), 256, 0, stream>>>(w3a, pk3a_h, pk3a_l, 256, 256);
    pack_w_kernel<<<tg(27 * 256 * 256), 256, 0, stream>>>(w3b, pk3b_h, pk3b_l, 256, 256);
    transpose_w_kernel <<<tg(128 * 1728), 256, 0, stream>>>(wd1, wd1T, 128, 1728);
    transpose_w_kernel <<<tg(64 * 81),    256, 0, stream>>>(w1a, waT,  64, 81);
    transpose_w4_kernel<<<tg(64 * 1728),  256, 0, stream>>>(w1b, wb4,  64, 1728);
    transpose_w_kernel <<<tg(64 * 3),     256, 0, stream>>>(w1d, wdTt, 64, 3);

    maxpool_kernel<64, 32><<<dim3(2 * 32768 / 256), 256, 0, stream>>>(mask, m2);
    maxpool_kernel<32, 16><<<dim3(2 * 4096 / 256),  256, 0, stream>>>(m2, m3);
    build_list_kernel<<<dim3(2 * 262144 / 256), 256, 0, stream>>>(mask, list, idx, cnt);

    // stage 1 (sparse, fp32)
    stage1a_kernel<<<dim3(2048), 64, 0, stream>>>(x, waT, list, cnt, t1c);
    stage1b_kernel<<<dim3(2048), 64, 0, stream>>>(t1c, x, wb4, wdTt, list, idx, cnt, x1c);
    wd1_kernel<<<dim3(128, 8, 2), 256, 0, stream>>>(x1c, idx, wd1T, xin2_h, xin2_l);

    // stage-1 scratch dead; clear R2/R3 (t2/x2 pads)
    hipMemsetAsync(R2, 0, RSZ, stream);
    hipMemsetAsync(R3, 0, RSZ, stream);

    // stage2 res block (MFMA): 2048 blocks each
    mfma_conv_kernel<128, 128, 32, 32, 1, 2, EPI_MASK | EPI_LEAKY>
        <<<dim3(2048, 1), 256, 0, stream>>>(xin2_h, xin2_l, pk2a_h, pk2a_l, m2,
                                            nullptr, nullptr, t2_h, t2_l);
    mfma_conv_kernel<128, 128, 32, 32, 1, 2, EPI_MASK | EPI_RESID | EPI_LEAKY>
        <<<dim3(2048, 1), 256, 0, stream>>>(t2_h, t2_l, pk2b_h, pk2b_l, m2,
                                            xin2_h, xin2_l, x2_h, x2_l);

    // xin2 dead -> clear xin3 area (stage-3 layout pads)
    hipMemsetAsync(R1, 0, 2 * A3HI, stream);
    mfma_conv_kernel<128, 256, 32, 16, 2, 2, EPI_LEAKY>
        <<<dim3(512, 2), 256, 0, stream>>>(x2_h, x2_l, pkd2_h, pkd2_l, nullptr,
                                           nullptr, nullptr, xin3_h, xin3_l);

    hipMemsetAsync(R2, 0, 2 * A3HI, stream);
    mfma_conv_kernel<256, 256, 16, 16, 1, 2, EPI_MASK | EPI_LEAKY>
        <<<dim3(512, 2), 256, 0, stream>>>(xin3_h, xin3_l, pk3a_h, pk3a_l, m3,
                                           nullptr, nullptr, t3_h, t3_l);

    hipMemsetAsync(R3, 0, 2 * A3HI, stream);
    mfma_conv_kernel<256, 256, 16, 16, 1, 2, EPI_MASK | EPI_RESID | EPI_LEAKY>
        <<<dim3(512, 2), 256, 0, stream>>>(t3_h, t3_l, pk3b_h, pk3b_l, m3,
                                           xin3_h, xin3_l, x3_h, x3_l);

    // wd3 (fp32 from hi/lo CL) -> partials in R2, then fused reduce
    wd3_kernel<<<dim3(1024), 256, 0, stream>>>(x3_h, x3_l, wd3, part);
    reduce_kernel<<<dim3(256), 64, 0, stream>>>(part, out);
}

// Round 6
// 3036.073 us; speedup vs baseline: 3.4646x; 1.0876x over previous
//
#include <hip/hip_runtime.h>

// ---------------------------------------------------------------------------
// SparseEncoderResUNet on MI355X — round 6: MFMA conv restructure.
// r5 diagnosis: latency/traffic-bound (MfmaUtil 16%, VALUBusy 9%, FETCH 275MB
// vs 38MB ideal). Fix: (a) RY=2 row-pairs per block, 4 waves share B frags;
// (b) NNF=RY*NX up to 4 -> loads/MFMA 0.67->0.375; (c) ci-tile outermost ->
// A working set per phase 432KB, L2-resident weights.
// Numerics: split-bf16, all 4 cross products (r5 measured absmax 0.0).
// Workspace map identical to r5 (126,688,256 B).
// ---------------------------------------------------------------------------

enum { EPI_MASK = 1, EPI_LEAKY = 2, EPI_RESID = 4 };
#define ROWCAP 32768

typedef short  bf16x8 __attribute__((ext_vector_type(8)));
typedef float  f32x4  __attribute__((ext_vector_type(4)));
typedef ushort us4    __attribute__((ext_vector_type(4)));

__device__ __forceinline__ float leaky(float v) { return v >= 0.f ? v : 0.2f * v; }
__device__ __forceinline__ ushort f2bf(float f) {
    unsigned u = __float_as_uint(f);
    return (ushort)((u + 0x7FFFu + ((u >> 16) & 1u)) >> 16);
}
__device__ __forceinline__ float bf2f(ushort h) {
    return __uint_as_float((unsigned)h << 16);
}

// ---------------- weight transpose: w[co][cik] -> wT[cik][co] ----------------
__global__ __launch_bounds__(256) void transpose_w_kernel(
    const float* __restrict__ w, float* __restrict__ wT, int CO, int CIK)
{
    int i = blockIdx.x * 256 + threadIdx.x;
    if (i >= CO * CIK) return;
    int co = i / CIK, r = i - co * CIK;
    wT[(size_t)r * CO + co] = w[i];
}

// interleaved-by-4 layout for stage1b
__global__ __launch_bounds__(256) void transpose_w4_kernel(
    const float* __restrict__ w, float* __restrict__ w4, int CO, int CIK)
{
    int i = blockIdx.x * 256 + threadIdx.x;
    if (i >= CO * CIK) return;
    int co = i / CIK, r = i - co * CIK;
    w4[(((size_t)(r >> 2) * CO) + co) * 4 + (r & 3)] = w[i];
}

// ---------------- pack weights into MFMA A-frag layout (hi/lo bf16) ----------
// out index i = (((tap*NCI + ct)*NMT + mt)*64 + L)*8 + j
//   co = mt*16 + (L&15),  ci = ct*32 + (L>>4)*8 + j,  w[co][ci][tap]
__global__ __launch_bounds__(256) void pack_w_kernel(
    const float* __restrict__ w, ushort* __restrict__ Ah, ushort* __restrict__ Al,
    int CI, int CO)
{
    int i = blockIdx.x * 256 + threadIdx.x;
    if (i >= 27 * CI * CO) return;
    int j = i & 7, L = (i >> 3) & 63, rest = i >> 9;
    int NMT = CO >> 4, NCI = CI >> 5;
    int mt = rest % NMT; rest /= NMT;
    int ct = rest % NCI;
    int tap = rest / NCI;
    int co = mt * 16 + (L & 15);
    int ci = ct * 32 + (L >> 4) * 8 + j;
    float v = w[((size_t)co * CI + ci) * 27 + tap];
    ushort h = f2bf(v);
    Ah[i] = h;
    Al[i] = f2bf(v - bf2f(h));
}

// ---------------- maxpool k3 s2 p1 (down_mask) ----------------
template<int DIN, int DOUT>
__global__ __launch_bounds__(256) void maxpool_kernel(
    const float* __restrict__ in, float* __restrict__ out)
{
    int i = blockIdx.x * 256 + threadIdx.x;
    constexpr int D3O = DOUT * DOUT * DOUT;
    if (i >= 2 * D3O) return;
    int b = i / D3O;
    int v = i - b * D3O;
    int z = v / (DOUT * DOUT), y = (v / DOUT) % DOUT, x = v % DOUT;
    float mx = 0.f;
    #pragma unroll
    for (int dz = 0; dz < 3; ++dz)
        #pragma unroll
        for (int dy = 0; dy < 3; ++dy)
            #pragma unroll
            for (int dx = 0; dx < 3; ++dx) {
                int zi = 2 * z - 1 + dz, yi = 2 * y - 1 + dy, xi = 2 * x - 1 + dx;
                if ((unsigned)zi < (unsigned)DIN && (unsigned)yi < (unsigned)DIN &&
                    (unsigned)xi < (unsigned)DIN)
                    mx = fmaxf(mx, in[(size_t)b * DIN * DIN * DIN + (zi * DIN + yi) * DIN + xi]);
            }
    out[i] = mx;
}

// ---------------- active-voxel list + dense index map ----------------
__global__ __launch_bounds__(256) void build_list_kernel(
    const float* __restrict__ m, int* __restrict__ list, int* __restrict__ idxmap,
    int* __restrict__ count)
{
    int i = blockIdx.x * 256 + threadIdx.x;
    if (i >= 2 * 262144) return;
    if (m[i] > 0.5f) {
        int k = atomicAdd(count, 1);
        if (k < ROWCAP) {
            list[k] = i;
            idxmap[i] = k;
        }
    }
}

// ---------------- stage1 conv-a (3->64, gathered) -> t1c[row][64] ----------------
__global__ __launch_bounds__(64) void stage1a_kernel(
    const float* __restrict__ x, const float* __restrict__ waT,
    const int* __restrict__ list, const int* __restrict__ count,
    float* __restrict__ t1c)
{
    __shared__ float smem[81];
    int n = min(*count, ROWCAP);
    for (int i = blockIdx.x; i < n; i += gridDim.x) {
        int lin = list[i];
        int b = lin >> 18;
        int v = lin & 262143;
        int z = v >> 12, y = (v >> 6) & 63, xx = v & 63;
        for (int j = threadIdx.x; j < 81; j += 64) {
            int ci = j / 27, t = j - ci * 27;
            int zz = z + t / 9 - 1, yy = y + (t / 3) % 3 - 1, xc = xx + t % 3 - 1;
            float val = 0.f;
            if ((unsigned)zz < 64u && (unsigned)yy < 64u && (unsigned)xc < 64u)
                val = x[(size_t)(b * 3 + ci) * 262144 + (zz << 12) + (yy << 6) + xc];
            smem[j] = val;
        }
        __syncthreads();
        float acc = 0.f;
        #pragma unroll 9
        for (int j = 0; j < 81; ++j)
            acc = fmaf(smem[j], waT[j * 64 + threadIdx.x], acc);
        t1c[(size_t)i * 64 + threadIdx.x] = leaky(acc);
        __syncthreads();
    }
}

// ---------------- stage1 conv-b (64->64, gathered) + 1x1 identity ----------------
__global__ __launch_bounds__(64) void stage1b_kernel(
    const float* __restrict__ t1c, const float* __restrict__ x,
    const float* __restrict__ wb4, const float* __restrict__ wdT,
    const int* __restrict__ list, const int* __restrict__ idxmap,
    const int* __restrict__ count,
    float* __restrict__ x1c)
{
    __shared__ float sw[4 * 1728];
    int n = min(*count, ROWCAP);
    int nq = (n + 3) >> 2;
    for (int q = blockIdx.x; q < nq; q += gridDim.x) {
        for (int vv = 0; vv < 4; ++vv) {
            int i = q * 4 + vv;
            int lin = (i < n) ? list[i] : list[0];
            int b = lin >> 18;
            int v = lin & 262143;
            int z = v >> 12, y = (v >> 6) & 63, xx = v & 63;
            const int* im = idxmap + b * 262144;
            #pragma unroll
            for (int t = 0; t < 27; ++t) {
                int zz = z + t / 9 - 1, yy = y + (t / 3) % 3 - 1, xc = xx + t % 3 - 1;
                float val = 0.f;
                if ((unsigned)zz < 64u && (unsigned)yy < 64u && (unsigned)xc < 64u) {
                    int r = im[(zz << 12) + (yy << 6) + xc];
                    if (r >= 0)
                        val = t1c[(size_t)r * 64 + threadIdx.x];
                }
                sw[vv * 1728 + threadIdx.x * 27 + t] = val;
            }
        }
        __syncthreads();
        float acc[4] = {0.f, 0.f, 0.f, 0.f};
        const float* wp = wb4 + threadIdx.x * 4;
        for (int j4 = 0; j4 < 432; ++j4) {
            float4 w = *(const float4*)(wp + (size_t)j4 * 256);
            #pragma unroll
            for (int vv = 0; vv < 4; ++vv) {
                float4 s = *(const float4*)(&sw[vv * 1728 + j4 * 4]);
                acc[vv] = fmaf(s.x, w.x, acc[vv]);
                acc[vv] = fmaf(s.y, w.y, acc[vv]);
                acc[vv] = fmaf(s.z, w.z, acc[vv]);
                acc[vv] = fmaf(s.w, w.w, acc[vv]);
            }
        }
        #pragma unroll
        for (int vv = 0; vv < 4; ++vv) {
            int i = q * 4 + vv;
            if (i < n) {
                int lin = list[i];
                int b = lin >> 18;
                int v = lin & 262143;
                float id = 0.f;
                #pragma unroll
                for (int ci = 0; ci < 3; ++ci)
                    id = fmaf(x[(size_t)(b * 3 + ci) * 262144 + v], wdT[ci * 64 + threadIdx.x], id);
                x1c[(size_t)i * 64 + threadIdx.x] = leaky(acc[vv] + id);
            }
        }
        __syncthreads();
    }
}

// ---------------- wd1: gather-conv -> channel-last padded hi/lo bf16 ----------
// out layout: [2][32][32][33][128] + 128 lead; writes interior x only.
__global__ __launch_bounds__(256) void wd1_kernel(
    const float* __restrict__ x1c, const int* __restrict__ idxmap,
    const float* __restrict__ wT,   // [64*27][128]
    ushort* __restrict__ out_hi, ushort* __restrict__ out_lo)
{
    constexpr int CO_T = 16;
    int v = blockIdx.x * 256 + threadIdx.x;
    int b = blockIdx.z;
    int cog = blockIdx.y * CO_T;
    int zo = v >> 10, yo = (v >> 5) & 31, xo = v & 31;
    float acc[CO_T];
    #pragma unroll
    for (int j = 0; j < CO_T; ++j) acc[j] = 0.f;
    const int* im = idxmap + b * 262144;

    #pragma unroll
    for (int kz = 0; kz < 3; ++kz) {
        int zi = 2 * zo - 1 + kz;
        #pragma unroll
        for (int ky = 0; ky < 3; ++ky) {
            int yi = 2 * yo - 1 + ky;
            #pragma unroll
            for (int kx = 0; kx < 3; ++kx) {
                int xi = 2 * xo - 1 + kx;
                int r = -1;
                if ((unsigned)zi < 64u && (unsigned)yi < 64u && (unsigned)xi < 64u)
                    r = im[(zi << 12) + (yi << 6) + xi];
                if (r >= 0) {
                    const float* xr = x1c + (size_t)r * 64;
                    int tap = kz * 9 + ky * 3 + kx;
                    for (int ci = 0; ci < 64; ci += 4) {
                        float4 xv = *(const float4*)(xr + ci);
                        const float4* w0 = (const float4*)(wT + (size_t)((ci + 0) * 27 + tap) * 128 + cog);
                        const float4* w1 = (const float4*)(wT + (size_t)((ci + 1) * 27 + tap) * 128 + cog);
                        const float4* w2 = (const float4*)(wT + (size_t)((ci + 2) * 27 + tap) * 128 + cog);
                        const float4* w3 = (const float4*)(wT + (size_t)((ci + 3) * 27 + tap) * 128 + cog);
                        #pragma unroll
                        for (int j4 = 0; j4 < CO_T / 4; ++j4) {
                            float4 a0 = w0[j4], a1 = w1[j4], a2 = w2[j4], a3 = w3[j4];
                            float* ac = &acc[j4 * 4];
                            ac[0] = fmaf(xv.x, a0.x, ac[0]); ac[1] = fmaf(xv.x, a0.y, ac[1]);
                            ac[2] = fmaf(xv.x, a0.z, ac[2]); ac[3] = fmaf(xv.x, a0.w, ac[3]);
                            ac[0] = fmaf(xv.y, a1.x, ac[0]); ac[1] = fmaf(xv.y, a1.y, ac[1]);
                            ac[2] = fmaf(xv.y, a1.z, ac[2]); ac[3] = fmaf(xv.y, a1.w, ac[3]);
                            ac[0] = fmaf(xv.z, a2.x, ac[0]); ac[1] = fmaf(xv.z, a2.y, ac[1]);
                            ac[2] = fmaf(xv.z, a2.z, ac[2]); ac[3] = fmaf(xv.z, a2.w, ac[3]);
                            ac[0] = fmaf(xv.w, a3.x, ac[0]); ac[1] = fmaf(xv.w, a3.y, ac[1]);
                            ac[2] = fmaf(xv.w, a3.z, ac[2]); ac[3] = fmaf(xv.w, a3.w, ac[3]);
                        }
                    }
                }
            }
        }
    }
    size_t oa = ((((size_t)b * 32 + zo) * 32 + yo) * 33 + xo) * 128 + 128 + cog;
    #pragma unroll
    for (int g = 0; g < 4; ++g) {
        us4 h, l;
        #pragma unroll
        for (int r = 0; r < 4; ++r) {
            float val = leaky(acc[g * 4 + r]);
            ushort hb = f2bf(val);
            h[r] = hb;
            l[r] = f2bf(val - bf2f(hb));
        }
        *(us4*)(out_hi + oa + g * 4) = h;
        *(us4*)(out_lo + oa + g * 4) = l;
    }
}

// ---------------- MFMA implicit-GEMM conv v2 (split-bf16, 4 products) --------
// in : CL padded-x hi/lo [B][DI][DI][DI+1][CI] + CI lead
// out: CL padded-x hi/lo [B][DO][DO][DO+1][CO] + CO lead
// A  : packed frags [27][CI/32][CO/16][64][8] hi/lo
// Block = 4 waves covering the SAME RY output rows (B frags shared via L1);
// wave handles NCT co-tiles x RY rows x NX x-frags. ct loop outermost so the
// concurrent A working set stays small (L2-resident).
template<int CI, int CO, int DI, int DO, int S, int RY, int NX, int NCT, int EPI>
__global__ __launch_bounds__(256) void mfma_conv2_kernel(
    const ushort* __restrict__ in_hi, const ushort* __restrict__ in_lo,
    const ushort* __restrict__ Ah, const ushort* __restrict__ Al,
    const float* __restrict__ mask,
    const ushort* __restrict__ rh_, const ushort* __restrict__ rl_,
    ushort* __restrict__ out_hi, ushort* __restrict__ out_lo)
{
    constexpr int NCI = CI / 32;
    constexpr int NMT = CO / 16;
    constexpr int YG = DO / RY;
    const int rg = blockIdx.x;
    const int y0 = (rg % YG) * RY;
    const int z = (rg / YG) % DO;
    const int b = rg / (YG * DO);
    const int wave = threadIdx.x >> 6;
    const int lane = threadIdx.x & 63;
    const int n_l = lane & 15;
    const int q = lane >> 4;
    const int mt0 = (blockIdx.y * 4 + wave) * NCT;

    f32x4 acc[NCT][RY][NX];
    #pragma unroll
    for (int a = 0; a < NCT; ++a)
        #pragma unroll
        for (int r = 0; r < RY; ++r)
            #pragma unroll
            for (int c = 0; c < NX; ++c)
                acc[a][r][c] = (f32x4){0.f, 0.f, 0.f, 0.f};

    const bf16x8 zero8 = {0, 0, 0, 0, 0, 0, 0, 0};

    for (int ct = 0; ct < NCI; ++ct) {
        #pragma unroll
        for (int dz = 0; dz < 3; ++dz) {
            int zp = z * S + dz - 1;
            if ((unsigned)zp >= (unsigned)DI) continue;
            #pragma unroll
            for (int dy = 0; dy < 3; ++dy) {
                size_t rowb[RY];
                bool vy[RY];
                #pragma unroll
                for (int ry = 0; ry < RY; ++ry) {
                    int yp = (y0 + ry) * S + dy - 1;
                    vy[ry] = (unsigned)yp < (unsigned)DI;
                    rowb[ry] = ((((size_t)b * DI + zp) * DI + (vy[ry] ? yp : 0)) * (DI + 1)) * CI + CI;
                }
                #pragma unroll
                for (int dx = 0; dx < 3; ++dx) {
                    const int tap = dz * 9 + dy * 3 + dx;
                    bf16x8 bh[RY][NX], bl[RY][NX];
                    #pragma unroll
                    for (int ry = 0; ry < RY; ++ry)
                        #pragma unroll
                        for (int nx = 0; nx < NX; ++nx) {
                            if (vy[ry]) {
                                int xp = (nx * 16 + n_l) * S + dx - 1;
                                size_t ba = rowb[ry] + (size_t)xp * CI + ct * 32 + q * 8;
                                bh[ry][nx] = *(const bf16x8*)(in_hi + ba);
                                bl[ry][nx] = *(const bf16x8*)(in_lo + ba);
                            } else {
                                bh[ry][nx] = zero8;
                                bl[ry][nx] = zero8;
                            }
                        }
                    #pragma unroll
                    for (int mt = 0; mt < NCT; ++mt) {
                        size_t aa = ((size_t)(tap * NCI + ct) * NMT + (mt0 + mt)) * 512 + lane * 8;
                        bf16x8 ahf = *(const bf16x8*)(Ah + aa);
                        bf16x8 alf = *(const bf16x8*)(Al + aa);
                        #pragma unroll
                        for (int ry = 0; ry < RY; ++ry)
                            #pragma unroll
                            for (int nx = 0; nx < NX; ++nx) {
                                acc[mt][ry][nx] = __builtin_amdgcn_mfma_f32_16x16x32_bf16(ahf, bh[ry][nx], acc[mt][ry][nx], 0, 0, 0);
                                acc[mt][ry][nx] = __builtin_amdgcn_mfma_f32_16x16x32_bf16(ahf, bl[ry][nx], acc[mt][ry][nx], 0, 0, 0);
                                acc[mt][ry][nx] = __builtin_amdgcn_mfma_f32_16x16x32_bf16(alf, bh[ry][nx], acc[mt][ry][nx], 0, 0, 0);
                                acc[mt][ry][nx] = __builtin_amdgcn_mfma_f32_16x16x32_bf16(alf, bl[ry][nx], acc[mt][ry][nx], 0, 0, 0);
                            }
                    }
                }
            }
        }
    }

    // epilogue: C/D layout col(n)=lane&15, row(m within 16) = q*4 + reg
    #pragma unroll
    for (int ry = 0; ry < RY; ++ry) {
        int yo = y0 + ry;
        const size_t orowb = ((((size_t)b * DO + z) * DO + yo) * (DO + 1)) * CO + CO;
        #pragma unroll
        for (int nx = 0; nx < NX; ++nx) {
            int xo = nx * 16 + n_l;
            float mval = 1.f;
            if (EPI & EPI_MASK) mval = mask[(((size_t)b * DO + z) * DO + yo) * DO + xo];
            #pragma unroll
            for (int mt = 0; mt < NCT; ++mt) {
                size_t oa = orowb + (size_t)xo * CO + (mt0 + mt) * 16 + q * 4;
                float rs[4] = {0.f, 0.f, 0.f, 0.f};
                if (EPI & EPI_RESID) {
                    us4 rh4 = *(const us4*)(rh_ + oa);
                    us4 rl4 = *(const us4*)(rl_ + oa);
                    #pragma unroll
                    for (int r = 0; r < 4; ++r) rs[r] = bf2f(rh4[r]) + bf2f(rl4[r]);
                }
                us4 oh, ol;
                #pragma unroll
                for (int r = 0; r < 4; ++r) {
                    float v = acc[mt][ry][nx][r];
                    if (EPI & EPI_MASK) v *= mval;
                    if (EPI & EPI_RESID) v += rs[r];
                    if (EPI & EPI_LEAKY) v = leaky(v);
                    ushort hb = f2bf(v);
                    oh[r] = hb;
                    ol[r] = f2bf(v - bf2f(hb));
                }
                *(us4*)(out_hi + oa) = oh;
                *(us4*)(out_lo + oa) = ol;
            }
        }
    }
}

// ---------------- wd3: fp32 split-K conv from hi/lo CL x3 ----------------
__global__ __launch_bounds__(256) void wd3_kernel(
    const ushort* __restrict__ xh, const ushort* __restrict__ xl,
    const float* __restrict__ w, float* __restrict__ part)
{
    int gid = blockIdx.x * 256 + threadIdx.x;     // 262144 threads
    int v = gid & 511;
    int c4 = (gid >> 9) & 31;
    int b = (gid >> 14) & 1;
    int kc = gid >> 15;                           // 0..7
    int x = v & 7, y = (v >> 3) & 7, z = v >> 6;
    int cog = c4 * 4;
    float acc[4] = {0.f, 0.f, 0.f, 0.f};
    const float* wb = w + (size_t)cog * 6912 + (size_t)(kc * 32) * 27;

    for (int dz = 0; dz < 3; ++dz) {
        int zp = 2 * z + dz - 1;
        if ((unsigned)zp >= 16u) continue;
        for (int dy = 0; dy < 3; ++dy) {
            int yp = 2 * y + dy - 1;
            if ((unsigned)yp >= 16u) continue;
            const size_t rowb = ((((size_t)b * 16 + zp) * 16 + yp) * 17) * 256 + 256;
            for (int dx = 0; dx < 3; ++dx) {
                int xp = 2 * x + dx - 1;           // padded: always valid
                int tap = dz * 9 + dy * 3 + dx;
                const size_t base = rowb + (size_t)xp * 256 + kc * 32;
                #pragma unroll 4
                for (int ci = 0; ci < 32; ++ci) {
                    float xv = bf2f(xh[base + ci]) + bf2f(xl[base + ci]);
                    #pragma unroll
                    for (int j = 0; j < 4; ++j)
                        acc[j] = fmaf(xv, wb[(size_t)j * 6912 + ci * 27 + tap], acc[j]);
                }
            }
        }
    }
    #pragma unroll
    for (int j = 0; j < 4; ++j)
        part[(((size_t)kc * 2 + b) * 128 + cog + j) * 512 + v] = acc[j];
}

// ---------------- final: sum 8 partials + leaky + mean/max pool over 8^3 ------
__global__ __launch_bounds__(64) void reduce_kernel(
    const float* __restrict__ part, float* __restrict__ out)
{
    int bc = blockIdx.x;
    int b = bc >> 7, c = bc & 127;
    const float* p = part + (size_t)(b * 128 + c) * 512;
    float s = 0.f, mx = -3.4e38f;
    for (int i = threadIdx.x; i < 512; i += 64) {
        float v = 0.f;
        #pragma unroll
        for (int k = 0; k < 8; ++k) v += p[(size_t)k * 131072 + i];
        v = leaky(v);
        s += v;
        mx = fmaxf(mx, v);
    }
    #pragma unroll
    for (int o = 32; o > 0; o >>= 1) {
        s += __shfl_down(s, o);
        mx = fmaxf(mx, __shfl_down(mx, o));
    }
    if (threadIdx.x == 0) {
        out[b * 256 + c] = s * (1.f / 512.f);
        out[b * 256 + 128 + c] = mx;
    }
}

__global__ __launch_bounds__(256) void zero_out_kernel(float* __restrict__ out, int n)
{
    int i = blockIdx.x * 256 + threadIdx.x;
    if (i < n) out[i] = 0.f;
}

// ---------------------------------------------------------------------------
extern "C" void kernel_launch(void* const* d_in, const int* in_sizes, int n_in,
                              void* d_out, int out_size, void* d_ws, size_t ws_size,
                              hipStream_t stream)
{
    (void)in_sizes; (void)n_in;
    const float* x    = (const float*)d_in[0];
    const float* mask = (const float*)d_in[1];
    const float* w1a  = (const float*)d_in[2];
    const float* w1b  = (const float*)d_in[3];
    const float* w1d  = (const float*)d_in[4];
    const float* wd1  = (const float*)d_in[5];
    const float* w2a  = (const float*)d_in[6];
    const float* w2b  = (const float*)d_in[7];
    const float* wd2  = (const float*)d_in[8];
    const float* w3a  = (const float*)d_in[9];
    const float* w3b  = (const float*)d_in[10];
    const float* wd3  = (const float*)d_in[11];
    float* out = (float*)d_out;
    char* ws = (char*)d_ws;

    const size_t RSZ   = 34603520;     // one stage-2 region (hi+lo)
    const size_t A2HI  = 17301760;     // hi->lo offset within stage-2 region
    const size_t A3HI  = 4456960;      // hi->lo offset within stage-3 tensor
    char* R1 = ws;
    char* R2 = ws + RSZ;
    char* R3 = ws + 2 * RSZ;
    size_t off = 3 * RSZ;
    auto alloc = [&](size_t bytes) { char* p = ws + off; off = (off + bytes + 255) & ~255ull; return p; };
    ushort* pk2a_h = (ushort*)alloc(884736);
    ushort* pk2a_l = (ushort*)alloc(884736);
    ushort* pk2b_h = (ushort*)alloc(884736);
    ushort* pk2b_l = (ushort*)alloc(884736);
    ushort* pkd2_h = (ushort*)alloc(1769472);
    ushort* pkd2_l = (ushort*)alloc(1769472);
    ushort* pk3a_h = (ushort*)alloc(3538944);
    ushort* pk3a_l = (ushort*)alloc(3538944);
    ushort* pk3b_h = (ushort*)alloc(3538944);
    ushort* pk3b_l = (ushort*)alloc(3538944);
    float*  wd1T   = (float*)alloc(884736);
    float*  waT    = (float*)alloc(20736);
    float*  wb4    = (float*)alloc(442368);
    float*  wdTt   = (float*)alloc(768);
    float*  m2     = (float*)alloc(262144);
    float*  m3     = (float*)alloc(32768);
    int*    cnt    = (int*)alloc(256);
    const size_t NEED = off;

    if (ws_size < NEED) {
        zero_out_kernel<<<dim3((out_size + 255) / 256), 256, 0, stream>>>(out, out_size);
        return;
    }

    // stage-1 scratch aliased into R2 (dead before t2 is written)
    float* t1c  = (float*)R2;
    float* x1c  = (float*)(R2 + 8388608);
    int*   idx  = (int*)(R2 + 16777216);
    int*   list = (int*)(R2 + 18874368);
    // wd3 partials aliased into R2 (t3 dead by then)
    float* part = (float*)R2;

    ushort* xin2_h = (ushort*)R1;             ushort* xin2_l = (ushort*)(R1 + A2HI);
    ushort* t2_h   = (ushort*)R2;             ushort* t2_l   = (ushort*)(R2 + A2HI);
    ushort* x2_h   = (ushort*)R3;             ushort* x2_l   = (ushort*)(R3 + A2HI);
    ushort* xin3_h = (ushort*)R1;             ushort* xin3_l = (ushort*)(R1 + A3HI);
    ushort* t3_h   = (ushort*)R2;             ushort* t3_l   = (ushort*)(R2 + A3HI);
    ushort* x3_h   = (ushort*)R3;             ushort* x3_l   = (ushort*)(R3 + A3HI);

    hipMemsetAsync(cnt, 0, 4, stream);
    hipMemsetAsync(idx, 0xFF, 2097152, stream);
    hipMemsetAsync(R1, 0, RSZ, stream);           // xin2 pads

    auto tg = [](int n) { return dim3((n + 255) / 256); };
    pack_w_kernel<<<tg(27 * 128 * 128), 256, 0, stream>>>(w2a, pk2a_h, pk2a_l, 128, 128);
    pack_w_kernel<<<tg(27 * 128 * 128), 256, 0, stream>>>(w2b, pk2b_h, pk2b_l, 128, 128);
    pack_w_kernel<<<tg(27 * 128 * 256), 256, 0, stream>>>(wd2, pkd2_h, pkd2_l, 128, 256);
    pack_w_kernel<<<tg(27 * 256 * 256), 256, 0, stream>>>(w3a, pk3a_h, pk3a_l, 256, 256);
    pack_w_kernel<<<tg(27 * 256 * 256), 256, 0, stream>>>(w3b, pk3b_h, pk3b_l, 256, 256);
    transpose_w_kernel <<<tg(128 * 1728), 256, 0, stream>>>(wd1, wd1T, 128, 1728);
    transpose_w_kernel <<<tg(64 * 81),    256, 0, stream>>>(w1a, waT,  64, 81);
    transpose_w4_kernel<<<tg(64 * 1728),  256, 0, stream>>>(w1b, wb4,  64, 1728);
    transpose_w_kernel <<<tg(64 * 3),     256, 0, stream>>>(w1d, wdTt, 64, 3);

    maxpool_kernel<64, 32><<<dim3(2 * 32768 / 256), 256, 0, stream>>>(mask, m2);
    maxpool_kernel<32, 16><<<dim3(2 * 4096 / 256),  256, 0, stream>>>(m2, m3);
    build_list_kernel<<<dim3(2 * 262144 / 256), 256, 0, stream>>>(mask, list, idx, cnt);

    // stage 1 (sparse, fp32)
    stage1a_kernel<<<dim3(2048), 64, 0, stream>>>(x, waT, list, cnt, t1c);
    stage1b_kernel<<<dim3(2048), 64, 0, stream>>>(t1c, x, wb4, wdTt, list, idx, cnt, x1c);
    wd1_kernel<<<dim3(128, 8, 2), 256, 0, stream>>>(x1c, idx, wd1T, xin2_h, xin2_l);

    // stage-1 scratch dead; clear R2/R3 (t2/x2 pads)
    hipMemsetAsync(R2, 0, RSZ, stream);
    hipMemsetAsync(R3, 0, RSZ, stream);

    // stage2 res block: block = 2 rows x all 128 co; grid 1024
    mfma_conv2_kernel<128, 128, 32, 32, 1, 2, 2, 2, EPI_MASK | EPI_LEAKY>
        <<<dim3(1024, 1), 256, 0, stream>>>(xin2_h, xin2_l, pk2a_h, pk2a_l, m2,
                                            nullptr, nullptr, t2_h, t2_l);
    mfma_conv2_kernel<128, 128, 32, 32, 1, 2, 2, 2, EPI_MASK | EPI_RESID | EPI_LEAKY>
        <<<dim3(1024, 1), 256, 0, stream>>>(t2_h, t2_l, pk2b_h, pk2b_l, m2,
                                            xin2_h, xin2_l, x2_h, x2_l);

    // xin2 dead -> clear xin3 area (stage-3 layout pads)
    hipMemsetAsync(R1, 0, 2 * A3HI, stream);
    // wd2: block = 2 rows x 128 co (half), grid (256,2)
    mfma_conv2_kernel<128, 256, 32, 16, 2, 2, 1, 2, EPI_LEAKY>
        <<<dim3(256, 2), 256, 0, stream>>>(x2_h, x2_l, pkd2_h, pkd2_l, nullptr,
                                           nullptr, nullptr, xin3_h, xin3_l);

    hipMemsetAsync(R2, 0, 2 * A3HI, stream);
    mfma_conv2_kernel<256, 256, 16, 16, 1, 2, 1, 2, EPI_MASK | EPI_LEAKY>
        <<<dim3(256, 2), 256, 0, stream>>>(xin3_h, xin3_l, pk3a_h, pk3a_l, m3,
                                           nullptr, nullptr, t3_h, t3_l);

    hipMemsetAsync(R3, 0, 2 * A3HI, stream);
    mfma_conv2_kernel<256, 256, 16, 16, 1, 2, 1, 2, EPI_MASK | EPI_RESID | EPI_LEAKY>
        <<<dim3(256, 2), 256, 0, stream>>>(t3_h, t3_l, pk3b_h, pk3b_l, m3,
                                           xin3_h, xin3_l, x3_h, x3_l);

    // wd3 (fp32 from hi/lo CL) -> partials in R2, then fused reduce
    wd3_kernel<<<dim3(1024), 256, 0, stream>>>(x3_h, x3_l, wd3, part);
    reduce_kernel<<<dim3(256), 64, 0, stream>>>(part, out);
}

// Round 7
// 2696.403 us; speedup vs baseline: 3.9010x; 1.1260x over previous
//
#include <hip/hip_runtime.h>

// ---------------------------------------------------------------------------
// SparseEncoderResUNet on MI355X — round 7: wd3 onto MFMA.
// r6 diagnosis: wd3_kernel 500us (16% of total) at 3.6TF — per-lane scattered
// fp32 weight reads. Fix: pack wd3 weights into MFMA A-frag layout (into R1,
// dead after conv3b) and run a dedicated split-bf16 MFMA GEMM (N-frag = 2 y
// rows x 8 x), writing fp32 x4 directly; reduce becomes a pure pool.
// Everything else unchanged from r6 (2.9ms, absmax 0).
// ---------------------------------------------------------------------------

enum { EPI_MASK = 1, EPI_LEAKY = 2, EPI_RESID = 4 };
#define ROWCAP 32768

typedef short  bf16x8 __attribute__((ext_vector_type(8)));
typedef float  f32x4  __attribute__((ext_vector_type(4)));
typedef ushort us4    __attribute__((ext_vector_type(4)));

__device__ __forceinline__ float leaky(float v) { return v >= 0.f ? v : 0.2f * v; }
__device__ __forceinline__ ushort f2bf(float f) {
    unsigned u = __float_as_uint(f);
    return (ushort)((u + 0x7FFFu + ((u >> 16) & 1u)) >> 16);
}
__device__ __forceinline__ float bf2f(ushort h) {
    return __uint_as_float((unsigned)h << 16);
}

// ---------------- weight transpose: w[co][cik] -> wT[cik][co] ----------------
__global__ __launch_bounds__(256) void transpose_w_kernel(
    const float* __restrict__ w, float* __restrict__ wT, int CO, int CIK)
{
    int i = blockIdx.x * 256 + threadIdx.x;
    if (i >= CO * CIK) return;
    int co = i / CIK, r = i - co * CIK;
    wT[(size_t)r * CO + co] = w[i];
}

// interleaved-by-4 layout for stage1b
__global__ __launch_bounds__(256) void transpose_w4_kernel(
    const float* __restrict__ w, float* __restrict__ w4, int CO, int CIK)
{
    int i = blockIdx.x * 256 + threadIdx.x;
    if (i >= CO * CIK) return;
    int co = i / CIK, r = i - co * CIK;
    w4[(((size_t)(r >> 2) * CO) + co) * 4 + (r & 3)] = w[i];
}

// ---------------- pack weights into MFMA A-frag layout (hi/lo bf16) ----------
// out index i = (((tap*NCI + ct)*NMT + mt)*64 + L)*8 + j
//   co = mt*16 + (L&15),  ci = ct*32 + (L>>4)*8 + j,  w[co][ci][tap]
__global__ __launch_bounds__(256) void pack_w_kernel(
    const float* __restrict__ w, ushort* __restrict__ Ah, ushort* __restrict__ Al,
    int CI, int CO)
{
    int i = blockIdx.x * 256 + threadIdx.x;
    if (i >= 27 * CI * CO) return;
    int j = i & 7, L = (i >> 3) & 63, rest = i >> 9;
    int NMT = CO >> 4, NCI = CI >> 5;
    int mt = rest % NMT; rest /= NMT;
    int ct = rest % NCI;
    int tap = rest / NCI;
    int co = mt * 16 + (L & 15);
    int ci = ct * 32 + (L >> 4) * 8 + j;
    float v = w[((size_t)co * CI + ci) * 27 + tap];
    ushort h = f2bf(v);
    Ah[i] = h;
    Al[i] = f2bf(v - bf2f(h));
}

// ---------------- maxpool k3 s2 p1 (down_mask) ----------------
template<int DIN, int DOUT>
__global__ __launch_bounds__(256) void maxpool_kernel(
    const float* __restrict__ in, float* __restrict__ out)
{
    int i = blockIdx.x * 256 + threadIdx.x;
    constexpr int D3O = DOUT * DOUT * DOUT;
    if (i >= 2 * D3O) return;
    int b = i / D3O;
    int v = i - b * D3O;
    int z = v / (DOUT * DOUT), y = (v / DOUT) % DOUT, x = v % DOUT;
    float mx = 0.f;
    #pragma unroll
    for (int dz = 0; dz < 3; ++dz)
        #pragma unroll
        for (int dy = 0; dy < 3; ++dy)
            #pragma unroll
            for (int dx = 0; dx < 3; ++dx) {
                int zi = 2 * z - 1 + dz, yi = 2 * y - 1 + dy, xi = 2 * x - 1 + dx;
                if ((unsigned)zi < (unsigned)DIN && (unsigned)yi < (unsigned)DIN &&
                    (unsigned)xi < (unsigned)DIN)
                    mx = fmaxf(mx, in[(size_t)b * DIN * DIN * DIN + (zi * DIN + yi) * DIN + xi]);
            }
    out[i] = mx;
}

// ---------------- active-voxel list + dense index map ----------------
__global__ __launch_bounds__(256) void build_list_kernel(
    const float* __restrict__ m, int* __restrict__ list, int* __restrict__ idxmap,
    int* __restrict__ count)
{
    int i = blockIdx.x * 256 + threadIdx.x;
    if (i >= 2 * 262144) return;
    if (m[i] > 0.5f) {
        int k = atomicAdd(count, 1);
        if (k < ROWCAP) {
            list[k] = i;
            idxmap[i] = k;
        }
    }
}

// ---------------- stage1 conv-a (3->64, gathered) -> t1c[row][64] ----------------
__global__ __launch_bounds__(64) void stage1a_kernel(
    const float* __restrict__ x, const float* __restrict__ waT,
    const int* __restrict__ list, const int* __restrict__ count,
    float* __restrict__ t1c)
{
    __shared__ float smem[81];
    int n = min(*count, ROWCAP);
    for (int i = blockIdx.x; i < n; i += gridDim.x) {
        int lin = list[i];
        int b = lin >> 18;
        int v = lin & 262143;
        int z = v >> 12, y = (v >> 6) & 63, xx = v & 63;
        for (int j = threadIdx.x; j < 81; j += 64) {
            int ci = j / 27, t = j - ci * 27;
            int zz = z + t / 9 - 1, yy = y + (t / 3) % 3 - 1, xc = xx + t % 3 - 1;
            float val = 0.f;
            if ((unsigned)zz < 64u && (unsigned)yy < 64u && (unsigned)xc < 64u)
                val = x[(size_t)(b * 3 + ci) * 262144 + (zz << 12) + (yy << 6) + xc];
            smem[j] = val;
        }
        __syncthreads();
        float acc = 0.f;
        #pragma unroll 9
        for (int j = 0; j < 81; ++j)
            acc = fmaf(smem[j], waT[j * 64 + threadIdx.x], acc);
        t1c[(size_t)i * 64 + threadIdx.x] = leaky(acc);
        __syncthreads();
    }
}

// ---------------- stage1 conv-b (64->64, gathered) + 1x1 identity ----------------
__global__ __launch_bounds__(64) void stage1b_kernel(
    const float* __restrict__ t1c, const float* __restrict__ x,
    const float* __restrict__ wb4, const float* __restrict__ wdT,
    const int* __restrict__ list, const int* __restrict__ idxmap,
    const int* __restrict__ count,
    float* __restrict__ x1c)
{
    __shared__ float sw[4 * 1728];
    int n = min(*count, ROWCAP);
    int nq = (n + 3) >> 2;
    for (int q = blockIdx.x; q < nq; q += gridDim.x) {
        for (int vv = 0; vv < 4; ++vv) {
            int i = q * 4 + vv;
            int lin = (i < n) ? list[i] : list[0];
            int b = lin >> 18;
            int v = lin & 262143;
            int z = v >> 12, y = (v >> 6) & 63, xx = v & 63;
            const int* im = idxmap + b * 262144;
            #pragma unroll
            for (int t = 0; t < 27; ++t) {
                int zz = z + t / 9 - 1, yy = y + (t / 3) % 3 - 1, xc = xx + t % 3 - 1;
                float val = 0.f;
                if ((unsigned)zz < 64u && (unsigned)yy < 64u && (unsigned)xc < 64u) {
                    int r = im[(zz << 12) + (yy << 6) + xc];
                    if (r >= 0)
                        val = t1c[(size_t)r * 64 + threadIdx.x];
                }
                sw[vv * 1728 + threadIdx.x * 27 + t] = val;
            }
        }
        __syncthreads();
        float acc[4] = {0.f, 0.f, 0.f, 0.f};
        const float* wp = wb4 + threadIdx.x * 4;
        for (int j4 = 0; j4 < 432; ++j4) {
            float4 w = *(const float4*)(wp + (size_t)j4 * 256);
            #pragma unroll
            for (int vv = 0; vv < 4; ++vv) {
                float4 s = *(const float4*)(&sw[vv * 1728 + j4 * 4]);
                acc[vv] = fmaf(s.x, w.x, acc[vv]);
                acc[vv] = fmaf(s.y, w.y, acc[vv]);
                acc[vv] = fmaf(s.z, w.z, acc[vv]);
                acc[vv] = fmaf(s.w, w.w, acc[vv]);
            }
        }
        #pragma unroll
        for (int vv = 0; vv < 4; ++vv) {
            int i = q * 4 + vv;
            if (i < n) {
                int lin = list[i];
                int b = lin >> 18;
                int v = lin & 262143;
                float id = 0.f;
                #pragma unroll
                for (int ci = 0; ci < 3; ++ci)
                    id = fmaf(x[(size_t)(b * 3 + ci) * 262144 + v], wdT[ci * 64 + threadIdx.x], id);
                x1c[(size_t)i * 64 + threadIdx.x] = leaky(acc[vv] + id);
            }
        }
        __syncthreads();
    }
}

// ---------------- wd1: gather-conv -> channel-last padded hi/lo bf16 ----------
__global__ __launch_bounds__(256) void wd1_kernel(
    const float* __restrict__ x1c, const int* __restrict__ idxmap,
    const float* __restrict__ wT,   // [64*27][128]
    ushort* __restrict__ out_hi, ushort* __restrict__ out_lo)
{
    constexpr int CO_T = 16;
    int v = blockIdx.x * 256 + threadIdx.x;
    int b = blockIdx.z;
    int cog = blockIdx.y * CO_T;
    int zo = v >> 10, yo = (v >> 5) & 31, xo = v & 31;
    float acc[CO_T];
    #pragma unroll
    for (int j = 0; j < CO_T; ++j) acc[j] = 0.f;
    const int* im = idxmap + b * 262144;

    #pragma unroll
    for (int kz = 0; kz < 3; ++kz) {
        int zi = 2 * zo - 1 + kz;
        #pragma unroll
        for (int ky = 0; ky < 3; ++ky) {
            int yi = 2 * yo - 1 + ky;
            #pragma unroll
            for (int kx = 0; kx < 3; ++kx) {
                int xi = 2 * xo - 1 + kx;
                int r = -1;
                if ((unsigned)zi < 64u && (unsigned)yi < 64u && (unsigned)xi < 64u)
                    r = im[(zi << 12) + (yi << 6) + xi];
                if (r >= 0) {
                    const float* xr = x1c + (size_t)r * 64;
                    int tap = kz * 9 + ky * 3 + kx;
                    for (int ci = 0; ci < 64; ci += 4) {
                        float4 xv = *(const float4*)(xr + ci);
                        const float4* w0 = (const float4*)(wT + (size_t)((ci + 0) * 27 + tap) * 128 + cog);
                        const float4* w1 = (const float4*)(wT + (size_t)((ci + 1) * 27 + tap) * 128 + cog);
                        const float4* w2 = (const float4*)(wT + (size_t)((ci + 2) * 27 + tap) * 128 + cog);
                        const float4* w3 = (const float4*)(wT + (size_t)((ci + 3) * 27 + tap) * 128 + cog);
                        #pragma unroll
                        for (int j4 = 0; j4 < CO_T / 4; ++j4) {
                            float4 a0 = w0[j4], a1 = w1[j4], a2 = w2[j4], a3 = w3[j4];
                            float* ac = &acc[j4 * 4];
                            ac[0] = fmaf(xv.x, a0.x, ac[0]); ac[1] = fmaf(xv.x, a0.y, ac[1]);
                            ac[2] = fmaf(xv.x, a0.z, ac[2]); ac[3] = fmaf(xv.x, a0.w, ac[3]);
                            ac[0] = fmaf(xv.y, a1.x, ac[0]); ac[1] = fmaf(xv.y, a1.y, ac[1]);
                            ac[2] = fmaf(xv.y, a1.z, ac[2]); ac[3] = fmaf(xv.y, a1.w, ac[3]);
                            ac[0] = fmaf(xv.z, a2.x, ac[0]); ac[1] = fmaf(xv.z, a2.y, ac[1]);
                            ac[2] = fmaf(xv.z, a2.z, ac[2]); ac[3] = fmaf(xv.z, a2.w, ac[3]);
                            ac[0] = fmaf(xv.w, a3.x, ac[0]); ac[1] = fmaf(xv.w, a3.y, ac[1]);
                            ac[2] = fmaf(xv.w, a3.z, ac[2]); ac[3] = fmaf(xv.w, a3.w, ac[3]);
                        }
                    }
                }
            }
        }
    }
    size_t oa = ((((size_t)b * 32 + zo) * 32 + yo) * 33 + xo) * 128 + 128 + cog;
    #pragma unroll
    for (int g = 0; g < 4; ++g) {
        us4 h, l;
        #pragma unroll
        for (int r = 0; r < 4; ++r) {
            float val = leaky(acc[g * 4 + r]);
            ushort hb = f2bf(val);
            h[r] = hb;
            l[r] = f2bf(val - bf2f(hb));
        }
        *(us4*)(out_hi + oa + g * 4) = h;
        *(us4*)(out_lo + oa + g * 4) = l;
    }
}

// ---------------- MFMA implicit-GEMM conv v2 (split-bf16, 4 products) --------
template<int CI, int CO, int DI, int DO, int S, int RY, int NX, int NCT, int EPI>
__global__ __launch_bounds__(256) void mfma_conv2_kernel(
    const ushort* __restrict__ in_hi, const ushort* __restrict__ in_lo,
    const ushort* __restrict__ Ah, const ushort* __restrict__ Al,
    const float* __restrict__ mask,
    const ushort* __restrict__ rh_, const ushort* __restrict__ rl_,
    ushort* __restrict__ out_hi, ushort* __restrict__ out_lo)
{
    constexpr int NCI = CI / 32;
    constexpr int NMT = CO / 16;
    constexpr int YG = DO / RY;
    const int rg = blockIdx.x;
    const int y0 = (rg % YG) * RY;
    const int z = (rg / YG) % DO;
    const int b = rg / (YG * DO);
    const int wave = threadIdx.x >> 6;
    const int lane = threadIdx.x & 63;
    const int n_l = lane & 15;
    const int q = lane >> 4;
    const int mt0 = (blockIdx.y * 4 + wave) * NCT;

    f32x4 acc[NCT][RY][NX];
    #pragma unroll
    for (int a = 0; a < NCT; ++a)
        #pragma unroll
        for (int r = 0; r < RY; ++r)
            #pragma unroll
            for (int c = 0; c < NX; ++c)
                acc[a][r][c] = (f32x4){0.f, 0.f, 0.f, 0.f};

    const bf16x8 zero8 = {0, 0, 0, 0, 0, 0, 0, 0};

    for (int ct = 0; ct < NCI; ++ct) {
        #pragma unroll
        for (int dz = 0; dz < 3; ++dz) {
            int zp = z * S + dz - 1;
            if ((unsigned)zp >= (unsigned)DI) continue;
            #pragma unroll
            for (int dy = 0; dy < 3; ++dy) {
                size_t rowb[RY];
                bool vy[RY];
                #pragma unroll
                for (int ry = 0; ry < RY; ++ry) {
                    int yp = (y0 + ry) * S + dy - 1;
                    vy[ry] = (unsigned)yp < (unsigned)DI;
                    rowb[ry] = ((((size_t)b * DI + zp) * DI + (vy[ry] ? yp : 0)) * (DI + 1)) * CI + CI;
                }
                #pragma unroll
                for (int dx = 0; dx < 3; ++dx) {
                    const int tap = dz * 9 + dy * 3 + dx;
                    bf16x8 bh[RY][NX], bl[RY][NX];
                    #pragma unroll
                    for (int ry = 0; ry < RY; ++ry)
                        #pragma unroll
                        for (int nx = 0; nx < NX; ++nx) {
                            if (vy[ry]) {
                                int xp = (nx * 16 + n_l) * S + dx - 1;
                                size_t ba = rowb[ry] + (size_t)xp * CI + ct * 32 + q * 8;
                                bh[ry][nx] = *(const bf16x8*)(in_hi + ba);
                                bl[ry][nx] = *(const bf16x8*)(in_lo + ba);
                            } else {
                                bh[ry][nx] = zero8;
                                bl[ry][nx] = zero8;
                            }
                        }
                    #pragma unroll
                    for (int mt = 0; mt < NCT; ++mt) {
                        size_t aa = ((size_t)(tap * NCI + ct) * NMT + (mt0 + mt)) * 512 + lane * 8;
                        bf16x8 ahf = *(const bf16x8*)(Ah + aa);
                        bf16x8 alf = *(const bf16x8*)(Al + aa);
                        #pragma unroll
                        for (int ry = 0; ry < RY; ++ry)
                            #pragma unroll
                            for (int nx = 0; nx < NX; ++nx) {
                                acc[mt][ry][nx] = __builtin_amdgcn_mfma_f32_16x16x32_bf16(ahf, bh[ry][nx], acc[mt][ry][nx], 0, 0, 0);
                                acc[mt][ry][nx] = __builtin_amdgcn_mfma_f32_16x16x32_bf16(ahf, bl[ry][nx], acc[mt][ry][nx], 0, 0, 0);
                                acc[mt][ry][nx] = __builtin_amdgcn_mfma_f32_16x16x32_bf16(alf, bh[ry][nx], acc[mt][ry][nx], 0, 0, 0);
                                acc[mt][ry][nx] = __builtin_amdgcn_mfma_f32_16x16x32_bf16(alf, bl[ry][nx], acc[mt][ry][nx], 0, 0, 0);
                            }
                    }
                }
            }
        }
    }

    #pragma unroll
    for (int ry = 0; ry < RY; ++ry) {
        int yo = y0 + ry;
        const size_t orowb = ((((size_t)b * DO + z) * DO + yo) * (DO + 1)) * CO + CO;
        #pragma unroll
        for (int nx = 0; nx < NX; ++nx) {
            int xo = nx * 16 + n_l;
            float mval = 1.f;
            if (EPI & EPI_MASK) mval = mask[(((size_t)b * DO + z) * DO + yo) * DO + xo];
            #pragma unroll
            for (int mt = 0; mt < NCT; ++mt) {
                size_t oa = orowb + (size_t)xo * CO + (mt0 + mt) * 16 + q * 4;
                float rs[4] = {0.f, 0.f, 0.f, 0.f};
                if (EPI & EPI_RESID) {
                    us4 rh4 = *(const us4*)(rh_ + oa);
                    us4 rl4 = *(const us4*)(rl_ + oa);
                    #pragma unroll
                    for (int r = 0; r < 4; ++r) rs[r] = bf2f(rh4[r]) + bf2f(rl4[r]);
                }
                us4 oh, ol;
                #pragma unroll
                for (int r = 0; r < 4; ++r) {
                    float v = acc[mt][ry][nx][r];
                    if (EPI & EPI_MASK) v *= mval;
                    if (EPI & EPI_RESID) v += rs[r];
                    if (EPI & EPI_LEAKY) v = leaky(v);
                    ushort hb = f2bf(v);
                    oh[r] = hb;
                    ol[r] = f2bf(v - bf2f(hb));
                }
                *(us4*)(out_hi + oa) = oh;
                *(us4*)(out_lo + oa) = ol;
            }
        }
    }
}

// ---------------- wd3 via MFMA: x3 CL hi/lo -> x4 fp32 [2][128][512] ----------
// N-frag col n = (y&1)*8 + x (2 output y-rows x 8 x). Grid 64 blocks:
// blk = b*32 + z*4 + yg. 4 waves x 2 M-tiles = all 128 co.
__global__ __launch_bounds__(256) void wd3_mfma_kernel(
    const ushort* __restrict__ xh, const ushort* __restrict__ xl,
    const ushort* __restrict__ Ah, const ushort* __restrict__ Al,
    float* __restrict__ x4)
{
    constexpr int NCI = 8;   // 256/32
    constexpr int NMT = 8;   // 128/16
    const int blk = blockIdx.x;
    const int yg = blk & 3;
    const int z = (blk >> 2) & 7;
    const int b = blk >> 5;
    const int wave = threadIdx.x >> 6;
    const int lane = threadIdx.x & 63;
    const int n_l = lane & 15;
    const int q = lane >> 4;
    const int y = yg * 2 + (n_l >> 3);
    const int x = n_l & 7;
    const int mt0 = wave * 2;

    f32x4 acc[2];
    acc[0] = (f32x4){0.f, 0.f, 0.f, 0.f};
    acc[1] = (f32x4){0.f, 0.f, 0.f, 0.f};
    const bf16x8 zero8 = {0, 0, 0, 0, 0, 0, 0, 0};

    for (int ct = 0; ct < NCI; ++ct) {
        #pragma unroll
        for (int dz = 0; dz < 3; ++dz) {
            int zp = 2 * z + dz - 1;
            if ((unsigned)zp >= 16u) continue;            // wave-uniform
            #pragma unroll
            for (int dy = 0; dy < 3; ++dy) {
                int yp = 2 * y + dy - 1;
                bool vy = (unsigned)yp < 16u;             // per-lane
                int ypc = vy ? yp : 0;
                #pragma unroll
                for (int dx = 0; dx < 3; ++dx) {
                    int xp = 2 * x + dx - 1;              // [-1,15]; lead slot pads
                    int tap = dz * 9 + dy * 3 + dx;
                    size_t ba = ((((size_t)b * 16 + zp) * 16 + ypc) * 17 + 1 + xp) * 256
                              + ct * 32 + q * 8;
                    bf16x8 bh = vy ? *(const bf16x8*)(xh + ba) : zero8;
                    bf16x8 bl = vy ? *(const bf16x8*)(xl + ba) : zero8;
                    #pragma unroll
                    for (int mt = 0; mt < 2; ++mt) {
                        size_t aa = ((size_t)(tap * NCI + ct) * NMT + (mt0 + mt)) * 512 + lane * 8;
                        bf16x8 ahf = *(const bf16x8*)(Ah + aa);
                        bf16x8 alf = *(const bf16x8*)(Al + aa);
                        acc[mt] = __builtin_amdgcn_mfma_f32_16x16x32_bf16(ahf, bh, acc[mt], 0, 0, 0);
                        acc[mt] = __builtin_amdgcn_mfma_f32_16x16x32_bf16(ahf, bl, acc[mt], 0, 0, 0);
                        acc[mt] = __builtin_amdgcn_mfma_f32_16x16x32_bf16(alf, bh, acc[mt], 0, 0, 0);
                        acc[mt] = __builtin_amdgcn_mfma_f32_16x16x32_bf16(alf, bl, acc[mt], 0, 0, 0);
                    }
                }
            }
        }
    }
    #pragma unroll
    for (int mt = 0; mt < 2; ++mt)
        #pragma unroll
        for (int r = 0; r < 4; ++r) {
            int co = (mt0 + mt) * 16 + q * 4 + r;
            x4[((size_t)(b * 128 + co)) * 512 + z * 64 + y * 8 + x] = leaky(acc[mt][r]);
        }
}

// ---------------- final: mean/max pool over 8^3 (leaky already applied) -------
__global__ __launch_bounds__(64) void reduce_kernel(
    const float* __restrict__ x4, float* __restrict__ out)
{
    int bc = blockIdx.x;
    int b = bc >> 7, c = bc & 127;
    const float* p = x4 + (size_t)(b * 128 + c) * 512;
    float s = 0.f, mx = -3.4e38f;
    for (int i = threadIdx.x; i < 512; i += 64) {
        float v = p[i];
        s += v;
        mx = fmaxf(mx, v);
    }
    #pragma unroll
    for (int o = 32; o > 0; o >>= 1) {
        s += __shfl_down(s, o);
        mx = fmaxf(mx, __shfl_down(mx, o));
    }
    if (threadIdx.x == 0) {
        out[b * 256 + c] = s * (1.f / 512.f);
        out[b * 256 + 128 + c] = mx;
    }
}

__global__ __launch_bounds__(256) void zero_out_kernel(float* __restrict__ out, int n)
{
    int i = blockIdx.x * 256 + threadIdx.x;
    if (i < n) out[i] = 0.f;
}

// ---------------------------------------------------------------------------
extern "C" void kernel_launch(void* const* d_in, const int* in_sizes, int n_in,
                              void* d_out, int out_size, void* d_ws, size_t ws_size,
                              hipStream_t stream)
{
    (void)in_sizes; (void)n_in;
    const float* x    = (const float*)d_in[0];
    const float* mask = (const float*)d_in[1];
    const float* w1a  = (const float*)d_in[2];
    const float* w1b  = (const float*)d_in[3];
    const float* w1d  = (const float*)d_in[4];
    const float* wd1  = (const float*)d_in[5];
    const float* w2a  = (const float*)d_in[6];
    const float* w2b  = (const float*)d_in[7];
    const float* wd2  = (const float*)d_in[8];
    const float* w3a  = (const float*)d_in[9];
    const float* w3b  = (const float*)d_in[10];
    const float* wd3  = (const float*)d_in[11];
    float* out = (float*)d_out;
    char* ws = (char*)d_ws;

    const size_t RSZ   = 34603520;     // one stage-2 region (hi+lo)
    const size_t A2HI  = 17301760;     // hi->lo offset within stage-2 region
    const size_t A3HI  = 4456960;      // hi->lo offset within stage-3 tensor
    char* R1 = ws;
    char* R2 = ws + RSZ;
    char* R3 = ws + 2 * RSZ;
    size_t off = 3 * RSZ;
    auto alloc = [&](size_t bytes) { char* p = ws + off; off = (off + bytes + 255) & ~255ull; return p; };
    ushort* pk2a_h = (ushort*)alloc(884736);
    ushort* pk2a_l = (ushort*)alloc(884736);
    ushort* pk2b_h = (ushort*)alloc(884736);
    ushort* pk2b_l = (ushort*)alloc(884736);
    ushort* pkd2_h = (ushort*)alloc(1769472);
    ushort* pkd2_l = (ushort*)alloc(1769472);
    ushort* pk3a_h = (ushort*)alloc(3538944);
    ushort* pk3a_l = (ushort*)alloc(3538944);
    ushort* pk3b_h = (ushort*)alloc(3538944);
    ushort* pk3b_l = (ushort*)alloc(3538944);
    float*  wd1T   = (float*)alloc(884736);
    float*  waT    = (float*)alloc(20736);
    float*  wb4    = (float*)alloc(442368);
    float*  wdTt   = (float*)alloc(768);
    float*  m2     = (float*)alloc(262144);
    float*  m3     = (float*)alloc(32768);
    int*    cnt    = (int*)alloc(256);
    const size_t NEED = off;

    if (ws_size < NEED) {
        zero_out_kernel<<<dim3((out_size + 255) / 256), 256, 0, stream>>>(out, out_size);
        return;
    }

    // stage-1 scratch aliased into R2 (dead before t2 is written)
    float* t1c  = (float*)R2;
    float* x1c  = (float*)(R2 + 8388608);
    int*   idx  = (int*)(R2 + 16777216);
    int*   list = (int*)(R2 + 18874368);
    // late-phase aliases: wd3 packed weights -> R1 (xin3 dead after conv3b);
    // x4 fp32 -> R2 (t3 dead after conv3b)
    ushort* pkd3_h = (ushort*)R1;
    ushort* pkd3_l = (ushort*)(R1 + 1769472);
    float*  x4     = (float*)R2;

    ushort* xin2_h = (ushort*)R1;             ushort* xin2_l = (ushort*)(R1 + A2HI);
    ushort* t2_h   = (ushort*)R2;             ushort* t2_l   = (ushort*)(R2 + A2HI);
    ushort* x2_h   = (ushort*)R3;             ushort* x2_l   = (ushort*)(R3 + A2HI);
    ushort* xin3_h = (ushort*)R1;             ushort* xin3_l = (ushort*)(R1 + A3HI);
    ushort* t3_h   = (ushort*)R2;             ushort* t3_l   = (ushort*)(R2 + A3HI);
    ushort* x3_h   = (ushort*)R3;             ushort* x3_l   = (ushort*)(R3 + A3HI);

    hipMemsetAsync(cnt, 0, 4, stream);
    hipMemsetAsync(idx, 0xFF, 2097152, stream);
    hipMemsetAsync(R1, 0, RSZ, stream);           // xin2 pads

    auto tg = [](int n) { return dim3((n + 255) / 256); };
    pack_w_kernel<<<tg(27 * 128 * 128), 256, 0, stream>>>(w2a, pk2a_h, pk2a_l, 128, 128);
    pack_w_kernel<<<tg(27 * 128 * 128), 256, 0, stream>>>(w2b, pk2b_h, pk2b_l, 128, 128);
    pack_w_kernel<<<tg(27 * 128 * 256), 256, 0, stream>>>(wd2, pkd2_h, pkd2_l, 128, 256);
    pack_w_kernel<<<tg(27 * 256 * 256), 256, 0, stream>>>(w3a, pk3a_h, pk3a_l, 256, 256);
    pack_w_kernel<<<tg(27 * 256 * 256), 256, 0, stream>>>(w3b, pk3b_h, pk3b_l, 256, 256);
    transpose_w_kernel <<<tg(128 * 1728), 256, 0, stream>>>(wd1, wd1T, 128, 1728);
    transpose_w_kernel <<<tg(64 * 81),    256, 0, stream>>>(w1a, waT,  64, 81);
    transpose_w4_kernel<<<tg(64 * 1728),  256, 0, stream>>>(w1b, wb4,  64, 1728);
    transpose_w_kernel <<<tg(64 * 3),     256, 0, stream>>>(w1d, wdTt, 64, 3);

    maxpool_kernel<64, 32><<<dim3(2 * 32768 / 256), 256, 0, stream>>>(mask, m2);
    maxpool_kernel<32, 16><<<dim3(2 * 4096 / 256),  256, 0, stream>>>(m2, m3);
    build_list_kernel<<<dim3(2 * 262144 / 256), 256, 0, stream>>>(mask, list, idx, cnt);

    // stage 1 (sparse, fp32)
    stage1a_kernel<<<dim3(2048), 64, 0, stream>>>(x, waT, list, cnt, t1c);
    stage1b_kernel<<<dim3(2048), 64, 0, stream>>>(t1c, x, wb4, wdTt, list, idx, cnt, x1c);
    wd1_kernel<<<dim3(128, 8, 2), 256, 0, stream>>>(x1c, idx, wd1T, xin2_h, xin2_l);

    // stage-1 scratch dead; clear R2/R3 (t2/x2 pads)
    hipMemsetAsync(R2, 0, RSZ, stream);
    hipMemsetAsync(R3, 0, RSZ, stream);

    // stage2 res block
    mfma_conv2_kernel<128, 128, 32, 32, 1, 2, 2, 2, EPI_MASK | EPI_LEAKY>
        <<<dim3(1024, 1), 256, 0, stream>>>(xin2_h, xin2_l, pk2a_h, pk2a_l, m2,
                                            nullptr, nullptr, t2_h, t2_l);
    mfma_conv2_kernel<128, 128, 32, 32, 1, 2, 2, 2, EPI_MASK | EPI_RESID | EPI_LEAKY>
        <<<dim3(1024, 1), 256, 0, stream>>>(t2_h, t2_l, pk2b_h, pk2b_l, m2,
                                            xin2_h, xin2_l, x2_h, x2_l);

    // xin2 dead -> clear xin3 area
    hipMemsetAsync(R1, 0, 2 * A3HI, stream);
    mfma_conv2_kernel<128, 256, 32, 16, 2, 2, 1, 2, EPI_LEAKY>
        <<<dim3(256, 2), 256, 0, stream>>>(x2_h, x2_l, pkd2_h, pkd2_l, nullptr,
                                           nullptr, nullptr, xin3_h, xin3_l);

    hipMemsetAsync(R2, 0, 2 * A3HI, stream);
    mfma_conv2_kernel<256, 256, 16, 16, 1, 2, 1, 2, EPI_MASK | EPI_LEAKY>
        <<<dim3(256, 2), 256, 0, stream>>>(xin3_h, xin3_l, pk3a_h, pk3a_l, m3,
                                           nullptr, nullptr, t3_h, t3_l);

    hipMemsetAsync(R3, 0, 2 * A3HI, stream);
    mfma_conv2_kernel<256, 256, 16, 16, 1, 2, 1, 2, EPI_MASK | EPI_RESID | EPI_LEAKY>
        <<<dim3(256, 2), 256, 0, stream>>>(t3_h, t3_l, pk3b_h, pk3b_l, m3,
                                           xin3_h, xin3_l, x3_h, x3_l);

    // xin3 (R1) and t3 (R2) dead: pack wd3 weights into R1, run MFMA wd3 -> x4 (R2)
    pack_w_kernel<<<tg(27 * 256 * 128), 256, 0, stream>>>(wd3, pkd3_h, pkd3_l, 256, 128);
    wd3_mfma_kernel<<<dim3(64), 256, 0, stream>>>(x3_h, x3_l, pkd3_h, pkd3_l, x4);

    reduce_kernel<<<dim3(256), 64, 0, stream>>>(x4, out);
}

// Round 8
// 2647.758 us; speedup vs baseline: 3.9727x; 1.0184x over previous
//
#include <hip/hip_runtime.h>

// ---------------------------------------------------------------------------
// SparseEncoderResUNet on MI355X — round 8: interleaved hi/lo + 3-product.
// r7 diagnosis: MFMA convs latency-bound (MfmaUtil 19%, VALU 9%); hi/lo split
// in separate planes doubles cacheline touches per fragment; wd1 probe chain
// serialized. Fixes:
//  (a) activations + packed weights store hi/lo interleaved per 8 channels
//      ([ct][q][8hi][8lo]) -> both loads of a fragment share one 64B line;
//  (b) drop al*bl product (3 MFMAs; residual ~2^-16 rel, threshold 7.8e-3);
//  (c) wd1: all 27 idxmap probes hoisted before FMA blocks.
// Workspace map as r7 (126.7 MB).
// ---------------------------------------------------------------------------

enum { EPI_MASK = 1, EPI_LEAKY = 2, EPI_RESID = 4 };
#define ROWCAP 32768

typedef short  bf16x8 __attribute__((ext_vector_type(8)));
typedef float  f32x4  __attribute__((ext_vector_type(4)));
typedef ushort us4    __attribute__((ext_vector_type(4)));

__device__ __forceinline__ float leaky(float v) { return v >= 0.f ? v : 0.2f * v; }
__device__ __forceinline__ ushort f2bf(float f) {
    unsigned u = __float_as_uint(f);
    return (ushort)((u + 0x7FFFu + ((u >> 16) & 1u)) >> 16);
}
__device__ __forceinline__ float bf2f(ushort h) {
    return __uint_as_float((unsigned)h << 16);
}
// channel c -> offset within a voxel's CI*2 block (interleaved hi/lo by 8)
__device__ __forceinline__ int choff(int c) {
    return (c >> 5) * 64 + ((c >> 3) & 3) * 16 + (c & 7);
}

// ---------------- weight transpose: w[co][cik] -> wT[cik][co] ----------------
__global__ __launch_bounds__(256) void transpose_w_kernel(
    const float* __restrict__ w, float* __restrict__ wT, int CO, int CIK)
{
    int i = blockIdx.x * 256 + threadIdx.x;
    if (i >= CO * CIK) return;
    int co = i / CIK, r = i - co * CIK;
    wT[(size_t)r * CO + co] = w[i];
}

// interleaved-by-4 layout for stage1b
__global__ __launch_bounds__(256) void transpose_w4_kernel(
    const float* __restrict__ w, float* __restrict__ w4, int CO, int CIK)
{
    int i = blockIdx.x * 256 + threadIdx.x;
    if (i >= CO * CIK) return;
    int co = i / CIK, r = i - co * CIK;
    w4[(((size_t)(r >> 2) * CO) + co) * 4 + (r & 3)] = w[i];
}

// ---------------- pack weights into MFMA A-frag layout, hi/lo interleaved ----
// out[i], i = (((tap*NCI+ct)*NMT+mt)*64 + L)*16 + hilo*8 + j
//   co = mt*16 + (L&15),  ci = ct*32 + (L>>4)*8 + j
__global__ __launch_bounds__(256) void pack_w_kernel(
    const float* __restrict__ w, ushort* __restrict__ A, int CI, int CO)
{
    int i = blockIdx.x * 256 + threadIdx.x;
    if (i >= 27 * CI * CO * 2) return;
    int j = i & 7, hilo = (i >> 3) & 1, L = (i >> 4) & 63, rest = i >> 10;
    int NMT = CO >> 4, NCI = CI >> 5;
    int mt = rest % NMT; rest /= NMT;
    int ct = rest % NCI;
    int tap = rest / NCI;
    int co = mt * 16 + (L & 15);
    int ci = ct * 32 + (L >> 4) * 8 + j;
    float v = w[((size_t)co * CI + ci) * 27 + tap];
    ushort h = f2bf(v);
    A[i] = hilo ? f2bf(v - bf2f(h)) : h;
}

// ---------------- maxpool k3 s2 p1 (down_mask) ----------------
template<int DIN, int DOUT>
__global__ __launch_bounds__(256) void maxpool_kernel(
    const float* __restrict__ in, float* __restrict__ out)
{
    int i = blockIdx.x * 256 + threadIdx.x;
    constexpr int D3O = DOUT * DOUT * DOUT;
    if (i >= 2 * D3O) return;
    int b = i / D3O;
    int v = i - b * D3O;
    int z = v / (DOUT * DOUT), y = (v / DOUT) % DOUT, x = v % DOUT;
    float mx = 0.f;
    #pragma unroll
    for (int dz = 0; dz < 3; ++dz)
        #pragma unroll
        for (int dy = 0; dy < 3; ++dy)
            #pragma unroll
            for (int dx = 0; dx < 3; ++dx) {
                int zi = 2 * z - 1 + dz, yi = 2 * y - 1 + dy, xi = 2 * x - 1 + dx;
                if ((unsigned)zi < (unsigned)DIN && (unsigned)yi < (unsigned)DIN &&
                    (unsigned)xi < (unsigned)DIN)
                    mx = fmaxf(mx, in[(size_t)b * DIN * DIN * DIN + (zi * DIN + yi) * DIN + xi]);
            }
    out[i] = mx;
}

// ---------------- active-voxel list + dense index map ----------------
__global__ __launch_bounds__(256) void build_list_kernel(
    const float* __restrict__ m, int* __restrict__ list, int* __restrict__ idxmap,
    int* __restrict__ count)
{
    int i = blockIdx.x * 256 + threadIdx.x;
    if (i >= 2 * 262144) return;
    if (m[i] > 0.5f) {
        int k = atomicAdd(count, 1);
        if (k < ROWCAP) {
            list[k] = i;
            idxmap[i] = k;
        }
    }
}

// ---------------- stage1 conv-a (3->64, gathered) -> t1c[row][64] ----------------
__global__ __launch_bounds__(64) void stage1a_kernel(
    const float* __restrict__ x, const float* __restrict__ waT,
    const int* __restrict__ list, const int* __restrict__ count,
    float* __restrict__ t1c)
{
    __shared__ float smem[81];
    int n = min(*count, ROWCAP);
    for (int i = blockIdx.x; i < n; i += gridDim.x) {
        int lin = list[i];
        int b = lin >> 18;
        int v = lin & 262143;
        int z = v >> 12, y = (v >> 6) & 63, xx = v & 63;
        for (int j = threadIdx.x; j < 81; j += 64) {
            int ci = j / 27, t = j - ci * 27;
            int zz = z + t / 9 - 1, yy = y + (t / 3) % 3 - 1, xc = xx + t % 3 - 1;
            float val = 0.f;
            if ((unsigned)zz < 64u && (unsigned)yy < 64u && (unsigned)xc < 64u)
                val = x[(size_t)(b * 3 + ci) * 262144 + (zz << 12) + (yy << 6) + xc];
            smem[j] = val;
        }
        __syncthreads();
        float acc = 0.f;
        #pragma unroll 9
        for (int j = 0; j < 81; ++j)
            acc = fmaf(smem[j], waT[j * 64 + threadIdx.x], acc);
        t1c[(size_t)i * 64 + threadIdx.x] = leaky(acc);
        __syncthreads();
    }
}

// ---------------- stage1 conv-b (64->64, gathered) + 1x1 identity ----------------
__global__ __launch_bounds__(64) void stage1b_kernel(
    const float* __restrict__ t1c, const float* __restrict__ x,
    const float* __restrict__ wb4, const float* __restrict__ wdT,
    const int* __restrict__ list, const int* __restrict__ idxmap,
    const int* __restrict__ count,
    float* __restrict__ x1c)
{
    __shared__ float sw[4 * 1728];
    int n = min(*count, ROWCAP);
    int nq = (n + 3) >> 2;
    for (int q = blockIdx.x; q < nq; q += gridDim.x) {
        for (int vv = 0; vv < 4; ++vv) {
            int i = q * 4 + vv;
            int lin = (i < n) ? list[i] : list[0];
            int b = lin >> 18;
            int v = lin & 262143;
            int z = v >> 12, y = (v >> 6) & 63, xx = v & 63;
            const int* im = idxmap + b * 262144;
            #pragma unroll
            for (int t = 0; t < 27; ++t) {
                int zz = z + t / 9 - 1, yy = y + (t / 3) % 3 - 1, xc = xx + t % 3 - 1;
                float val = 0.f;
                if ((unsigned)zz < 64u && (unsigned)yy < 64u && (unsigned)xc < 64u) {
                    int r = im[(zz << 12) + (yy << 6) + xc];
                    if (r >= 0)
                        val = t1c[(size_t)r * 64 + threadIdx.x];
                }
                sw[vv * 1728 + threadIdx.x * 27 + t] = val;
            }
        }
        __syncthreads();
        float acc[4] = {0.f, 0.f, 0.f, 0.f};
        const float* wp = wb4 + threadIdx.x * 4;
        for (int j4 = 0; j4 < 432; ++j4) {
            float4 w = *(const float4*)(wp + (size_t)j4 * 256);
            #pragma unroll
            for (int vv = 0; vv < 4; ++vv) {
                float4 s = *(const float4*)(&sw[vv * 1728 + j4 * 4]);
                acc[vv] = fmaf(s.x, w.x, acc[vv]);
                acc[vv] = fmaf(s.y, w.y, acc[vv]);
                acc[vv] = fmaf(s.z, w.z, acc[vv]);
                acc[vv] = fmaf(s.w, w.w, acc[vv]);
            }
        }
        #pragma unroll
        for (int vv = 0; vv < 4; ++vv) {
            int i = q * 4 + vv;
            if (i < n) {
                int lin = list[i];
                int b = lin >> 18;
                int v = lin & 262143;
                float id = 0.f;
                #pragma unroll
                for (int ci = 0; ci < 3; ++ci)
                    id = fmaf(x[(size_t)(b * 3 + ci) * 262144 + v], wdT[ci * 64 + threadIdx.x], id);
                x1c[(size_t)i * 64 + threadIdx.x] = leaky(acc[vv] + id);
            }
        }
        __syncthreads();
    }
}

// ---------------- wd1: gather-conv -> CL padded interleaved hi/lo -------------
// out: [2][32][32][33][256] + 256 lead (ushorts), per-voxel ch layout = choff.
__global__ __launch_bounds__(256) void wd1_kernel(
    const float* __restrict__ x1c, const int* __restrict__ idxmap,
    const float* __restrict__ wT,   // [64*27][128]
    ushort* __restrict__ outp)
{
    constexpr int CO_T = 16;
    int v = blockIdx.x * 256 + threadIdx.x;
    int b = blockIdx.z;
    int cog = blockIdx.y * CO_T;
    int zo = v >> 10, yo = (v >> 5) & 31, xo = v & 31;
    float acc[CO_T];
    #pragma unroll
    for (int j = 0; j < CO_T; ++j) acc[j] = 0.f;
    const int* im = idxmap + b * 262144;

    // hoist all 27 probes (independent loads in flight together)
    int rr[27];
    #pragma unroll
    for (int t = 0; t < 27; ++t) {
        int kz = t / 9, ky = (t / 3) % 3, kx = t % 3;
        int zi = 2 * zo - 1 + kz, yi = 2 * yo - 1 + ky, xi = 2 * xo - 1 + kx;
        rr[t] = -1;
        if ((unsigned)zi < 64u && (unsigned)yi < 64u && (unsigned)xi < 64u)
            rr[t] = im[(zi << 12) + (yi << 6) + xi];
    }

    #pragma unroll
    for (int t = 0; t < 27; ++t) {
        int r = rr[t];
        if (r >= 0) {
            const float* xr = x1c + (size_t)r * 64;
            for (int ci = 0; ci < 64; ci += 4) {
                float4 xv = *(const float4*)(xr + ci);
                const float4* w0 = (const float4*)(wT + (size_t)((ci + 0) * 27 + t) * 128 + cog);
                const float4* w1 = (const float4*)(wT + (size_t)((ci + 1) * 27 + t) * 128 + cog);
                const float4* w2 = (const float4*)(wT + (size_t)((ci + 2) * 27 + t) * 128 + cog);
                const float4* w3 = (const float4*)(wT + (size_t)((ci + 3) * 27 + t) * 128 + cog);
                #pragma unroll
                for (int j4 = 0; j4 < CO_T / 4; ++j4) {
                    float4 a0 = w0[j4], a1 = w1[j4], a2 = w2[j4], a3 = w3[j4];
                    float* ac = &acc[j4 * 4];
                    ac[0] = fmaf(xv.x, a0.x, ac[0]); ac[1] = fmaf(xv.x, a0.y, ac[1]);
                    ac[2] = fmaf(xv.x, a0.z, ac[2]); ac[3] = fmaf(xv.x, a0.w, ac[3]);
                    ac[0] = fmaf(xv.y, a1.x, ac[0]); ac[1] = fmaf(xv.y, a1.y, ac[1]);
                    ac[2] = fmaf(xv.y, a1.z, ac[2]); ac[3] = fmaf(xv.y, a1.w, ac[3]);
                    ac[0] = fmaf(xv.z, a2.x, ac[0]); ac[1] = fmaf(xv.z, a2.y, ac[1]);
                    ac[2] = fmaf(xv.z, a2.z, ac[2]); ac[3] = fmaf(xv.z, a2.w, ac[3]);
                    ac[0] = fmaf(xv.w, a3.x, ac[0]); ac[1] = fmaf(xv.w, a3.y, ac[1]);
                    ac[2] = fmaf(xv.w, a3.z, ac[2]); ac[3] = fmaf(xv.w, a3.w, ac[3]);
                }
            }
        }
    }
    size_t vb = ((((size_t)b * 32 + zo) * 32 + yo) * 33 + xo) * 256 + 256;
    #pragma unroll
    for (int g = 0; g < 4; ++g) {
        int c0 = cog + g * 4;
        int off = choff(c0);
        us4 h, l;
        #pragma unroll
        for (int r = 0; r < 4; ++r) {
            float val = leaky(acc[g * 4 + r]);
            ushort hb = f2bf(val);
            h[r] = hb;
            l[r] = f2bf(val - bf2f(hb));
        }
        *(us4*)(outp + vb + off) = h;
        *(us4*)(outp + vb + off + 8) = l;
    }
}

// ---------------- MFMA implicit-GEMM conv v3 (3-product, interleaved) --------
// in : [B][DI][DI][DI+1][CI*2] + CI*2 lead (interleaved hi/lo per 8 ch)
// out: same scheme with CO
// A  : [27][CI/32][CO/16][64][16] interleaved
template<int CI, int CO, int DI, int DO, int S, int RY, int NX, int NCT, int EPI>
__global__ __launch_bounds__(256) void mfma_conv3_kernel(
    const ushort* __restrict__ inp, const ushort* __restrict__ A,
    const float* __restrict__ mask, const ushort* __restrict__ resid,
    ushort* __restrict__ outp)
{
    constexpr int NCI = CI / 32;
    constexpr int NMT = CO / 16;
    constexpr int CV = CI * 2;
    constexpr int CVO = CO * 2;
    constexpr int YG = DO / RY;
    const int rg = blockIdx.x;
    const int y0 = (rg % YG) * RY;
    const int z = (rg / YG) % DO;
    const int b = rg / (YG * DO);
    const int wave = threadIdx.x >> 6;
    const int lane = threadIdx.x & 63;
    const int n_l = lane & 15;
    const int q = lane >> 4;
    const int mt0 = (blockIdx.y * 4 + wave) * NCT;

    f32x4 acc[NCT][RY][NX];
    #pragma unroll
    for (int a = 0; a < NCT; ++a)
        #pragma unroll
        for (int r = 0; r < RY; ++r)
            #pragma unroll
            for (int c = 0; c < NX; ++c)
                acc[a][r][c] = (f32x4){0.f, 0.f, 0.f, 0.f};

    const bf16x8 zero8 = {0, 0, 0, 0, 0, 0, 0, 0};

    for (int ct = 0; ct < NCI; ++ct) {
        #pragma unroll
        for (int dz = 0; dz < 3; ++dz) {
            int zp = z * S + dz - 1;
            if ((unsigned)zp >= (unsigned)DI) continue;
            #pragma unroll
            for (int dy = 0; dy < 3; ++dy) {
                size_t rowb[RY];
                bool vy[RY];
                #pragma unroll
                for (int ry = 0; ry < RY; ++ry) {
                    int yp = (y0 + ry) * S + dy - 1;
                    vy[ry] = (unsigned)yp < (unsigned)DI;
                    rowb[ry] = ((((size_t)b * DI + zp) * DI + (vy[ry] ? yp : 0)) * (DI + 1)) * CV + CV;
                }
                #pragma unroll
                for (int dx = 0; dx < 3; ++dx) {
                    const int tap = dz * 9 + dy * 3 + dx;
                    bf16x8 bh[RY][NX], bl[RY][NX];
                    #pragma unroll
                    for (int ry = 0; ry < RY; ++ry)
                        #pragma unroll
                        for (int nx = 0; nx < NX; ++nx) {
                            if (vy[ry]) {
                                int xp = (nx * 16 + n_l) * S + dx - 1;
                                size_t ba = rowb[ry] + (size_t)xp * CV + ct * 64 + q * 16;
                                bh[ry][nx] = *(const bf16x8*)(inp + ba);
                                bl[ry][nx] = *(const bf16x8*)(inp + ba + 8);
                            } else {
                                bh[ry][nx] = zero8;
                                bl[ry][nx] = zero8;
                            }
                        }
                    #pragma unroll
                    for (int mt = 0; mt < NCT; ++mt) {
                        size_t aa = ((size_t)(tap * NCI + ct) * NMT + (mt0 + mt)) * 1024 + lane * 16;
                        bf16x8 ahf = *(const bf16x8*)(A + aa);
                        bf16x8 alf = *(const bf16x8*)(A + aa + 8);
                        #pragma unroll
                        for (int ry = 0; ry < RY; ++ry)
                            #pragma unroll
                            for (int nx = 0; nx < NX; ++nx) {
                                acc[mt][ry][nx] = __builtin_amdgcn_mfma_f32_16x16x32_bf16(ahf, bh[ry][nx], acc[mt][ry][nx], 0, 0, 0);
                                acc[mt][ry][nx] = __builtin_amdgcn_mfma_f32_16x16x32_bf16(ahf, bl[ry][nx], acc[mt][ry][nx], 0, 0, 0);
                                acc[mt][ry][nx] = __builtin_amdgcn_mfma_f32_16x16x32_bf16(alf, bh[ry][nx], acc[mt][ry][nx], 0, 0, 0);
                            }
                    }
                }
            }
        }
    }

    #pragma unroll
    for (int ry = 0; ry < RY; ++ry) {
        int yo = y0 + ry;
        #pragma unroll
        for (int nx = 0; nx < NX; ++nx) {
            int xo = nx * 16 + n_l;
            size_t vb = ((((size_t)b * DO + z) * DO + yo) * (DO + 1)) * CVO + CVO + (size_t)xo * CVO;
            float mval = 1.f;
            if (EPI & EPI_MASK) mval = mask[(((size_t)b * DO + z) * DO + yo) * DO + xo];
            #pragma unroll
            for (int mt = 0; mt < NCT; ++mt) {
                int c0 = (mt0 + mt) * 16 + q * 4;
                size_t oa = vb + choff(c0);
                float rs[4] = {0.f, 0.f, 0.f, 0.f};
                if (EPI & EPI_RESID) {
                    us4 rh4 = *(const us4*)(resid + oa);
                    us4 rl4 = *(const us4*)(resid + oa + 8);
                    #pragma unroll
                    for (int r = 0; r < 4; ++r) rs[r] = bf2f(rh4[r]) + bf2f(rl4[r]);
                }
                us4 oh, ol;
                #pragma unroll
                for (int r = 0; r < 4; ++r) {
                    float v = acc[mt][ry][nx][r];
                    if (EPI & EPI_MASK) v *= mval;
                    if (EPI & EPI_RESID) v += rs[r];
                    if (EPI & EPI_LEAKY) v = leaky(v);
                    ushort hb = f2bf(v);
                    oh[r] = hb;
                    ol[r] = f2bf(v - bf2f(hb));
                }
                *(us4*)(outp + oa) = oh;
                *(us4*)(outp + oa + 8) = ol;
            }
        }
    }
}

// ---------------- wd3 via MFMA (3-product, interleaved) -> x4 fp32 ------------
__global__ __launch_bounds__(256) void wd3_mfma_kernel(
    const ushort* __restrict__ x3, const ushort* __restrict__ A,
    float* __restrict__ x4)
{
    constexpr int NCI = 8;   // 256/32
    constexpr int NMT = 8;   // 128/16
    const int blk = blockIdx.x;
    const int yg = blk & 3;
    const int z = (blk >> 2) & 7;
    const int b = blk >> 5;
    const int wave = threadIdx.x >> 6;
    const int lane = threadIdx.x & 63;
    const int n_l = lane & 15;
    const int q = lane >> 4;
    const int y = yg * 2 + (n_l >> 3);
    const int x = n_l & 7;
    const int mt0 = wave * 2;

    f32x4 acc[2];
    acc[0] = (f32x4){0.f, 0.f, 0.f, 0.f};
    acc[1] = (f32x4){0.f, 0.f, 0.f, 0.f};
    const bf16x8 zero8 = {0, 0, 0, 0, 0, 0, 0, 0};

    for (int ct = 0; ct < NCI; ++ct) {
        #pragma unroll
        for (int dz = 0; dz < 3; ++dz) {
            int zp = 2 * z + dz - 1;
            if ((unsigned)zp >= 16u) continue;
            #pragma unroll
            for (int dy = 0; dy < 3; ++dy) {
                int yp = 2 * y + dy - 1;
                bool vy = (unsigned)yp < 16u;
                int ypc = vy ? yp : 0;
                #pragma unroll
                for (int dx = 0; dx < 3; ++dx) {
                    int xp = 2 * x + dx - 1;
                    int tap = dz * 9 + dy * 3 + dx;
                    size_t ba = ((((size_t)b * 16 + zp) * 16 + ypc) * 17 + 1 + xp) * 512
                              + ct * 64 + q * 16;
                    bf16x8 bh = vy ? *(const bf16x8*)(x3 + ba) : zero8;
                    bf16x8 bl = vy ? *(const bf16x8*)(x3 + ba + 8) : zero8;
                    #pragma unroll
                    for (int mt = 0; mt < 2; ++mt) {
                        size_t aa = ((size_t)(tap * NCI + ct) * NMT + (mt0 + mt)) * 1024 + lane * 16;
                        bf16x8 ahf = *(const bf16x8*)(A + aa);
                        bf16x8 alf = *(const bf16x8*)(A + aa + 8);
                        acc[mt] = __builtin_amdgcn_mfma_f32_16x16x32_bf16(ahf, bh, acc[mt], 0, 0, 0);
                        acc[mt] = __builtin_amdgcn_mfma_f32_16x16x32_bf16(ahf, bl, acc[mt], 0, 0, 0);
                        acc[mt] = __builtin_amdgcn_mfma_f32_16x16x32_bf16(alf, bh, acc[mt], 0, 0, 0);
                    }
                }
            }
        }
    }
    #pragma unroll
    for (int mt = 0; mt < 2; ++mt)
        #pragma unroll
        for (int r = 0; r < 4; ++r) {
            int co = (mt0 + mt) * 16 + q * 4 + r;
            x4[((size_t)(b * 128 + co)) * 512 + z * 64 + y * 8 + x] = leaky(acc[mt][r]);
        }
}

// ---------------- final: mean/max pool over 8^3 -------------------------------
__global__ __launch_bounds__(64) void reduce_kernel(
    const float* __restrict__ x4, float* __restrict__ out)
{
    int bc = blockIdx.x;
    int b = bc >> 7, c = bc & 127;
    const float* p = x4 + (size_t)(b * 128 + c) * 512;
    float s = 0.f, mx = -3.4e38f;
    for (int i = threadIdx.x; i < 512; i += 64) {
        float v = p[i];
        s += v;
        mx = fmaxf(mx, v);
    }
    #pragma unroll
    for (int o = 32; o > 0; o >>= 1) {
        s += __shfl_down(s, o);
        mx = fmaxf(mx, __shfl_down(mx, o));
    }
    if (threadIdx.x == 0) {
        out[b * 256 + c] = s * (1.f / 512.f);
        out[b * 256 + 128 + c] = mx;
    }
}

__global__ __launch_bounds__(256) void zero_out_kernel(float* __restrict__ out, int n)
{
    int i = blockIdx.x * 256 + threadIdx.x;
    if (i < n) out[i] = 0.f;
}

// ---------------------------------------------------------------------------
extern "C" void kernel_launch(void* const* d_in, const int* in_sizes, int n_in,
                              void* d_out, int out_size, void* d_ws, size_t ws_size,
                              hipStream_t stream)
{
    (void)in_sizes; (void)n_in;
    const float* x    = (const float*)d_in[0];
    const float* mask = (const float*)d_in[1];
    const float* w1a  = (const float*)d_in[2];
    const float* w1b  = (const float*)d_in[3];
    const float* w1d  = (const float*)d_in[4];
    const float* wd1  = (const float*)d_in[5];
    const float* w2a  = (const float*)d_in[6];
    const float* w2b  = (const float*)d_in[7];
    const float* wd2  = (const float*)d_in[8];
    const float* w3a  = (const float*)d_in[9];
    const float* w3b  = (const float*)d_in[10];
    const float* wd3  = (const float*)d_in[11];
    float* out = (float*)d_out;
    char* ws = (char*)d_ws;

    const size_t RSZ = 34603520;      // stage-2 tensor region (interleaved)
    const size_t SZ3 = 8913920;       // stage-3 tensor bytes
    char* R1 = ws;
    char* R2 = ws + RSZ;
    char* R3 = ws + 2 * RSZ;
    size_t off = 3 * RSZ;
    auto alloc = [&](size_t bytes) { char* p = ws + off; off = (off + bytes + 255) & ~255ull; return p; };
    ushort* pk2a = (ushort*)alloc(1769472);
    ushort* pk2b = (ushort*)alloc(1769472);
    ushort* pkd2 = (ushort*)alloc(3538944);
    ushort* pk3a = (ushort*)alloc(7077888);
    ushort* pk3b = (ushort*)alloc(7077888);
    float*  wd1T = (float*)alloc(884736);
    float*  waT  = (float*)alloc(20736);
    float*  wb4  = (float*)alloc(442368);
    float*  wdTt = (float*)alloc(768);
    float*  m2   = (float*)alloc(262144);
    float*  m3   = (float*)alloc(32768);
    int*    cnt  = (int*)alloc(256);
    const size_t NEED = off;

    if (ws_size < NEED) {
        zero_out_kernel<<<dim3((out_size + 255) / 256), 256, 0, stream>>>(out, out_size);
        return;
    }

    // stage-1 scratch aliased into R2 (dead before t2 is written)
    float* t1c  = (float*)R2;
    float* x1c  = (float*)(R2 + 8388608);
    int*   idx  = (int*)(R2 + 16777216);
    int*   list = (int*)(R2 + 18874368);
    // late-phase aliases
    ushort* pkd3 = (ushort*)R1;       // 3,538,944 B (xin3 dead after conv3b)
    float*  x4   = (float*)R2;        // 524,288 B (t3 dead after conv3b)

    ushort* xin2 = (ushort*)R1;
    ushort* t2   = (ushort*)R2;
    ushort* x2   = (ushort*)R3;
    ushort* xin3 = (ushort*)R1;
    ushort* t3   = (ushort*)R2;
    ushort* x3   = (ushort*)R3;

    hipMemsetAsync(cnt, 0, 4, stream);
    hipMemsetAsync(idx, 0xFF, 2097152, stream);
    hipMemsetAsync(R1, 0, RSZ, stream);           // xin2 pads

    auto tg = [](int n) { return dim3((n + 255) / 256); };
    pack_w_kernel<<<tg(27 * 128 * 128 * 2), 256, 0, stream>>>(w2a, pk2a, 128, 128);
    pack_w_kernel<<<tg(27 * 128 * 128 * 2), 256, 0, stream>>>(w2b, pk2b, 128, 128);
    pack_w_kernel<<<tg(27 * 128 * 256 * 2), 256, 0, stream>>>(wd2, pkd2, 128, 256);
    pack_w_kernel<<<tg(27 * 256 * 256 * 2), 256, 0, stream>>>(w3a, pk3a, 256, 256);
    pack_w_kernel<<<tg(27 * 256 * 256 * 2), 256, 0, stream>>>(w3b, pk3b, 256, 256);
    transpose_w_kernel <<<tg(128 * 1728), 256, 0, stream>>>(wd1, wd1T, 128, 1728);
    transpose_w_kernel <<<tg(64 * 81),    256, 0, stream>>>(w1a, waT,  64, 81);
    transpose_w4_kernel<<<tg(64 * 1728),  256, 0, stream>>>(w1b, wb4,  64, 1728);
    transpose_w_kernel <<<tg(64 * 3),     256, 0, stream>>>(w1d, wdTt, 64, 3);

    maxpool_kernel<64, 32><<<dim3(2 * 32768 / 256), 256, 0, stream>>>(mask, m2);
    maxpool_kernel<32, 16><<<dim3(2 * 4096 / 256),  256, 0, stream>>>(m2, m3);
    build_list_kernel<<<dim3(2 * 262144 / 256), 256, 0, stream>>>(mask, list, idx, cnt);

    // stage 1 (sparse, fp32)
    stage1a_kernel<<<dim3(2048), 64, 0, stream>>>(x, waT, list, cnt, t1c);
    stage1b_kernel<<<dim3(2048), 64, 0, stream>>>(t1c, x, wb4, wdTt, list, idx, cnt, x1c);
    wd1_kernel<<<dim3(128, 8, 2), 256, 0, stream>>>(x1c, idx, wd1T, xin2);

    // stage-1 scratch dead; clear R2/R3 (t2/x2 pads)
    hipMemsetAsync(R2, 0, RSZ, stream);
    hipMemsetAsync(R3, 0, RSZ, stream);

    // stage2 res block
    mfma_conv3_kernel<128, 128, 32, 32, 1, 2, 2, 2, EPI_MASK | EPI_LEAKY>
        <<<dim3(1024, 1), 256, 0, stream>>>(xin2, pk2a, m2, nullptr, t2);
    mfma_conv3_kernel<128, 128, 32, 32, 1, 2, 2, 2, EPI_MASK | EPI_RESID | EPI_LEAKY>
        <<<dim3(1024, 1), 256, 0, stream>>>(t2, pk2b, m2, xin2, x2);

    // xin2 dead -> clear xin3 area
    hipMemsetAsync(R1, 0, SZ3, stream);
    mfma_conv3_kernel<128, 256, 32, 16, 2, 2, 1, 2, EPI_LEAKY>
        <<<dim3(256, 2), 256, 0, stream>>>(x2, pkd2, nullptr, nullptr, xin3);

    hipMemsetAsync(R2, 0, SZ3, stream);
    mfma_conv3_kernel<256, 256, 16, 16, 1, 2, 1, 2, EPI_MASK | EPI_LEAKY>
        <<<dim3(256, 2), 256, 0, stream>>>(xin3, pk3a, m3, nullptr, t3);

    hipMemsetAsync(R3, 0, SZ3, stream);
    mfma_conv3_kernel<256, 256, 16, 16, 1, 2, 1, 2, EPI_MASK | EPI_RESID | EPI_LEAKY>
        <<<dim3(256, 2), 256, 0, stream>>>(t3, pk3b, m3, xin3, x3);

    // xin3 (R1) and t3 (R2) dead: pack wd3 -> R1, MFMA wd3 -> x4 (R2)
    pack_w_kernel<<<tg(27 * 256 * 128 * 2), 256, 0, stream>>>(wd3, pkd3, 256, 128);
    wd3_mfma_kernel<<<dim3(64), 256, 0, stream>>>(x3, pkd3, x4);

    reduce_kernel<<<dim3(256), 64, 0, stream>>>(x4, out);
}

// Round 9
// 2336.836 us; speedup vs baseline: 4.5013x; 1.1331x over previous
//
#include <hip/hip_runtime.h>

// ---------------------------------------------------------------------------
// SparseEncoderResUNet on MI355X — round 9: wd1 divergence fix.
// r8 diagnosis: wd1 525us (20% of total) — lanes=voxels makes the per-tap
// sparsity test per-lane: wave runs 96% of tap bodies with ~5% lanes active
// (~19x wasted issue). Fix: lanes=channels, one output voxel per 128-thread
// block; probes + active rows staged in LDS; tap skip wave-uniform; weight
// reads 512B-coalesced from L2 (~2.9GB total -> ~85us floor).
// Accumulation order unchanged -> bit-identical (absmax 0.0).
// Everything else identical to r8.
// ---------------------------------------------------------------------------

enum { EPI_MASK = 1, EPI_LEAKY = 2, EPI_RESID = 4 };
#define ROWCAP 32768

typedef short  bf16x8 __attribute__((ext_vector_type(8)));
typedef float  f32x4  __attribute__((ext_vector_type(4)));
typedef ushort us4    __attribute__((ext_vector_type(4)));

__device__ __forceinline__ float leaky(float v) { return v >= 0.f ? v : 0.2f * v; }
__device__ __forceinline__ ushort f2bf(float f) {
    unsigned u = __float_as_uint(f);
    return (ushort)((u + 0x7FFFu + ((u >> 16) & 1u)) >> 16);
}
__device__ __forceinline__ float bf2f(ushort h) {
    return __uint_as_float((unsigned)h << 16);
}
// channel c -> offset within a voxel's CI*2 block (interleaved hi/lo by 8)
__device__ __forceinline__ int choff(int c) {
    return (c >> 5) * 64 + ((c >> 3) & 3) * 16 + (c & 7);
}

// ---------------- weight transpose: w[co][cik] -> wT[cik][co] ----------------
__global__ __launch_bounds__(256) void transpose_w_kernel(
    const float* __restrict__ w, float* __restrict__ wT, int CO, int CIK)
{
    int i = blockIdx.x * 256 + threadIdx.x;
    if (i >= CO * CIK) return;
    int co = i / CIK, r = i - co * CIK;
    wT[(size_t)r * CO + co] = w[i];
}

// interleaved-by-4 layout for stage1b
__global__ __launch_bounds__(256) void transpose_w4_kernel(
    const float* __restrict__ w, float* __restrict__ w4, int CO, int CIK)
{
    int i = blockIdx.x * 256 + threadIdx.x;
    if (i >= CO * CIK) return;
    int co = i / CIK, r = i - co * CIK;
    w4[(((size_t)(r >> 2) * CO) + co) * 4 + (r & 3)] = w[i];
}

// ---------------- pack weights into MFMA A-frag layout, hi/lo interleaved ----
__global__ __launch_bounds__(256) void pack_w_kernel(
    const float* __restrict__ w, ushort* __restrict__ A, int CI, int CO)
{
    int i = blockIdx.x * 256 + threadIdx.x;
    if (i >= 27 * CI * CO * 2) return;
    int j = i & 7, hilo = (i >> 3) & 1, L = (i >> 4) & 63, rest = i >> 10;
    int NMT = CO >> 4, NCI = CI >> 5;
    int mt = rest % NMT; rest /= NMT;
    int ct = rest % NCI;
    int tap = rest / NCI;
    int co = mt * 16 + (L & 15);
    int ci = ct * 32 + (L >> 4) * 8 + j;
    float v = w[((size_t)co * CI + ci) * 27 + tap];
    ushort h = f2bf(v);
    A[i] = hilo ? f2bf(v - bf2f(h)) : h;
}

// ---------------- maxpool k3 s2 p1 (down_mask) ----------------
template<int DIN, int DOUT>
__global__ __launch_bounds__(256) void maxpool_kernel(
    const float* __restrict__ in, float* __restrict__ out)
{
    int i = blockIdx.x * 256 + threadIdx.x;
    constexpr int D3O = DOUT * DOUT * DOUT;
    if (i >= 2 * D3O) return;
    int b = i / D3O;
    int v = i - b * D3O;
    int z = v / (DOUT * DOUT), y = (v / DOUT) % DOUT, x = v % DOUT;
    float mx = 0.f;
    #pragma unroll
    for (int dz = 0; dz < 3; ++dz)
        #pragma unroll
        for (int dy = 0; dy < 3; ++dy)
            #pragma unroll
            for (int dx = 0; dx < 3; ++dx) {
                int zi = 2 * z - 1 + dz, yi = 2 * y - 1 + dy, xi = 2 * x - 1 + dx;
                if ((unsigned)zi < (unsigned)DIN && (unsigned)yi < (unsigned)DIN &&
                    (unsigned)xi < (unsigned)DIN)
                    mx = fmaxf(mx, in[(size_t)b * DIN * DIN * DIN + (zi * DIN + yi) * DIN + xi]);
            }
    out[i] = mx;
}

// ---------------- active-voxel list + dense index map ----------------
__global__ __launch_bounds__(256) void build_list_kernel(
    const float* __restrict__ m, int* __restrict__ list, int* __restrict__ idxmap,
    int* __restrict__ count)
{
    int i = blockIdx.x * 256 + threadIdx.x;
    if (i >= 2 * 262144) return;
    if (m[i] > 0.5f) {
        int k = atomicAdd(count, 1);
        if (k < ROWCAP) {
            list[k] = i;
            idxmap[i] = k;
        }
    }
}

// ---------------- stage1 conv-a (3->64, gathered) -> t1c[row][64] ----------------
__global__ __launch_bounds__(64) void stage1a_kernel(
    const float* __restrict__ x, const float* __restrict__ waT,
    const int* __restrict__ list, const int* __restrict__ count,
    float* __restrict__ t1c)
{
    __shared__ float smem[81];
    int n = min(*count, ROWCAP);
    for (int i = blockIdx.x; i < n; i += gridDim.x) {
        int lin = list[i];
        int b = lin >> 18;
        int v = lin & 262143;
        int z = v >> 12, y = (v >> 6) & 63, xx = v & 63;
        for (int j = threadIdx.x; j < 81; j += 64) {
            int ci = j / 27, t = j - ci * 27;
            int zz = z + t / 9 - 1, yy = y + (t / 3) % 3 - 1, xc = xx + t % 3 - 1;
            float val = 0.f;
            if ((unsigned)zz < 64u && (unsigned)yy < 64u && (unsigned)xc < 64u)
                val = x[(size_t)(b * 3 + ci) * 262144 + (zz << 12) + (yy << 6) + xc];
            smem[j] = val;
        }
        __syncthreads();
        float acc = 0.f;
        #pragma unroll 9
        for (int j = 0; j < 81; ++j)
            acc = fmaf(smem[j], waT[j * 64 + threadIdx.x], acc);
        t1c[(size_t)i * 64 + threadIdx.x] = leaky(acc);
        __syncthreads();
    }
}

// ---------------- stage1 conv-b (64->64, gathered) + 1x1 identity ----------------
__global__ __launch_bounds__(64) void stage1b_kernel(
    const float* __restrict__ t1c, const float* __restrict__ x,
    const float* __restrict__ wb4, const float* __restrict__ wdT,
    const int* __restrict__ list, const int* __restrict__ idxmap,
    const int* __restrict__ count,
    float* __restrict__ x1c)
{
    __shared__ float sw[4 * 1728];
    int n = min(*count, ROWCAP);
    int nq = (n + 3) >> 2;
    for (int q = blockIdx.x; q < nq; q += gridDim.x) {
        for (int vv = 0; vv < 4; ++vv) {
            int i = q * 4 + vv;
            int lin = (i < n) ? list[i] : list[0];
            int b = lin >> 18;
            int v = lin & 262143;
            int z = v >> 12, y = (v >> 6) & 63, xx = v & 63;
            const int* im = idxmap + b * 262144;
            #pragma unroll
            for (int t = 0; t < 27; ++t) {
                int zz = z + t / 9 - 1, yy = y + (t / 3) % 3 - 1, xc = xx + t % 3 - 1;
                float val = 0.f;
                if ((unsigned)zz < 64u && (unsigned)yy < 64u && (unsigned)xc < 64u) {
                    int r = im[(zz << 12) + (yy << 6) + xc];
                    if (r >= 0)
                        val = t1c[(size_t)r * 64 + threadIdx.x];
                }
                sw[vv * 1728 + threadIdx.x * 27 + t] = val;
            }
        }
        __syncthreads();
        float acc[4] = {0.f, 0.f, 0.f, 0.f};
        const float* wp = wb4 + threadIdx.x * 4;
        for (int j4 = 0; j4 < 432; ++j4) {
            float4 w = *(const float4*)(wp + (size_t)j4 * 256);
            #pragma unroll
            for (int vv = 0; vv < 4; ++vv) {
                float4 s = *(const float4*)(&sw[vv * 1728 + j4 * 4]);
                acc[vv] = fmaf(s.x, w.x, acc[vv]);
                acc[vv] = fmaf(s.y, w.y, acc[vv]);
                acc[vv] = fmaf(s.z, w.z, acc[vv]);
                acc[vv] = fmaf(s.w, w.w, acc[vv]);
            }
        }
        #pragma unroll
        for (int vv = 0; vv < 4; ++vv) {
            int i = q * 4 + vv;
            if (i < n) {
                int lin = list[i];
                int b = lin >> 18;
                int v = lin & 262143;
                float id = 0.f;
                #pragma unroll
                for (int ci = 0; ci < 3; ++ci)
                    id = fmaf(x[(size_t)(b * 3 + ci) * 262144 + v], wdT[ci * 64 + threadIdx.x], id);
                x1c[(size_t)i * 64 + threadIdx.x] = leaky(acc[vv] + id);
            }
        }
        __syncthreads();
    }
}

// ---------------- wd1 v2: lanes = channels, wave-uniform tap skip -------------
// block = 128 threads (thread = co), one output voxel; out interleaved CL.
__global__ __launch_bounds__(128) void wd1_kernel(
    const float* __restrict__ x1c, const int* __restrict__ idxmap,
    const float* __restrict__ wT,   // [ci*27+tap][128]
    ushort* __restrict__ outp)
{
    __shared__ int   srr[27];
    __shared__ float sx[27][64];
    const int tid = threadIdx.x;
    const int v = blockIdx.x;           // 0..32767
    const int b = blockIdx.y;
    const int zo = v >> 10, yo = (v >> 5) & 31, xo = v & 31;
    const int* im = idxmap + b * 262144;

    if (tid < 27) {
        int kz = tid / 9, ky = (tid / 3) % 3, kx = tid % 3;
        int zi = 2 * zo - 1 + kz, yi = 2 * yo - 1 + ky, xi = 2 * xo - 1 + kx;
        int r = -1;
        if ((unsigned)zi < 64u && (unsigned)yi < 64u && (unsigned)xi < 64u)
            r = im[(zi << 12) + (yi << 6) + xi];
        srr[tid] = r;
    }
    __syncthreads();
    #pragma unroll 1
    for (int t = 0; t < 27; ++t) {
        int r = srr[t];
        if (r >= 0 && tid < 64)
            sx[t][tid] = x1c[(size_t)r * 64 + tid];
    }
    __syncthreads();

    float acc = 0.f;
    #pragma unroll 1
    for (int t = 0; t < 27; ++t) {
        if (srr[t] < 0) continue;
        const float* wp = wT + (size_t)t * 128 + tid;
        const float* xr = sx[t];
        #pragma unroll 8
        for (int ci = 0; ci < 64; ++ci)
            acc = fmaf(xr[ci], wp[(size_t)ci * 27 * 128], acc);
    }
    float val = leaky(acc);
    ushort hb = f2bf(val);
    ushort lb = f2bf(val - bf2f(hb));
    size_t vb = ((((size_t)b * 32 + zo) * 32 + yo) * 33 + xo) * 256 + 256;
    int off = choff(tid);
    outp[vb + off] = hb;
    outp[vb + off + 8] = lb;
}

// ---------------- MFMA implicit-GEMM conv v3 (3-product, interleaved) --------
template<int CI, int CO, int DI, int DO, int S, int RY, int NX, int NCT, int EPI>
__global__ __launch_bounds__(256) void mfma_conv3_kernel(
    const ushort* __restrict__ inp, const ushort* __restrict__ A,
    const float* __restrict__ mask, const ushort* __restrict__ resid,
    ushort* __restrict__ outp)
{
    constexpr int NCI = CI / 32;
    constexpr int NMT = CO / 16;
    constexpr int CV = CI * 2;
    constexpr int CVO = CO * 2;
    constexpr int YG = DO / RY;
    const int rg = blockIdx.x;
    const int y0 = (rg % YG) * RY;
    const int z = (rg / YG) % DO;
    const int b = rg / (YG * DO);
    const int wave = threadIdx.x >> 6;
    const int lane = threadIdx.x & 63;
    const int n_l = lane & 15;
    const int q = lane >> 4;
    const int mt0 = (blockIdx.y * 4 + wave) * NCT;

    f32x4 acc[NCT][RY][NX];
    #pragma unroll
    for (int a = 0; a < NCT; ++a)
        #pragma unroll
        for (int r = 0; r < RY; ++r)
            #pragma unroll
            for (int c = 0; c < NX; ++c)
                acc[a][r][c] = (f32x4){0.f, 0.f, 0.f, 0.f};

    const bf16x8 zero8 = {0, 0, 0, 0, 0, 0, 0, 0};

    for (int ct = 0; ct < NCI; ++ct) {
        #pragma unroll
        for (int dz = 0; dz < 3; ++dz) {
            int zp = z * S + dz - 1;
            if ((unsigned)zp >= (unsigned)DI) continue;
            #pragma unroll
            for (int dy = 0; dy < 3; ++dy) {
                size_t rowb[RY];
                bool vy[RY];
                #pragma unroll
                for (int ry = 0; ry < RY; ++ry) {
                    int yp = (y0 + ry) * S + dy - 1;
                    vy[ry] = (unsigned)yp < (unsigned)DI;
                    rowb[ry] = ((((size_t)b * DI + zp) * DI + (vy[ry] ? yp : 0)) * (DI + 1)) * CV + CV;
                }
                #pragma unroll
                for (int dx = 0; dx < 3; ++dx) {
                    const int tap = dz * 9 + dy * 3 + dx;
                    bf16x8 bh[RY][NX], bl[RY][NX];
                    #pragma unroll
                    for (int ry = 0; ry < RY; ++ry)
                        #pragma unroll
                        for (int nx = 0; nx < NX; ++nx) {
                            if (vy[ry]) {
                                int xp = (nx * 16 + n_l) * S + dx - 1;
                                size_t ba = rowb[ry] + (size_t)xp * CV + ct * 64 + q * 16;
                                bh[ry][nx] = *(const bf16x8*)(inp + ba);
                                bl[ry][nx] = *(const bf16x8*)(inp + ba + 8);
                            } else {
                                bh[ry][nx] = zero8;
                                bl[ry][nx] = zero8;
                            }
                        }
                    #pragma unroll
                    for (int mt = 0; mt < NCT; ++mt) {
                        size_t aa = ((size_t)(tap * NCI + ct) * NMT + (mt0 + mt)) * 1024 + lane * 16;
                        bf16x8 ahf = *(const bf16x8*)(A + aa);
                        bf16x8 alf = *(const bf16x8*)(A + aa + 8);
                        #pragma unroll
                        for (int ry = 0; ry < RY; ++ry)
                            #pragma unroll
                            for (int nx = 0; nx < NX; ++nx) {
                                acc[mt][ry][nx] = __builtin_amdgcn_mfma_f32_16x16x32_bf16(ahf, bh[ry][nx], acc[mt][ry][nx], 0, 0, 0);
                                acc[mt][ry][nx] = __builtin_amdgcn_mfma_f32_16x16x32_bf16(ahf, bl[ry][nx], acc[mt][ry][nx], 0, 0, 0);
                                acc[mt][ry][nx] = __builtin_amdgcn_mfma_f32_16x16x32_bf16(alf, bh[ry][nx], acc[mt][ry][nx], 0, 0, 0);
                            }
                    }
                }
            }
        }
    }

    #pragma unroll
    for (int ry = 0; ry < RY; ++ry) {
        int yo = y0 + ry;
        #pragma unroll
        for (int nx = 0; nx < NX; ++nx) {
            int xo = nx * 16 + n_l;
            size_t vb = ((((size_t)b * DO + z) * DO + yo) * (DO + 1)) * CVO + CVO + (size_t)xo * CVO;
            float mval = 1.f;
            if (EPI & EPI_MASK) mval = mask[(((size_t)b * DO + z) * DO + yo) * DO + xo];
            #pragma unroll
            for (int mt = 0; mt < NCT; ++mt) {
                int c0 = (mt0 + mt) * 16 + q * 4;
                size_t oa = vb + choff(c0);
                float rs[4] = {0.f, 0.f, 0.f, 0.f};
                if (EPI & EPI_RESID) {
                    us4 rh4 = *(const us4*)(resid + oa);
                    us4 rl4 = *(const us4*)(resid + oa + 8);
                    #pragma unroll
                    for (int r = 0; r < 4; ++r) rs[r] = bf2f(rh4[r]) + bf2f(rl4[r]);
                }
                us4 oh, ol;
                #pragma unroll
                for (int r = 0; r < 4; ++r) {
                    float v = acc[mt][ry][nx][r];
                    if (EPI & EPI_MASK) v *= mval;
                    if (EPI & EPI_RESID) v += rs[r];
                    if (EPI & EPI_LEAKY) v = leaky(v);
                    ushort hb = f2bf(v);
                    oh[r] = hb;
                    ol[r] = f2bf(v - bf2f(hb));
                }
                *(us4*)(outp + oa) = oh;
                *(us4*)(outp + oa + 8) = ol;
            }
        }
    }
}

// ---------------- wd3 via MFMA (3-product, interleaved) -> x4 fp32 ------------
__global__ __launch_bounds__(256) void wd3_mfma_kernel(
    const ushort* __restrict__ x3, const ushort* __restrict__ A,
    float* __restrict__ x4)
{
    constexpr int NCI = 8;   // 256/32
    constexpr int NMT = 8;   // 128/16
    const int blk = blockIdx.x;
    const int yg = blk & 3;
    const int z = (blk >> 2) & 7;
    const int b = blk >> 5;
    const int wave = threadIdx.x >> 6;
    const int lane = threadIdx.x & 63;
    const int n_l = lane & 15;
    const int q = lane >> 4;
    const int y = yg * 2 + (n_l >> 3);
    const int x = n_l & 7;
    const int mt0 = wave * 2;

    f32x4 acc[2];
    acc[0] = (f32x4){0.f, 0.f, 0.f, 0.f};
    acc[1] = (f32x4){0.f, 0.f, 0.f, 0.f};
    const bf16x8 zero8 = {0, 0, 0, 0, 0, 0, 0, 0};

    for (int ct = 0; ct < NCI; ++ct) {
        #pragma unroll
        for (int dz = 0; dz < 3; ++dz) {
            int zp = 2 * z + dz - 1;
            if ((unsigned)zp >= 16u) continue;
            #pragma unroll
            for (int dy = 0; dy < 3; ++dy) {
                int yp = 2 * y + dy - 1;
                bool vy = (unsigned)yp < 16u;
                int ypc = vy ? yp : 0;
                #pragma unroll
                for (int dx = 0; dx < 3; ++dx) {
                    int xp = 2 * x + dx - 1;
                    int tap = dz * 9 + dy * 3 + dx;
                    size_t ba = ((((size_t)b * 16 + zp) * 16 + ypc) * 17 + 1 + xp) * 512
                              + ct * 64 + q * 16;
                    bf16x8 bh = vy ? *(const bf16x8*)(x3 + ba) : zero8;
                    bf16x8 bl = vy ? *(const bf16x8*)(x3 + ba + 8) : zero8;
                    #pragma unroll
                    for (int mt = 0; mt < 2; ++mt) {
                        size_t aa = ((size_t)(tap * NCI + ct) * NMT + (mt0 + mt)) * 1024 + lane * 16;
                        bf16x8 ahf = *(const bf16x8*)(A + aa);
                        bf16x8 alf = *(const bf16x8*)(A + aa + 8);
                        acc[mt] = __builtin_amdgcn_mfma_f32_16x16x32_bf16(ahf, bh, acc[mt], 0, 0, 0);
                        acc[mt] = __builtin_amdgcn_mfma_f32_16x16x32_bf16(ahf, bl, acc[mt], 0, 0, 0);
                        acc[mt] = __builtin_amdgcn_mfma_f32_16x16x32_bf16(alf, bh, acc[mt], 0, 0, 0);
                    }
                }
            }
        }
    }
    #pragma unroll
    for (int mt = 0; mt < 2; ++mt)
        #pragma unroll
        for (int r = 0; r < 4; ++r) {
            int co = (mt0 + mt) * 16 + q * 4 + r;
            x4[((size_t)(b * 128 + co)) * 512 + z * 64 + y * 8 + x] = leaky(acc[mt][r]);
        }
}

// ---------------- final: mean/max pool over 8^3 -------------------------------
__global__ __launch_bounds__(64) void reduce_kernel(
    const float* __restrict__ x4, float* __restrict__ out)
{
    int bc = blockIdx.x;
    int b = bc >> 7, c = bc & 127;
    const float* p = x4 + (size_t)(b * 128 + c) * 512;
    float s = 0.f, mx = -3.4e38f;
    for (int i = threadIdx.x; i < 512; i += 64) {
        float v = p[i];
        s += v;
        mx = fmaxf(mx, v);
    }
    #pragma unroll
    for (int o = 32; o > 0; o >>= 1) {
        s += __shfl_down(s, o);
        mx = fmaxf(mx, __shfl_down(mx, o));
    }
    if (threadIdx.x == 0) {
        out[b * 256 + c] = s * (1.f / 512.f);
        out[b * 256 + 128 + c] = mx;
    }
}

__global__ __launch_bounds__(256) void zero_out_kernel(float* __restrict__ out, int n)
{
    int i = blockIdx.x * 256 + threadIdx.x;
    if (i < n) out[i] = 0.f;
}

// ---------------------------------------------------------------------------
extern "C" void kernel_launch(void* const* d_in, const int* in_sizes, int n_in,
                              void* d_out, int out_size, void* d_ws, size_t ws_size,
                              hipStream_t stream)
{
    (void)in_sizes; (void)n_in;
    const float* x    = (const float*)d_in[0];
    const float* mask = (const float*)d_in[1];
    const float* w1a  = (const float*)d_in[2];
    const float* w1b  = (const float*)d_in[3];
    const float* w1d  = (const float*)d_in[4];
    const float* wd1  = (const float*)d_in[5];
    const float* w2a  = (const float*)d_in[6];
    const float* w2b  = (const float*)d_in[7];
    const float* wd2  = (const float*)d_in[8];
    const float* w3a  = (const float*)d_in[9];
    const float* w3b  = (const float*)d_in[10];
    const float* wd3  = (const float*)d_in[11];
    float* out = (float*)d_out;
    char* ws = (char*)d_ws;

    const size_t RSZ = 34603520;      // stage-2 tensor region (interleaved)
    const size_t SZ3 = 8913920;       // stage-3 tensor bytes
    char* R1 = ws;
    char* R2 = ws + RSZ;
    char* R3 = ws + 2 * RSZ;
    size_t off = 3 * RSZ;
    auto alloc = [&](size_t bytes) { char* p = ws + off; off = (off + bytes + 255) & ~255ull; return p; };
    ushort* pk2a = (ushort*)alloc(1769472);
    ushort* pk2b = (ushort*)alloc(1769472);
    ushort* pkd2 = (ushort*)alloc(3538944);
    ushort* pk3a = (ushort*)alloc(7077888);
    ushort* pk3b = (ushort*)alloc(7077888);
    float*  wd1T = (float*)alloc(884736);
    float*  waT  = (float*)alloc(20736);
    float*  wb4  = (float*)alloc(442368);
    float*  wdTt = (float*)alloc(768);
    float*  m2   = (float*)alloc(262144);
    float*  m3   = (float*)alloc(32768);
    int*    cnt  = (int*)alloc(256);
    const size_t NEED = off;

    if (ws_size < NEED) {
        zero_out_kernel<<<dim3((out_size + 255) / 256), 256, 0, stream>>>(out, out_size);
        return;
    }

    // stage-1 scratch aliased into R2 (dead before t2 is written)
    float* t1c  = (float*)R2;
    float* x1c  = (float*)(R2 + 8388608);
    int*   idx  = (int*)(R2 + 16777216);
    int*   list = (int*)(R2 + 18874368);
    // late-phase aliases
    ushort* pkd3 = (ushort*)R1;       // xin3 dead after conv3b
    float*  x4   = (float*)R2;        // t3 dead after conv3b

    ushort* xin2 = (ushort*)R1;
    ushort* t2   = (ushort*)R2;
    ushort* x2   = (ushort*)R3;
    ushort* xin3 = (ushort*)R1;
    ushort* t3   = (ushort*)R2;
    ushort* x3   = (ushort*)R3;

    hipMemsetAsync(cnt, 0, 4, stream);
    hipMemsetAsync(idx, 0xFF, 2097152, stream);
    hipMemsetAsync(R1, 0, RSZ, stream);           // xin2 pads

    auto tg = [](int n) { return dim3((n + 255) / 256); };
    pack_w_kernel<<<tg(27 * 128 * 128 * 2), 256, 0, stream>>>(w2a, pk2a, 128, 128);
    pack_w_kernel<<<tg(27 * 128 * 128 * 2), 256, 0, stream>>>(w2b, pk2b, 128, 128);
    pack_w_kernel<<<tg(27 * 128 * 256 * 2), 256, 0, stream>>>(wd2, pkd2, 128, 256);
    pack_w_kernel<<<tg(27 * 256 * 256 * 2), 256, 0, stream>>>(w3a, pk3a, 256, 256);
    pack_w_kernel<<<tg(27 * 256 * 256 * 2), 256, 0, stream>>>(w3b, pk3b, 256, 256);
    transpose_w_kernel <<<tg(128 * 1728), 256, 0, stream>>>(wd1, wd1T, 128, 1728);
    transpose_w_kernel <<<tg(64 * 81),    256, 0, stream>>>(w1a, waT,  64, 81);
    transpose_w4_kernel<<<tg(64 * 1728),  256, 0, stream>>>(w1b, wb4,  64, 1728);
    transpose_w_kernel <<<tg(64 * 3),     256, 0, stream>>>(w1d, wdTt, 64, 3);

    maxpool_kernel<64, 32><<<dim3(2 * 32768 / 256), 256, 0, stream>>>(mask, m2);
    maxpool_kernel<32, 16><<<dim3(2 * 4096 / 256),  256, 0, stream>>>(m2, m3);
    build_list_kernel<<<dim3(2 * 262144 / 256), 256, 0, stream>>>(mask, list, idx, cnt);

    // stage 1 (sparse, fp32)
    stage1a_kernel<<<dim3(2048), 64, 0, stream>>>(x, waT, list, cnt, t1c);
    stage1b_kernel<<<dim3(2048), 64, 0, stream>>>(t1c, x, wb4, wdTt, list, idx, cnt, x1c);
    wd1_kernel<<<dim3(32768, 2), 128, 0, stream>>>(x1c, idx, wd1T, xin2);

    // stage-1 scratch dead; clear R2/R3 (t2/x2 pads)
    hipMemsetAsync(R2, 0, RSZ, stream);
    hipMemsetAsync(R3, 0, RSZ, stream);

    // stage2 res block
    mfma_conv3_kernel<128, 128, 32, 32, 1, 2, 2, 2, EPI_MASK | EPI_LEAKY>
        <<<dim3(1024, 1), 256, 0, stream>>>(xin2, pk2a, m2, nullptr, t2);
    mfma_conv3_kernel<128, 128, 32, 32, 1, 2, 2, 2, EPI_MASK | EPI_RESID | EPI_LEAKY>
        <<<dim3(1024, 1), 256, 0, stream>>>(t2, pk2b, m2, xin2, x2);

    // xin2 dead -> clear xin3 area
    hipMemsetAsync(R1, 0, SZ3, stream);
    mfma_conv3_kernel<128, 256, 32, 16, 2, 2, 1, 2, EPI_LEAKY>
        <<<dim3(256, 2), 256, 0, stream>>>(x2, pkd2, nullptr, nullptr, xin3);

    hipMemsetAsync(R2, 0, SZ3, stream);
    mfma_conv3_kernel<256, 256, 16, 16, 1, 2, 1, 2, EPI_MASK | EPI_LEAKY>
        <<<dim3(256, 2), 256, 0, stream>>>(xin3, pk3a, m3, nullptr, t3);

    hipMemsetAsync(R3, 0, SZ3, stream);
    mfma_conv3_kernel<256, 256, 16, 16, 1, 2, 1, 2, EPI_MASK | EPI_RESID | EPI_LEAKY>
        <<<dim3(256, 2), 256, 0, stream>>>(t3, pk3b, m3, xin3, x3);

    // xin3 (R1) and t3 (R2) dead: pack wd3 -> R1, MFMA wd3 -> x4 (R2)
    pack_w_kernel<<<tg(27 * 256 * 128 * 2), 256, 0, stream>>>(wd3, pkd3, 256, 128);
    wd3_mfma_kernel<<<dim3(64), 256, 0, stream>>>(x3, pkd3, x4);

    reduce_kernel<<<dim3(256), 64, 0, stream>>>(x4, out);
}